// Round 1
// baseline (1060.264 us; speedup 1.0000x reference)
//
#include <hip/hip_runtime.h>
#include <math.h>

#define EPS 1e-5f

// B=1024 groups, n=32 points, channels: 3 -> 128 -> 256 -> (concat 512) -> 512 -> 384
// Output: (4,256,384) float32 == flat (1024,384)

// ---------------------------------------------------------------- K1: conv1 (3->128) pre-BN + per-channel partial stats + knn indices
__global__ __launch_bounds__(128) void k1_conv1_knn(
    const float* __restrict__ pg, const float* __restrict__ W1,
    const float* __restrict__ b1,
    float* __restrict__ h1, float* __restrict__ p1s, float* __restrict__ p1q,
    int* __restrict__ idxw)
{
    const int b = blockIdx.x;
    const int t = threadIdx.x;
    __shared__ float pgs[96];
    __shared__ float sqs[32];
    if (t < 96) pgs[t] = pg[b * 96 + t];
    __syncthreads();
    if (t < 32) {
        float x = pgs[t*3+0], y = pgs[t*3+1], z = pgs[t*3+2];
        sqs[t] = x*x + y*y + z*z;
    }
    __syncthreads();
    // conv1: channel o = t (128 channels)
    {
        const float w0 = W1[t*3+0], w1 = W1[t*3+1], w2 = W1[t*3+2];
        const float bb = b1[t];
        float s = 0.f, q = 0.f;
        float* hrow = h1 + (size_t)b*4096 + t*32;
        #pragma unroll
        for (int l = 0; l < 32; ++l) {
            float v = fmaf(w2, pgs[l*3+2], fmaf(w1, pgs[l*3+1], fmaf(w0, pgs[l*3+0], bb)));
            hrow[l] = v; s += v; q += v*v;
        }
        p1s[t*1024 + b] = s;   // layout [channel][block] for coalesced reduce
        p1q[t*1024 + b] = q;
    }
    // knn: 8 nearest of 32 (ties -> lowest index, matching top_k)
    if (t < 32) {
        const float xl = pgs[t*3+0], yl = pgs[t*3+1], zl = pgs[t*3+2];
        const float sql = sqs[t];
        float dist[32];
        #pragma unroll
        for (int m = 0; m < 32; ++m) {
            float dot = xl*pgs[m*3+0] + yl*pgs[m*3+1] + zl*pgs[m*3+2];
            dist[m] = sql + sqs[m] - 2.f*dot;
        }
        unsigned used = 0u;
        int* orow = idxw + b*256 + t*8;
        #pragma unroll
        for (int j = 0; j < 8; ++j) {
            float best = 3.4e38f; int bi = 0;
            #pragma unroll
            for (int m = 0; m < 32; ++m) {
                if (!((used >> m) & 1u) && dist[m] < best) { best = dist[m]; bi = m; }
            }
            used |= (1u << bi);
            orow[j] = bi;
        }
    }
}

// ---------------------------------------------------------------- generic BN finalize: one block per channel
__global__ void k_bn_fin(const float* __restrict__ ps, const float* __restrict__ pq,
                         int nPart, float invN,
                         const float* __restrict__ gamma, const float* __restrict__ beta,
                         float* __restrict__ scale, float* __restrict__ shift)
{
    const int o = blockIdx.x;
    const int t = threadIdx.x;
    float s = 0.f, q = 0.f;
    for (int i = t; i < nPart; i += blockDim.x) {
        s += ps[o*nPart + i];
        q += pq[o*nPart + i];
    }
    #pragma unroll
    for (int off = 32; off > 0; off >>= 1) {
        s += __shfl_down(s, off, 64);
        q += __shfl_down(q, off, 64);
    }
    __shared__ float rs[8], rq[8];
    const int wid = t >> 6;
    if ((t & 63) == 0) { rs[wid] = s; rq[wid] = q; }
    __syncthreads();
    if (t == 0) {
        float S = 0.f, Q = 0.f;
        const int nw = blockDim.x >> 6;
        for (int w = 0; w < nw; ++w) { S += rs[w]; Q += rq[w]; }
        float mu  = S * invN;
        float var = Q * invN - mu*mu;
        float sc  = gamma[o] * rsqrtf(var + EPS);
        scale[o] = sc;
        shift[o] = beta[o] - mu * sc;
    }
}

// ---------------------------------------------------------------- K3: BN1+relu -> conv2 (128->256) -> maxpool fg -> conv3 (512->512) pre-BN + partials
__global__ __launch_bounds__(256) void k3_conv23(
    const float* __restrict__ h1,
    const float* __restrict__ scale1, const float* __restrict__ shift1,
    const float* __restrict__ W2, const float* __restrict__ b2,
    const float* __restrict__ W3, const float* __restrict__ b3,
    float* __restrict__ h3, float* __restrict__ p3s, float* __restrict__ p3q)
{
    const int b = blockIdx.x;
    const int t = threadIdx.x;
    __shared__ float x1s[128*32];
    __shared__ float f2s[256*32];
    __shared__ float fgs[256];
    {
        const float4* src = (const float4*)(h1 + (size_t)b*4096);
        float4* dst = (float4*)x1s;
        for (int i4 = t; i4 < 1024; i4 += 256) {
            int c = i4 >> 3;
            float sc = scale1[c], sh = shift1[c];
            float4 v = src[i4];
            v.x = fmaxf(fmaf(v.x, sc, sh), 0.f);
            v.y = fmaxf(fmaf(v.y, sc, sh), 0.f);
            v.z = fmaxf(fmaf(v.z, sc, sh), 0.f);
            v.w = fmaxf(fmaf(v.w, sc, sh), 0.f);
            dst[i4] = v;
        }
    }
    __syncthreads();
    // conv2: channel o = t
    {
        float acc[32];
        const float bb = b2[t];
        #pragma unroll
        for (int l = 0; l < 32; ++l) acc[l] = bb;
        const float4* x1v = (const float4*)x1s;
        const float* wrow = W2 + t*128;
        for (int c = 0; c < 128; ++c) {
            float w = wrow[c];
            #pragma unroll
            for (int l4 = 0; l4 < 8; ++l4) {
                float4 v = x1v[c*8 + l4];
                acc[l4*4+0] = fmaf(w, v.x, acc[l4*4+0]);
                acc[l4*4+1] = fmaf(w, v.y, acc[l4*4+1]);
                acc[l4*4+2] = fmaf(w, v.z, acc[l4*4+2]);
                acc[l4*4+3] = fmaf(w, v.w, acc[l4*4+3]);
            }
        }
        float m = acc[0];
        #pragma unroll
        for (int l = 1; l < 32; ++l) m = fmaxf(m, acc[l]);
        fgs[t] = m;
        float4* f2v = (float4*)(f2s + t*32);
        #pragma unroll
        for (int l4 = 0; l4 < 8; ++l4)
            f2v[l4] = make_float4(acc[l4*4+0], acc[l4*4+1], acc[l4*4+2], acc[l4*4+3]);
    }
    __syncthreads();
    // conv3: channels o = t and t+256; first 256 inputs are fg (l-independent)
    {
        const int o0 = t, o1 = t + 256;
        const float* w0r = W3 + o0*512;
        const float* w1r = W3 + o1*512;
        float base0 = b3[o0], base1 = b3[o1];
        for (int c = 0; c < 256; ++c) {
            float g = fgs[c];
            base0 = fmaf(w0r[c], g, base0);
            base1 = fmaf(w1r[c], g, base1);
        }
        float a0[32], a1[32];
        #pragma unroll
        for (int l = 0; l < 32; ++l) { a0[l] = base0; a1[l] = base1; }
        const float4* f2v = (const float4*)f2s;
        for (int c = 0; c < 256; ++c) {
            float w0 = w0r[256 + c];
            float w1 = w1r[256 + c];
            #pragma unroll
            for (int l4 = 0; l4 < 8; ++l4) {
                float4 v = f2v[c*8 + l4];
                a0[l4*4+0] = fmaf(w0, v.x, a0[l4*4+0]);
                a0[l4*4+1] = fmaf(w0, v.y, a0[l4*4+1]);
                a0[l4*4+2] = fmaf(w0, v.z, a0[l4*4+2]);
                a0[l4*4+3] = fmaf(w0, v.w, a0[l4*4+3]);
                a1[l4*4+0] = fmaf(w1, v.x, a1[l4*4+0]);
                a1[l4*4+1] = fmaf(w1, v.y, a1[l4*4+1]);
                a1[l4*4+2] = fmaf(w1, v.z, a1[l4*4+2]);
                a1[l4*4+3] = fmaf(w1, v.w, a1[l4*4+3]);
            }
        }
        float4* d0 = (float4*)(h3 + (size_t)b*16384 + o0*32);
        float4* d1 = (float4*)(h3 + (size_t)b*16384 + o1*32);
        #pragma unroll
        for (int l4 = 0; l4 < 8; ++l4) {
            d0[l4] = make_float4(a0[l4*4+0], a0[l4*4+1], a0[l4*4+2], a0[l4*4+3]);
            d1[l4] = make_float4(a1[l4*4+0], a1[l4*4+1], a1[l4*4+2], a1[l4*4+3]);
        }
        float s0 = 0.f, q0 = 0.f, s1 = 0.f, q1 = 0.f;
        #pragma unroll
        for (int l = 0; l < 32; ++l) {
            s0 += a0[l]; q0 = fmaf(a0[l], a0[l], q0);
            s1 += a1[l]; q1 = fmaf(a1[l], a1[l], q1);
        }
        p3s[o0*1024 + b] = s0; p3q[o0*1024 + b] = q0;
        p3s[o1*1024 + b] = s1; p3q[o1*1024 + b] = q1;
    }
}

// ---------------------------------------------------------------- K5: BN3+relu -> conv4 (512->384) -> fg2, knn diff sums A, global dx partials
__global__ __launch_bounds__(192) void k5_conv4_feat(
    const float* __restrict__ h3,
    const float* __restrict__ scale3, const float* __restrict__ shift3,
    const float* __restrict__ W4, const float* __restrict__ b4,
    const int* __restrict__ idxw,
    float* __restrict__ fg2, float* __restrict__ A,
    float* __restrict__ S1p, float* __restrict__ S2p)
{
    const int b = blockIdx.x;
    const int t = threadIdx.x;
    __shared__ float xs[512*32];   // 64KB; later reused as f4 (384 rows, stride 33)
    __shared__ int idxs[256];
    __shared__ float r1[4], r2[4];
    {
        const float4* src = (const float4*)(h3 + (size_t)b*16384);
        float4* dst = (float4*)xs;
        for (int i4 = t; i4 < 4096; i4 += 192) {
            int c = i4 >> 3;
            float sc = scale3[c], sh = shift3[c];
            float4 v = src[i4];
            v.x = fmaxf(fmaf(v.x, sc, sh), 0.f);
            v.y = fmaxf(fmaf(v.y, sc, sh), 0.f);
            v.z = fmaxf(fmaf(v.z, sc, sh), 0.f);
            v.w = fmaxf(fmaf(v.w, sc, sh), 0.f);
            dst[i4] = v;
        }
    }
    for (int i = t; i < 256; i += 192) idxs[i] = idxw[b*256 + i];
    __syncthreads();
    const int o0 = t, o1 = t + 192;
    float a0[32], a1[32];
    {
        const float bb0 = b4[o0], bb1 = b4[o1];
        #pragma unroll
        for (int l = 0; l < 32; ++l) { a0[l] = bb0; a1[l] = bb1; }
        const float* w0r = W4 + o0*512;
        const float* w1r = W4 + o1*512;
        const float4* xv = (const float4*)xs;
        for (int c = 0; c < 512; ++c) {
            float w0 = w0r[c], w1 = w1r[c];
            #pragma unroll
            for (int l4 = 0; l4 < 8; ++l4) {
                float4 v = xv[c*8 + l4];
                a0[l4*4+0] = fmaf(w0, v.x, a0[l4*4+0]);
                a0[l4*4+1] = fmaf(w0, v.y, a0[l4*4+1]);
                a0[l4*4+2] = fmaf(w0, v.z, a0[l4*4+2]);
                a0[l4*4+3] = fmaf(w0, v.w, a0[l4*4+3]);
                a1[l4*4+0] = fmaf(w1, v.x, a1[l4*4+0]);
                a1[l4*4+1] = fmaf(w1, v.y, a1[l4*4+1]);
                a1[l4*4+2] = fmaf(w1, v.z, a1[l4*4+2]);
                a1[l4*4+3] = fmaf(w1, v.w, a1[l4*4+3]);
            }
        }
    }
    __syncthreads();   // all reads of xs done before overwrite
    // stash f4 rows with stride 33 (bank-conflict-free gather: bank=(o+m)%32)
    #pragma unroll
    for (int l = 0; l < 32; ++l) { xs[o0*33 + l] = a0[l]; xs[o1*33 + l] = a1[l]; }
    {
        float m0 = a0[0], m1 = a1[0];
        #pragma unroll
        for (int l = 1; l < 32; ++l) { m0 = fmaxf(m0, a0[l]); m1 = fmaxf(m1, a1[l]); }
        fg2[b*384 + o0] = m0;
        fg2[b*384 + o1] = m1;
    }
    __syncthreads();
    float A0 = 0.f, A1 = 0.f, q = 0.f;
    #pragma unroll
    for (int l = 0; l < 32; ++l) {
        float s0 = a0[l], s1 = a1[l];
        #pragma unroll
        for (int j = 0; j < 8; ++j) {
            int m = idxs[l*8 + j];
            float v0 = xs[o0*33 + m] - s0;
            float v1 = xs[o1*33 + m] - s1;
            A0 += v0; A1 += v1;
            q = fmaf(v0, v0, q); q = fmaf(v1, v1, q);
        }
    }
    A[b*384 + o0] = A0;
    A[b*384 + o1] = A1;
    float sc = A0 + A1;
    #pragma unroll
    for (int off = 32; off > 0; off >>= 1) {
        sc += __shfl_down(sc, off, 64);
        q  += __shfl_down(q,  off, 64);
    }
    const int wid = t >> 6;
    if ((t & 63) == 0) { r1[wid] = sc; r2[wid] = q; }
    __syncthreads();
    if (t == 0) {
        S1p[b] = r1[0] + r1[1] + r1[2];
        S2p[b] = r2[0] + r2[1] + r2[2];
    }
}

// ---------------------------------------------------------------- K6: global std over dx (ddof=1)
__global__ void k6_std(const float* __restrict__ S1p, const float* __restrict__ S2p,
                       float* __restrict__ stdv)
{
    const int t = threadIdx.x;
    double s = 0.0, q = 0.0;
    for (int i = t; i < 1024; i += 256) { s += (double)S1p[i]; q += (double)S2p[i]; }
    #pragma unroll
    for (int off = 32; off > 0; off >>= 1) {
        s += __shfl_down(s, off, 64);
        q += __shfl_down(q, off, 64);
    }
    __shared__ double rs[4], rq[4];
    const int wid = t >> 6;
    if ((t & 63) == 0) { rs[wid] = s; rq[wid] = q; }
    __syncthreads();
    if (t == 0) {
        double S = rs[0]+rs[1]+rs[2]+rs[3];
        double Q = rq[0]+rq[1]+rq[2]+rq[3];
        const double N = 1024.0 * 32.0 * 8.0 * 384.0;
        double var = (Q - S*S/N) / (N - 1.0);
        stdv[0] = (float)sqrt(var);
    }
}

// ---------------------------------------------------------------- K7: fused head GEMM (1024 x 384, K=768) pre-BN + partials
__global__ __launch_bounds__(384) void k7_fused(
    const float* __restrict__ fg2, const float* __restrict__ A,
    const float* __restrict__ alpha, const float* __restrict__ beta_aff,
    const float* __restrict__ stdv,
    const float* __restrict__ Wf, const float* __restrict__ bf,
    float* __restrict__ hf, float* __restrict__ pfs, float* __restrict__ pfq)
{
    const int blk = blockIdx.x;
    const int b0 = blk * 16;
    const int t = threadIdx.x;
    __shared__ float xf[16*768];
    const float inv = 1.f / (256.f * (stdv[0] + EPS));
    for (int bb = 0; bb < 16; ++bb) {
        for (int c = t; c < 768; c += 384) {
            float v;
            if (c < 384) v = fg2[(b0+bb)*384 + c];
            else {
                int cc = c - 384;
                v = fmaf(alpha[cc] * inv, A[(b0+bb)*384 + cc], beta_aff[cc]);
            }
            xf[bb*768 + c] = v;
        }
    }
    __syncthreads();
    const int o = t;
    float acc[16];
    const float bb0 = bf[o];
    #pragma unroll
    for (int i = 0; i < 16; ++i) acc[i] = bb0;
    const float4* wv = (const float4*)(Wf + o*768);
    const float4* xv = (const float4*)xf;
    for (int c4 = 0; c4 < 192; ++c4) {
        float4 w = wv[c4];
        #pragma unroll
        for (int i = 0; i < 16; ++i) {
            float4 x = xv[i*192 + c4];
            acc[i] = fmaf(w.x, x.x, acc[i]);
            acc[i] = fmaf(w.y, x.y, acc[i]);
            acc[i] = fmaf(w.z, x.z, acc[i]);
            acc[i] = fmaf(w.w, x.w, acc[i]);
        }
    }
    float s = 0.f, q = 0.f;
    #pragma unroll
    for (int i = 0; i < 16; ++i) {
        hf[(size_t)(b0+i)*384 + o] = acc[i];
        s += acc[i]; q = fmaf(acc[i], acc[i], q);
    }
    pfs[o*64 + blk] = s;
    pfq[o*64 + blk] = q;
}

// ---------------------------------------------------------------- K9: BNf + relu -> out
__global__ __launch_bounds__(384) void k9_out(
    const float* __restrict__ hf, const float* __restrict__ scalef,
    const float* __restrict__ shiftf, float* __restrict__ out)
{
    const int b = blockIdx.x, t = threadIdx.x;
    float v = fmaf(hf[(size_t)b*384 + t], scalef[t], shiftf[t]);
    out[(size_t)b*384 + t] = fmaxf(v, 0.f);
}

extern "C" void kernel_launch(void* const* d_in, const int* in_sizes, int n_in,
                              void* d_out, int out_size, void* d_ws, size_t ws_size,
                              hipStream_t stream) {
    const float* pg      = (const float*)d_in[0];
    const float* W1      = (const float*)d_in[1];
    const float* b1      = (const float*)d_in[2];
    const float* gamma1  = (const float*)d_in[3];
    const float* beta1   = (const float*)d_in[4];
    const float* W2      = (const float*)d_in[5];
    const float* b2      = (const float*)d_in[6];
    const float* W3      = (const float*)d_in[7];
    const float* b3      = (const float*)d_in[8];
    const float* gamma3  = (const float*)d_in[9];
    const float* beta3   = (const float*)d_in[10];
    const float* W4      = (const float*)d_in[11];
    const float* b4      = (const float*)d_in[12];
    const float* alpha   = (const float*)d_in[13];
    const float* beta_af = (const float*)d_in[14];
    const float* Wf      = (const float*)d_in[15];
    const float* bf      = (const float*)d_in[16];
    const float* gammaf  = (const float*)d_in[17];
    const float* betaf   = (const float*)d_in[18];
    float* out = (float*)d_out;

    float* w = (float*)d_ws;
    float* h1     = w;  w += 1024*128*32;   // 16 MB
    float* h3     = w;  w += 1024*512*32;   // 64 MB
    float* hf     = w;  w += 1024*384;
    float* fg2    = w;  w += 1024*384;
    float* A      = w;  w += 1024*384;
    float* p1s    = w;  w += 128*1024;
    float* p1q    = w;  w += 128*1024;
    float* p3s    = w;  w += 512*1024;
    float* p3q    = w;  w += 512*1024;
    float* pfs    = w;  w += 384*64;
    float* pfq    = w;  w += 384*64;
    float* S1p    = w;  w += 1024;
    float* S2p    = w;  w += 1024;
    float* scale1 = w;  w += 128;
    float* shift1 = w;  w += 128;
    float* scale3 = w;  w += 512;
    float* shift3 = w;  w += 512;
    float* scalef = w;  w += 384;
    float* shiftf = w;  w += 384;
    float* stdv   = w;  w += 4;
    int*   idxw   = (int*)w;  w += 1024*256;

    hipLaunchKernelGGL(k1_conv1_knn, dim3(1024), dim3(128), 0, stream,
                       pg, W1, b1, h1, p1s, p1q, idxw);
    hipLaunchKernelGGL(k_bn_fin, dim3(128), dim3(256), 0, stream,
                       p1s, p1q, 1024, 1.f/32768.f, gamma1, beta1, scale1, shift1);
    hipLaunchKernelGGL(k3_conv23, dim3(1024), dim3(256), 0, stream,
                       h1, scale1, shift1, W2, b2, W3, b3, h3, p3s, p3q);
    hipLaunchKernelGGL(k_bn_fin, dim3(512), dim3(256), 0, stream,
                       p3s, p3q, 1024, 1.f/32768.f, gamma3, beta3, scale3, shift3);
    hipLaunchKernelGGL(k5_conv4_feat, dim3(1024), dim3(192), 0, stream,
                       h3, scale3, shift3, W4, b4, idxw, fg2, A, S1p, S2p);
    hipLaunchKernelGGL(k6_std, dim3(1), dim3(256), 0, stream, S1p, S2p, stdv);
    hipLaunchKernelGGL(k7_fused, dim3(64), dim3(384), 0, stream,
                       fg2, A, alpha, beta_af, stdv, Wf, bf, hf, pfs, pfq);
    hipLaunchKernelGGL(k_bn_fin, dim3(384), dim3(256), 0, stream,
                       pfs, pfq, 64, 1.f/1024.f, gammaf, betaf, scalef, shiftf);
    hipLaunchKernelGGL(k9_out, dim3(1024), dim3(384), 0, stream,
                       hf, scalef, shiftf, out);
}

// Round 2
// 399.243 us; speedup vs baseline: 2.6557x; 2.6557x over previous
//
#include <hip/hip_runtime.h>
#include <math.h>

#define EPS 1e-5f

typedef __attribute__((ext_vector_type(8))) short s16x8;   // 8 bf16 (4 VGPRs)
typedef __attribute__((ext_vector_type(4))) float f32x4;   // MFMA C/D

__device__ __forceinline__ unsigned short f2bf(float x) {
    unsigned u = __float_as_uint(x);
    u += 0x7fffu + ((u >> 16) & 1u);           // round-to-nearest-even
    return (unsigned short)(u >> 16);
}
__device__ __forceinline__ float bf2f(unsigned short h) {
    return __uint_as_float(((unsigned)h) << 16);
}
__device__ __forceinline__ unsigned long long pack4bf(float a, float b, float c, float d) {
    return (unsigned long long)f2bf(a)
         | ((unsigned long long)f2bf(b) << 16)
         | ((unsigned long long)f2bf(c) << 32)
         | ((unsigned long long)f2bf(d) << 48);
}

// ---------------------------------------------------------------- kprep: fp32 weights -> bf16
__global__ __launch_bounds__(256) void kprep(
    const float* __restrict__ W2, const float* __restrict__ W3, const float* __restrict__ W4,
    unsigned short* __restrict__ W2b, unsigned short* __restrict__ W3b, unsigned short* __restrict__ W4b)
{
    int i = blockIdx.x * 256 + threadIdx.x;
    if (i < 32768)  W2b[i] = f2bf(W2[i]);
    if (i < 262144) W3b[i] = f2bf(W3[i]);
    if (i < 196608) W4b[i] = f2bf(W4[i]);
}

// ---------------------------------------------------------------- K1: conv1 (3->128) pre-BN + partial stats + knn indices
// h1 layout: [b][l][c]  (coalesced write across t, contiguous staging in k3)
__global__ __launch_bounds__(128) void k1_conv1_knn(
    const float* __restrict__ pg, const float* __restrict__ W1,
    const float* __restrict__ b1,
    float* __restrict__ h1, float* __restrict__ p1s, float* __restrict__ p1q,
    int* __restrict__ idxw)
{
    const int b = blockIdx.x;
    const int t = threadIdx.x;
    __shared__ float pgs[96];
    __shared__ float sqs[32];
    if (t < 96) pgs[t] = pg[b * 96 + t];
    __syncthreads();
    if (t < 32) {
        float x = pgs[t*3+0], y = pgs[t*3+1], z = pgs[t*3+2];
        sqs[t] = x*x + y*y + z*z;
    }
    __syncthreads();
    {
        const float w0 = W1[t*3+0], w1 = W1[t*3+1], w2 = W1[t*3+2];
        const float bb = b1[t];
        float s = 0.f, q = 0.f;
        float* hcol = h1 + (size_t)b*4096 + t;
        #pragma unroll
        for (int l = 0; l < 32; ++l) {
            float v = fmaf(w2, pgs[l*3+2], fmaf(w1, pgs[l*3+1], fmaf(w0, pgs[l*3+0], bb)));
            hcol[l*128] = v; s += v; q += v*v;
        }
        p1s[t*1024 + b] = s;
        p1q[t*1024 + b] = q;
    }
    if (t < 32) {
        const float xl = pgs[t*3+0], yl = pgs[t*3+1], zl = pgs[t*3+2];
        const float sql = sqs[t];
        float dist[32];
        #pragma unroll
        for (int m = 0; m < 32; ++m) {
            float dot = xl*pgs[m*3+0] + yl*pgs[m*3+1] + zl*pgs[m*3+2];
            dist[m] = sql + sqs[m] - 2.f*dot;
        }
        unsigned used = 0u;
        int* orow = idxw + b*256 + t*8;
        #pragma unroll
        for (int j = 0; j < 8; ++j) {
            float best = 3.4e38f; int bi = 0;
            #pragma unroll
            for (int m = 0; m < 32; ++m) {
                if (!((used >> m) & 1u) && dist[m] < best) { best = dist[m]; bi = m; }
            }
            used |= (1u << bi);
            orow[j] = bi;
        }
    }
}

// ---------------------------------------------------------------- BN finalize (one block per channel)
__global__ void k_bn_fin(const float* __restrict__ ps, const float* __restrict__ pq,
                         int nPart, float invN,
                         const float* __restrict__ gamma, const float* __restrict__ beta,
                         float* __restrict__ scale, float* __restrict__ shift)
{
    const int o = blockIdx.x;
    const int t = threadIdx.x;
    float s = 0.f, q = 0.f;
    for (int i = t; i < nPart; i += blockDim.x) {
        s += ps[o*nPart + i];
        q += pq[o*nPart + i];
    }
    #pragma unroll
    for (int off = 32; off > 0; off >>= 1) {
        s += __shfl_down(s, off, 64);
        q += __shfl_down(q, off, 64);
    }
    __shared__ float rs[8], rq[8];
    const int wid = t >> 6;
    if ((t & 63) == 0) { rs[wid] = s; rq[wid] = q; }
    __syncthreads();
    if (t == 0) {
        float S = 0.f, Q = 0.f;
        const int nw = blockDim.x >> 6;
        for (int w = 0; w < nw; ++w) { S += rs[w]; Q += rq[w]; }
        float mu  = S * invN;
        float var = Q * invN - mu*mu;
        float sc  = gamma[o] * rsqrtf(var + EPS);
        scale[o] = sc;
        shift[o] = beta[o] - mu * sc;
    }
}

// ---------------------------------------------------------------- K3: MFMA conv2 (128->256) + fg + MFMA conv3 (512->512)
// grid 1024, block 256 (4 waves). h3b output bf16 [b][l][o].
__global__ __launch_bounds__(256) void k3_mfma(
    const float* __restrict__ h1,
    const float* __restrict__ scale1, const float* __restrict__ shift1,
    const unsigned short* __restrict__ W2b, const float* __restrict__ b2,
    const unsigned short* __restrict__ W3b, const float* __restrict__ b3,
    unsigned short* __restrict__ h3b, float* __restrict__ p3s, float* __restrict__ p3q)
{
    const int b = blockIdx.x;
    const int t = threadIdx.x;
    __shared__ __align__(16) unsigned short B1[32*136];   // x1 bf16 [l][c], stride 136
    __shared__ __align__(16) unsigned short B3[32*520];   // concat[fg,f2] bf16 [l][c], stride 520

    // ---- stage x1 = relu(BN1(h1)) as bf16 [l][c]
    {
        const int l = t >> 3, c0 = (t & 7) * 16;
        const float4* src = (const float4*)(h1 + (size_t)b*4096 + l*128 + c0);
        #pragma unroll
        for (int i = 0; i < 4; ++i) {
            float4 v = src[i];
            int c = c0 + i*4;
            float e0 = fmaxf(fmaf(v.x, scale1[c+0], shift1[c+0]), 0.f);
            float e1 = fmaxf(fmaf(v.y, scale1[c+1], shift1[c+1]), 0.f);
            float e2 = fmaxf(fmaf(v.z, scale1[c+2], shift1[c+2]), 0.f);
            float e3 = fmaxf(fmaf(v.w, scale1[c+3], shift1[c+3]), 0.f);
            *(unsigned long long*)&B1[l*136 + c] = pack4bf(e0, e1, e2, e3);
        }
    }
    __syncthreads();

    const int wave = t >> 6;
    const int lane = t & 63;
    const int m    = lane & 15;
    const int quad = lane >> 4;

    // ---- conv2: M=256 (wave: 4 M-tiles), N=32 (2 N-tiles), K=128
    f32x4 acc2[4][2];
    #pragma unroll
    for (int mt = 0; mt < 4; ++mt)
        #pragma unroll
        for (int n = 0; n < 2; ++n)
            acc2[mt][n] = (f32x4){0.f, 0.f, 0.f, 0.f};

    #pragma unroll
    for (int kt = 0; kt < 4; ++kt) {
        s16x8 bv0 = *(const s16x8*)&B1[ m      *136 + kt*32 + quad*8];
        s16x8 bv1 = *(const s16x8*)&B1[(m+16)  *136 + kt*32 + quad*8];
        #pragma unroll
        for (int mt = 0; mt < 4; ++mt) {
            const int o = wave*64 + mt*16 + m;
            s16x8 av = *(const s16x8*)(W2b + (size_t)o*128 + kt*32 + quad*8);
            acc2[mt][0] = __builtin_amdgcn_mfma_f32_16x16x32_bf16(av, bv0, acc2[mt][0], 0, 0, 0);
            acc2[mt][1] = __builtin_amdgcn_mfma_f32_16x16x32_bf16(av, bv1, acc2[mt][1], 0, 0, 0);
        }
    }
    // bias + fg + write B3
    #pragma unroll
    for (int mt = 0; mt < 4; ++mt) {
        const int o0 = wave*64 + mt*16 + quad*4;
        #pragma unroll
        for (int r = 0; r < 4; ++r) {
            float bb = b2[o0 + r];
            acc2[mt][0][r] += bb;
            acc2[mt][1][r] += bb;
        }
        // f2 part (rows 256..511 of concat)
        #pragma unroll
        for (int n = 0; n < 2; ++n) {
            const int l = n*16 + m;
            *(unsigned long long*)&B3[l*520 + 256 + o0] =
                pack4bf(acc2[mt][n][0], acc2[mt][n][1], acc2[mt][n][2], acc2[mt][n][3]);
        }
        // fg part (rows 0..255), replicated over all 32 l
        float fx[4];
        #pragma unroll
        for (int r = 0; r < 4; ++r) fx[r] = fmaxf(acc2[mt][0][r], acc2[mt][1][r]);
        #pragma unroll
        for (int msk = 1; msk < 16; msk <<= 1)
            #pragma unroll
            for (int r = 0; r < 4; ++r) fx[r] = fmaxf(fx[r], __shfl_xor(fx[r], msk, 16));
        unsigned long long pk = pack4bf(fx[0], fx[1], fx[2], fx[3]);
        *(unsigned long long*)&B3[ m      *520 + o0] = pk;
        *(unsigned long long*)&B3[(m+16)  *520 + o0] = pk;
    }
    __syncthreads();

    // ---- conv3: M=512 (wave: 8 M-tiles), N=32 (2 N-tiles), K=512
    f32x4 acc3[8][2];
    #pragma unroll
    for (int mt = 0; mt < 8; ++mt)
        #pragma unroll
        for (int n = 0; n < 2; ++n)
            acc3[mt][n] = (f32x4){0.f, 0.f, 0.f, 0.f};

    for (int kt = 0; kt < 16; ++kt) {
        s16x8 bv0 = *(const s16x8*)&B3[ m      *520 + kt*32 + quad*8];
        s16x8 bv1 = *(const s16x8*)&B3[(m+16)  *520 + kt*32 + quad*8];
        #pragma unroll
        for (int mt = 0; mt < 8; ++mt) {
            const int o = wave*128 + mt*16 + m;
            s16x8 av = *(const s16x8*)(W3b + (size_t)o*512 + kt*32 + quad*8);
            acc3[mt][0] = __builtin_amdgcn_mfma_f32_16x16x32_bf16(av, bv0, acc3[mt][0], 0, 0, 0);
            acc3[mt][1] = __builtin_amdgcn_mfma_f32_16x16x32_bf16(av, bv1, acc3[mt][1], 0, 0, 0);
        }
    }
    // bias + store h3b (bf16 [l][o]) + stats
    #pragma unroll
    for (int mt = 0; mt < 8; ++mt) {
        const int o0 = wave*128 + mt*16 + quad*4;
        float s[4], q[4];
        #pragma unroll
        for (int r = 0; r < 4; ++r) {
            float bb = b3[o0 + r];
            acc3[mt][0][r] += bb;
            acc3[mt][1][r] += bb;
            s[r] = acc3[mt][0][r] + acc3[mt][1][r];
            q[r] = acc3[mt][0][r]*acc3[mt][0][r] + acc3[mt][1][r]*acc3[mt][1][r];
        }
        #pragma unroll
        for (int n = 0; n < 2; ++n) {
            const int l = n*16 + m;
            *(unsigned long long*)(h3b + (size_t)b*16384 + l*512 + o0) =
                pack4bf(acc3[mt][n][0], acc3[mt][n][1], acc3[mt][n][2], acc3[mt][n][3]);
        }
        #pragma unroll
        for (int msk = 1; msk < 16; msk <<= 1)
            #pragma unroll
            for (int r = 0; r < 4; ++r) {
                s[r] += __shfl_xor(s[r], msk, 16);
                q[r] += __shfl_xor(q[r], msk, 16);
            }
        if (m == 0) {
            #pragma unroll
            for (int r = 0; r < 4; ++r) {
                p3s[(size_t)(o0 + r)*1024 + b] = s[r];
                p3q[(size_t)(o0 + r)*1024 + b] = q[r];
            }
        }
    }
}

// ---------------------------------------------------------------- K5: MFMA conv4 (512->384) + fg2 + knn feature branch
// grid 1024, block 384 (6 waves).
__global__ __launch_bounds__(384) void k5_mfma(
    const unsigned short* __restrict__ h3b,
    const float* __restrict__ scale3, const float* __restrict__ shift3,
    const unsigned short* __restrict__ W4b, const float* __restrict__ b4,
    const int* __restrict__ idxw,
    float* __restrict__ fg2, float* __restrict__ A,
    float* __restrict__ S1p, float* __restrict__ S2p)
{
    const int b = blockIdx.x;
    const int t = threadIdx.x;
    __shared__ __align__(16) float smem[12672];      // union: B4 (33.3KB bf16) then f4s fp32 [o][33]
    unsigned short* B4 = (unsigned short*)smem;       // [l][c] stride 520
    float* f4s = smem;
    __shared__ int idxs[256];
    __shared__ float r1[6], r2[6];

    // ---- stage x3 = relu(BN3(h3b)) as bf16 [l][c]
    for (int i = t; i < 2048; i += 384) {
        const int l = i >> 6, c8 = (i & 63) * 8;
        s16x8 hv = *(const s16x8*)(h3b + (size_t)b*16384 + l*512 + c8);
        unsigned short ov[8];
        #pragma unroll
        for (int e = 0; e < 8; ++e) {
            int c = c8 + e;
            float v = fmaxf(fmaf(bf2f((unsigned short)hv[e]), scale3[c], shift3[c]), 0.f);
            ov[e] = f2bf(v);
        }
        uint4 o4;
        o4.x = (unsigned)ov[0] | ((unsigned)ov[1] << 16);
        o4.y = (unsigned)ov[2] | ((unsigned)ov[3] << 16);
        o4.z = (unsigned)ov[4] | ((unsigned)ov[5] << 16);
        o4.w = (unsigned)ov[6] | ((unsigned)ov[7] << 16);
        *(uint4*)&B4[l*520 + c8] = o4;
    }
    for (int i = t; i < 256; i += 384) idxs[i] = idxw[b*256 + i];
    __syncthreads();

    const int wave = t >> 6;
    const int lane = t & 63;
    const int m    = lane & 15;
    const int quad = lane >> 4;

    // ---- conv4: M=384 (wave: 4 M-tiles), N=32 (2 N-tiles), K=512
    f32x4 acc4[4][2];
    #pragma unroll
    for (int mt = 0; mt < 4; ++mt)
        #pragma unroll
        for (int n = 0; n < 2; ++n)
            acc4[mt][n] = (f32x4){0.f, 0.f, 0.f, 0.f};

    for (int kt = 0; kt < 16; ++kt) {
        s16x8 bv0 = *(const s16x8*)&B4[ m      *520 + kt*32 + quad*8];
        s16x8 bv1 = *(const s16x8*)&B4[(m+16)  *520 + kt*32 + quad*8];
        #pragma unroll
        for (int mt = 0; mt < 4; ++mt) {
            const int o = wave*64 + mt*16 + m;
            s16x8 av = *(const s16x8*)(W4b + (size_t)o*512 + kt*32 + quad*8);
            acc4[mt][0] = __builtin_amdgcn_mfma_f32_16x16x32_bf16(av, bv0, acc4[mt][0], 0, 0, 0);
            acc4[mt][1] = __builtin_amdgcn_mfma_f32_16x16x32_bf16(av, bv1, acc4[mt][1], 0, 0, 0);
        }
    }
    // bias + fg2
    #pragma unroll
    for (int mt = 0; mt < 4; ++mt) {
        const int o0 = wave*64 + mt*16 + quad*4;
        float fx[4];
        #pragma unroll
        for (int r = 0; r < 4; ++r) {
            float bb = b4[o0 + r];
            acc4[mt][0][r] += bb;
            acc4[mt][1][r] += bb;
            fx[r] = fmaxf(acc4[mt][0][r], acc4[mt][1][r]);
        }
        #pragma unroll
        for (int msk = 1; msk < 16; msk <<= 1)
            #pragma unroll
            for (int r = 0; r < 4; ++r) fx[r] = fmaxf(fx[r], __shfl_xor(fx[r], msk, 16));
        if (m == 0) {
            #pragma unroll
            for (int r = 0; r < 4; ++r) fg2[b*384 + o0 + r] = fx[r];
        }
    }
    __syncthreads();   // done reading B4; smem becomes f4s

    // ---- spill feat to LDS fp32 [o][l], stride 33 (bank = (o+l)%32)
    #pragma unroll
    for (int mt = 0; mt < 4; ++mt) {
        const int o0 = wave*64 + mt*16 + quad*4;
        #pragma unroll
        for (int n = 0; n < 2; ++n) {
            const int l = n*16 + m;
            #pragma unroll
            for (int r = 0; r < 4; ++r) f4s[(o0 + r)*33 + l] = acc4[mt][n][r];
        }
    }
    __syncthreads();

    // ---- knn branch: per-thread o = t
    {
        const float* row = &f4s[t*33];
        float A0 = 0.f, qq = 0.f;
        #pragma unroll
        for (int l = 0; l < 32; ++l) {
            const float sl = row[l];
            const int* ir = &idxs[l*8];
            #pragma unroll
            for (int j = 0; j < 8; ++j) {
                float v = row[ir[j]] - sl;
                A0 += v; qq = fmaf(v, v, qq);
            }
        }
        A[b*384 + t] = A0;
        float sA = A0, sQ = qq;
        #pragma unroll
        for (int off = 32; off > 0; off >>= 1) {
            sA += __shfl_down(sA, off, 64);
            sQ += __shfl_down(sQ, off, 64);
        }
        if (lane == 0) { r1[wave] = sA; r2[wave] = sQ; }
    }
    __syncthreads();
    if (t == 0) {
        S1p[b] = r1[0]+r1[1]+r1[2]+r1[3]+r1[4]+r1[5];
        S2p[b] = r2[0]+r2[1]+r2[2]+r2[3]+r2[4]+r2[5];
    }
}

// ---------------------------------------------------------------- K6: global std over dx (ddof=1)
__global__ void k6_std(const float* __restrict__ S1p, const float* __restrict__ S2p,
                       float* __restrict__ stdv)
{
    const int t = threadIdx.x;
    double s = 0.0, q = 0.0;
    for (int i = t; i < 1024; i += 256) { s += (double)S1p[i]; q += (double)S2p[i]; }
    #pragma unroll
    for (int off = 32; off > 0; off >>= 1) {
        s += __shfl_down(s, off, 64);
        q += __shfl_down(q, off, 64);
    }
    __shared__ double rs[4], rq[4];
    const int wid = t >> 6;
    if ((t & 63) == 0) { rs[wid] = s; rq[wid] = q; }
    __syncthreads();
    if (t == 0) {
        double S = rs[0]+rs[1]+rs[2]+rs[3];
        double Q = rq[0]+rq[1]+rq[2]+rq[3];
        const double N = 1024.0 * 32.0 * 8.0 * 384.0;
        double var = (Q - S*S/N) / (N - 1.0);
        stdv[0] = (float)sqrt(var);
    }
}

// ---------------------------------------------------------------- K7: fused head GEMM (1024 x 384, K=768) pre-BN + partials
__global__ __launch_bounds__(384) void k7_fused(
    const float* __restrict__ fg2, const float* __restrict__ A,
    const float* __restrict__ alpha, const float* __restrict__ beta_aff,
    const float* __restrict__ stdv,
    const float* __restrict__ Wf, const float* __restrict__ bf,
    float* __restrict__ hf, float* __restrict__ pfs, float* __restrict__ pfq)
{
    const int blk = blockIdx.x;
    const int b0 = blk * 16;
    const int t = threadIdx.x;
    __shared__ float xf[16*768];
    const float inv = 1.f / (256.f * (stdv[0] + EPS));
    for (int bb = 0; bb < 16; ++bb) {
        for (int c = t; c < 768; c += 384) {
            float v;
            if (c < 384) v = fg2[(b0+bb)*384 + c];
            else {
                int cc = c - 384;
                v = fmaf(alpha[cc] * inv, A[(b0+bb)*384 + cc], beta_aff[cc]);
            }
            xf[bb*768 + c] = v;
        }
    }
    __syncthreads();
    const int o = t;
    float acc[16];
    const float bb0 = bf[o];
    #pragma unroll
    for (int i = 0; i < 16; ++i) acc[i] = bb0;
    const float4* wv = (const float4*)(Wf + o*768);
    const float4* xv = (const float4*)xf;
    for (int c4 = 0; c4 < 192; ++c4) {
        float4 w = wv[c4];
        #pragma unroll
        for (int i = 0; i < 16; ++i) {
            float4 x = xv[i*192 + c4];
            acc[i] = fmaf(w.x, x.x, acc[i]);
            acc[i] = fmaf(w.y, x.y, acc[i]);
            acc[i] = fmaf(w.z, x.z, acc[i]);
            acc[i] = fmaf(w.w, x.w, acc[i]);
        }
    }
    float s = 0.f, q = 0.f;
    #pragma unroll
    for (int i = 0; i < 16; ++i) {
        hf[(size_t)(b0+i)*384 + o] = acc[i];
        s += acc[i]; q = fmaf(acc[i], acc[i], q);
    }
    pfs[o*64 + blk] = s;
    pfq[o*64 + blk] = q;
}

// ---------------------------------------------------------------- K9: BNf + relu -> out
__global__ __launch_bounds__(384) void k9_out(
    const float* __restrict__ hf, const float* __restrict__ scalef,
    const float* __restrict__ shiftf, float* __restrict__ out)
{
    const int b = blockIdx.x, t = threadIdx.x;
    float v = fmaf(hf[(size_t)b*384 + t], scalef[t], shiftf[t]);
    out[(size_t)b*384 + t] = fmaxf(v, 0.f);
}

extern "C" void kernel_launch(void* const* d_in, const int* in_sizes, int n_in,
                              void* d_out, int out_size, void* d_ws, size_t ws_size,
                              hipStream_t stream) {
    const float* pg      = (const float*)d_in[0];
    const float* W1      = (const float*)d_in[1];
    const float* b1      = (const float*)d_in[2];
    const float* gamma1  = (const float*)d_in[3];
    const float* beta1   = (const float*)d_in[4];
    const float* W2      = (const float*)d_in[5];
    const float* b2      = (const float*)d_in[6];
    const float* W3      = (const float*)d_in[7];
    const float* b3      = (const float*)d_in[8];
    const float* gamma3  = (const float*)d_in[9];
    const float* beta3   = (const float*)d_in[10];
    const float* W4      = (const float*)d_in[11];
    const float* b4      = (const float*)d_in[12];
    const float* alpha   = (const float*)d_in[13];
    const float* beta_af = (const float*)d_in[14];
    const float* Wf      = (const float*)d_in[15];
    const float* bf      = (const float*)d_in[16];
    const float* gammaf  = (const float*)d_in[17];
    const float* betaf   = (const float*)d_in[18];
    float* out = (float*)d_out;

    float* w = (float*)d_ws;
    float* h1     = w;  w += 1024*4096;            // 16 MB, [b][l][c]
    unsigned short* h3b = (unsigned short*)w; w += 1024*16384/2;  // 32 MB bf16 [b][l][o]
    unsigned short* W2b = (unsigned short*)w; w += 32768/2;
    unsigned short* W3b = (unsigned short*)w; w += 262144/2;
    unsigned short* W4b = (unsigned short*)w; w += 196608/2;
    float* hf     = w;  w += 1024*384;
    float* fg2    = w;  w += 1024*384;
    float* A      = w;  w += 1024*384;
    float* p1s    = w;  w += 128*1024;
    float* p1q    = w;  w += 128*1024;
    float* p3s    = w;  w += 512*1024;
    float* p3q    = w;  w += 512*1024;
    float* pfs    = w;  w += 384*64;
    float* pfq    = w;  w += 384*64;
    float* S1p    = w;  w += 1024;
    float* S2p    = w;  w += 1024;
    float* scale1 = w;  w += 128;
    float* shift1 = w;  w += 128;
    float* scale3 = w;  w += 512;
    float* shift3 = w;  w += 512;
    float* scalef = w;  w += 384;
    float* shiftf = w;  w += 384;
    float* stdv   = w;  w += 4;
    int*   idxw   = (int*)w;  w += 1024*256;

    hipLaunchKernelGGL(kprep, dim3(1024), dim3(256), 0, stream, W2, W3, W4, W2b, W3b, W4b);
    hipLaunchKernelGGL(k1_conv1_knn, dim3(1024), dim3(128), 0, stream,
                       pg, W1, b1, h1, p1s, p1q, idxw);
    hipLaunchKernelGGL(k_bn_fin, dim3(128), dim3(256), 0, stream,
                       p1s, p1q, 1024, 1.f/32768.f, gamma1, beta1, scale1, shift1);
    hipLaunchKernelGGL(k3_mfma, dim3(1024), dim3(256), 0, stream,
                       h1, scale1, shift1, W2b, b2, W3b, b3, h3b, p3s, p3q);
    hipLaunchKernelGGL(k_bn_fin, dim3(512), dim3(256), 0, stream,
                       p3s, p3q, 1024, 1.f/32768.f, gamma3, beta3, scale3, shift3);
    hipLaunchKernelGGL(k5_mfma, dim3(1024), dim3(384), 0, stream,
                       h3b, scale3, shift3, W4b, b4, idxw, fg2, A, S1p, S2p);
    hipLaunchKernelGGL(k6_std, dim3(1), dim3(256), 0, stream, S1p, S2p, stdv);
    hipLaunchKernelGGL(k7_fused, dim3(64), dim3(384), 0, stream,
                       fg2, A, alpha, beta_af, stdv, Wf, bf, hf, pfs, pfq);
    hipLaunchKernelGGL(k_bn_fin, dim3(384), dim3(256), 0, stream,
                       pfs, pfq, 64, 1.f/1024.f, gammaf, betaf, scalef, shiftf);
    hipLaunchKernelGGL(k9_out, dim3(1024), dim3(384), 0, stream,
                       hf, scalef, shiftf, out);
}

// Round 3
// 331.982 us; speedup vs baseline: 3.1937x; 1.2026x over previous
//
#include <hip/hip_runtime.h>
#include <math.h>

#define EPS 1e-5f

typedef __attribute__((ext_vector_type(8))) short s16x8;   // 8 bf16 (4 VGPRs)
typedef __attribute__((ext_vector_type(4))) float f32x4;   // MFMA C/D

__device__ __forceinline__ unsigned short f2bf(float x) {
    unsigned u = __float_as_uint(x);
    u += 0x7fffu + ((u >> 16) & 1u);           // round-to-nearest-even
    return (unsigned short)(u >> 16);
}
__device__ __forceinline__ float bf2f(unsigned short h) {
    return __uint_as_float(((unsigned)h) << 16);
}
__device__ __forceinline__ unsigned long long pack4bf(float a, float b, float c, float d) {
    return (unsigned long long)f2bf(a)
         | ((unsigned long long)f2bf(b) << 16)
         | ((unsigned long long)f2bf(c) << 32)
         | ((unsigned long long)f2bf(d) << 48);
}

// ---------------------------------------------------------------- kprep: fp32 weights -> bf16
__global__ __launch_bounds__(256) void kprep(
    const float* __restrict__ W2, const float* __restrict__ W3, const float* __restrict__ W4,
    unsigned short* __restrict__ W2b, unsigned short* __restrict__ W3b, unsigned short* __restrict__ W4b)
{
    int i = blockIdx.x * 256 + threadIdx.x;
    if (i < 32768)  W2b[i] = f2bf(W2[i]);
    if (i < 262144) W3b[i] = f2bf(W3[i]);
    if (i < 196608) W4b[i] = f2bf(W4[i]);
}

// ---------------------------------------------------------------- K1: conv1 (3->128) pre-BN + partial stats + knn indices
// h1 layout: [b][l][c]; p1s/p1q layout [b][c] (coalesced)
__global__ __launch_bounds__(128) void k1_conv1_knn(
    const float* __restrict__ pg, const float* __restrict__ W1,
    const float* __restrict__ b1,
    float* __restrict__ h1, float* __restrict__ p1s, float* __restrict__ p1q,
    int* __restrict__ idxw)
{
    const int b = blockIdx.x;
    const int t = threadIdx.x;
    __shared__ float pgs[96];
    __shared__ float sqs[32];
    if (t < 96) pgs[t] = pg[b * 96 + t];
    __syncthreads();
    if (t < 32) {
        float x = pgs[t*3+0], y = pgs[t*3+1], z = pgs[t*3+2];
        sqs[t] = x*x + y*y + z*z;
    }
    __syncthreads();
    {
        const float w0 = W1[t*3+0], w1 = W1[t*3+1], w2 = W1[t*3+2];
        const float bb = b1[t];
        float s = 0.f, q = 0.f;
        float* hcol = h1 + (size_t)b*4096 + t;
        #pragma unroll
        for (int l = 0; l < 32; ++l) {
            float v = fmaf(w2, pgs[l*3+2], fmaf(w1, pgs[l*3+1], fmaf(w0, pgs[l*3+0], bb)));
            hcol[l*128] = v; s += v; q += v*v;
        }
        p1s[b*128 + t] = s;
        p1q[b*128 + t] = q;
    }
    if (t < 32) {
        const float xl = pgs[t*3+0], yl = pgs[t*3+1], zl = pgs[t*3+2];
        const float sql = sqs[t];
        float dist[32];
        #pragma unroll
        for (int m = 0; m < 32; ++m) {
            float dot = xl*pgs[m*3+0] + yl*pgs[m*3+1] + zl*pgs[m*3+2];
            dist[m] = sql + sqs[m] - 2.f*dot;
        }
        unsigned used = 0u;
        int* orow = idxw + b*256 + t*8;
        #pragma unroll
        for (int j = 0; j < 8; ++j) {
            float best = 3.4e38f; int bi = 0;
            #pragma unroll
            for (int m = 0; m < 32; ++m) {
                if (!((used >> m) & 1u) && dist[m] < best) { best = dist[m]; bi = m; }
            }
            used |= (1u << bi);
            orow[j] = bi;
        }
    }
}

// ---------------------------------------------------------------- BN finalize, partials layout [part][chan]
// grid = nChan/16, block 256. Coalesced 64B-line reads.
__global__ __launch_bounds__(256) void k_bn_fin2(
    const float* __restrict__ ps, const float* __restrict__ pq,
    int nPart, int nChan, float invN,
    const float* __restrict__ gamma, const float* __restrict__ beta,
    float* __restrict__ scale, float* __restrict__ shift)
{
    const int ob = blockIdx.x * 16;
    const int t = threadIdx.x;
    const int co = t & 15, i0 = t >> 4;
    float s = 0.f, q = 0.f;
    for (int i = i0; i < nPart; i += 16) {
        s += ps[(size_t)i*nChan + ob + co];
        q += pq[(size_t)i*nChan + ob + co];
    }
    __shared__ float ss[16][17], qs[16][17];
    ss[i0][co] = s; qs[i0][co] = q;
    __syncthreads();
    if (t < 16) {
        float S = 0.f, Q = 0.f;
        #pragma unroll
        for (int i = 0; i < 16; ++i) { S += ss[i][t]; Q += qs[i][t]; }
        const int o = ob + t;
        float mu  = S * invN;
        float var = Q * invN - mu*mu;
        float sc  = gamma[o] * rsqrtf(var + EPS);
        scale[o] = sc;
        shift[o] = beta[o] - mu * sc;
    }
}

// ---------------------------------------------------------------- K3: 2 groups/block. MFMA conv2 (128->256, N=64) + fg + MFMA conv3 (512->512, N=64)
// grid 512, block 256 (4 waves). LDS: B1 [64][136] unioned into B3 [64][520] (66.6 KB -> 2 blocks/CU)
__global__ __launch_bounds__(256, 2) void k3_mfma(
    const float* __restrict__ h1,
    const float* __restrict__ scale1, const float* __restrict__ shift1,
    const unsigned short* __restrict__ W2b, const float* __restrict__ b2,
    const unsigned short* __restrict__ W3b, const float* __restrict__ b3,
    unsigned short* __restrict__ h3b, float* __restrict__ p3s, float* __restrict__ p3q)
{
    const int g0 = blockIdx.x * 2;
    const int t = threadIdx.x;
    __shared__ __align__(16) unsigned short SB[64*520];
    unsigned short* B1 = SB;   // [64][136] during conv2
    unsigned short* B3 = SB;   // [64][520] during conv3 (B1 dead by then)

    // ---- stage x1 = relu(BN1(h1)) bf16, rows l 0..63 (2 groups), c 0..127
    {
        const int l = t >> 2, c0 = (t & 3) * 32;
        const int g = g0 + (l >> 5);
        const float4* src = (const float4*)(h1 + (size_t)g*4096 + (l & 31)*128 + c0);
        #pragma unroll
        for (int i = 0; i < 8; ++i) {
            float4 v = src[i];
            int c = c0 + i*4;
            float e0 = fmaxf(fmaf(v.x, scale1[c+0], shift1[c+0]), 0.f);
            float e1 = fmaxf(fmaf(v.y, scale1[c+1], shift1[c+1]), 0.f);
            float e2 = fmaxf(fmaf(v.z, scale1[c+2], shift1[c+2]), 0.f);
            float e3 = fmaxf(fmaf(v.w, scale1[c+3], shift1[c+3]), 0.f);
            *(unsigned long long*)&B1[l*136 + c] = pack4bf(e0, e1, e2, e3);
        }
    }
    __syncthreads();

    const int wave = t >> 6;
    const int lane = t & 63;
    const int m    = lane & 15;
    const int quad = lane >> 4;

    // ---- conv2: M=256, N=64, K=128
    f32x4 acc2[4][4];
    #pragma unroll
    for (int mt = 0; mt < 4; ++mt)
        #pragma unroll
        for (int n = 0; n < 4; ++n)
            acc2[mt][n] = (f32x4){0.f, 0.f, 0.f, 0.f};

    #pragma unroll
    for (int kt = 0; kt < 4; ++kt) {
        s16x8 bv[4];
        #pragma unroll
        for (int nt = 0; nt < 4; ++nt)
            bv[nt] = *(const s16x8*)&B1[(nt*16 + m)*136 + kt*32 + quad*8];
        #pragma unroll
        for (int mt = 0; mt < 4; ++mt) {
            s16x8 av = *(const s16x8*)(W2b + (size_t)(wave*64 + mt*16 + m)*128 + kt*32 + quad*8);
            #pragma unroll
            for (int nt = 0; nt < 4; ++nt)
                acc2[mt][nt] = __builtin_amdgcn_mfma_f32_16x16x32_bf16(av, bv[nt], acc2[mt][nt], 0, 0, 0);
        }
    }
    __syncthreads();   // all B1 reads done; SB becomes B3

    // ---- epilogue conv2: bias, write f2 (c 256..511), fg replicated (c 0..255)
    #pragma unroll
    for (int mt = 0; mt < 4; ++mt) {
        const int o0 = wave*64 + mt*16 + quad*4;
        #pragma unroll
        for (int r = 0; r < 4; ++r) {
            float bb = b2[o0 + r];
            #pragma unroll
            for (int nt = 0; nt < 4; ++nt) acc2[mt][nt][r] += bb;
        }
        #pragma unroll
        for (int nt = 0; nt < 4; ++nt) {
            const int row = nt*16 + m;
            *(unsigned long long*)&B3[row*520 + 256 + o0] =
                pack4bf(acc2[mt][nt][0], acc2[mt][nt][1], acc2[mt][nt][2], acc2[mt][nt][3]);
        }
        float f0[4], f1[4];
        #pragma unroll
        for (int r = 0; r < 4; ++r) {
            f0[r] = fmaxf(acc2[mt][0][r], acc2[mt][1][r]);
            f1[r] = fmaxf(acc2[mt][2][r], acc2[mt][3][r]);
        }
        #pragma unroll
        for (int msk = 1; msk < 16; msk <<= 1)
            #pragma unroll
            for (int r = 0; r < 4; ++r) {
                f0[r] = fmaxf(f0[r], __shfl_xor(f0[r], msk, 16));
                f1[r] = fmaxf(f1[r], __shfl_xor(f1[r], msk, 16));
            }
        unsigned long long pk0 = pack4bf(f0[0], f0[1], f0[2], f0[3]);
        unsigned long long pk1 = pack4bf(f1[0], f1[1], f1[2], f1[3]);
        *(unsigned long long*)&B3[(m     )*520 + o0] = pk0;
        *(unsigned long long*)&B3[(m + 16)*520 + o0] = pk0;
        *(unsigned long long*)&B3[(m + 32)*520 + o0] = pk1;
        *(unsigned long long*)&B3[(m + 48)*520 + o0] = pk1;
    }
    __syncthreads();

    // ---- conv3: M=512, N=64, K=512
    f32x4 acc3[8][4];
    #pragma unroll
    for (int mt = 0; mt < 8; ++mt)
        #pragma unroll
        for (int n = 0; n < 4; ++n)
            acc3[mt][n] = (f32x4){0.f, 0.f, 0.f, 0.f};

    #pragma unroll 4
    for (int kt = 0; kt < 16; ++kt) {
        s16x8 bv[4];
        #pragma unroll
        for (int nt = 0; nt < 4; ++nt)
            bv[nt] = *(const s16x8*)&B3[(nt*16 + m)*520 + kt*32 + quad*8];
        #pragma unroll
        for (int mt = 0; mt < 8; ++mt) {
            s16x8 av = *(const s16x8*)(W3b + (size_t)(wave*128 + mt*16 + m)*512 + kt*32 + quad*8);
            #pragma unroll
            for (int nt = 0; nt < 4; ++nt)
                acc3[mt][nt] = __builtin_amdgcn_mfma_f32_16x16x32_bf16(av, bv[nt], acc3[mt][nt], 0, 0, 0);
        }
    }

    // ---- epilogue conv3: bias, h3b bf16 [g][l][o], stats [g][o]
    #pragma unroll
    for (int mt = 0; mt < 8; ++mt) {
        const int o0 = wave*128 + mt*16 + quad*4;
        float s0[4], q0[4], s1[4], q1[4];
        #pragma unroll
        for (int r = 0; r < 4; ++r) {
            float bb = b3[o0 + r];
            #pragma unroll
            for (int nt = 0; nt < 4; ++nt) acc3[mt][nt][r] += bb;
            s0[r] = acc3[mt][0][r] + acc3[mt][1][r];
            q0[r] = acc3[mt][0][r]*acc3[mt][0][r] + acc3[mt][1][r]*acc3[mt][1][r];
            s1[r] = acc3[mt][2][r] + acc3[mt][3][r];
            q1[r] = acc3[mt][2][r]*acc3[mt][2][r] + acc3[mt][3][r]*acc3[mt][3][r];
        }
        #pragma unroll
        for (int nt = 0; nt < 4; ++nt) {
            const int g = g0 + (nt >> 1);
            const int l = (nt & 1)*16 + m;
            *(unsigned long long*)(h3b + (size_t)g*16384 + l*512 + o0) =
                pack4bf(acc3[mt][nt][0], acc3[mt][nt][1], acc3[mt][nt][2], acc3[mt][nt][3]);
        }
        #pragma unroll
        for (int msk = 1; msk < 16; msk <<= 1)
            #pragma unroll
            for (int r = 0; r < 4; ++r) {
                s0[r] += __shfl_xor(s0[r], msk, 16);
                q0[r] += __shfl_xor(q0[r], msk, 16);
                s1[r] += __shfl_xor(s1[r], msk, 16);
                q1[r] += __shfl_xor(q1[r], msk, 16);
            }
        if (m == 0) {
            #pragma unroll
            for (int r = 0; r < 4; ++r) {
                p3s[(size_t)g0*512 + o0 + r]       = s0[r];
                p3q[(size_t)g0*512 + o0 + r]       = q0[r];
                p3s[(size_t)(g0+1)*512 + o0 + r]   = s1[r];
                p3q[(size_t)(g0+1)*512 + o0 + r]   = q1[r];
            }
        }
    }
}

// ---------------------------------------------------------------- K5: 2 groups/block. MFMA conv4 (512->384, N=64) + fg2 + knn branch
// grid 512, block 384 (6 waves). LDS: B4 [64][520] bf16 union f4s [384][33] fp32 (66.6 KB)
__global__ __launch_bounds__(384, 2) void k5_mfma(
    const unsigned short* __restrict__ h3b,
    const float* __restrict__ scale3, const float* __restrict__ shift3,
    const unsigned short* __restrict__ W4b, const float* __restrict__ b4,
    const int* __restrict__ idxw,
    float* __restrict__ fg2, float* __restrict__ A,
    float* __restrict__ S1p, float* __restrict__ S2p)
{
    const int g0 = blockIdx.x * 2;
    const int t = threadIdx.x;
    __shared__ __align__(16) char smem[66560];
    unsigned short* B4 = (unsigned short*)smem;  // [64][520]
    float* f4s = (float*)smem;                   // [384][33]
    __shared__ int idxs[2][256];
    __shared__ float r1[6], r2[6];

    // ---- stage x3 = relu(BN3(h3b)) bf16 [l64][c512]
    for (int i = t; i < 4096; i += 384) {
        const int l = i >> 6, c8 = (i & 63) * 8;
        const int g = g0 + (l >> 5);
        s16x8 hv = *(const s16x8*)(h3b + (size_t)g*16384 + (l & 31)*512 + c8);
        unsigned short ov[8];
        #pragma unroll
        for (int e = 0; e < 8; ++e) {
            int c = c8 + e;
            float v = fmaxf(fmaf(bf2f((unsigned short)hv[e]), scale3[c], shift3[c]), 0.f);
            ov[e] = f2bf(v);
        }
        uint4 o4;
        o4.x = (unsigned)ov[0] | ((unsigned)ov[1] << 16);
        o4.y = (unsigned)ov[2] | ((unsigned)ov[3] << 16);
        o4.z = (unsigned)ov[4] | ((unsigned)ov[5] << 16);
        o4.w = (unsigned)ov[6] | ((unsigned)ov[7] << 16);
        *(uint4*)&B4[l*520 + c8] = o4;
    }
    for (int i = t; i < 512; i += 384) idxs[i >> 8][i & 255] = idxw[(g0 + (i >> 8))*256 + (i & 255)];
    __syncthreads();

    const int wave = t >> 6;
    const int lane = t & 63;
    const int m    = lane & 15;
    const int quad = lane >> 4;

    // ---- conv4: M=384, N=64, K=512
    f32x4 acc4[4][4];
    #pragma unroll
    for (int mt = 0; mt < 4; ++mt)
        #pragma unroll
        for (int n = 0; n < 4; ++n)
            acc4[mt][n] = (f32x4){0.f, 0.f, 0.f, 0.f};

    #pragma unroll 4
    for (int kt = 0; kt < 16; ++kt) {
        s16x8 bv[4];
        #pragma unroll
        for (int nt = 0; nt < 4; ++nt)
            bv[nt] = *(const s16x8*)&B4[(nt*16 + m)*520 + kt*32 + quad*8];
        #pragma unroll
        for (int mt = 0; mt < 4; ++mt) {
            s16x8 av = *(const s16x8*)(W4b + (size_t)(wave*64 + mt*16 + m)*512 + kt*32 + quad*8);
            #pragma unroll
            for (int nt = 0; nt < 4; ++nt)
                acc4[mt][nt] = __builtin_amdgcn_mfma_f32_16x16x32_bf16(av, bv[nt], acc4[mt][nt], 0, 0, 0);
        }
    }

    // ---- bias + fg2 per group
    #pragma unroll
    for (int mt = 0; mt < 4; ++mt) {
        const int o0 = wave*64 + mt*16 + quad*4;
        float f0[4], f1[4];
        #pragma unroll
        for (int r = 0; r < 4; ++r) {
            float bb = b4[o0 + r];
            #pragma unroll
            for (int nt = 0; nt < 4; ++nt) acc4[mt][nt][r] += bb;
            f0[r] = fmaxf(acc4[mt][0][r], acc4[mt][1][r]);
            f1[r] = fmaxf(acc4[mt][2][r], acc4[mt][3][r]);
        }
        #pragma unroll
        for (int msk = 1; msk < 16; msk <<= 1)
            #pragma unroll
            for (int r = 0; r < 4; ++r) {
                f0[r] = fmaxf(f0[r], __shfl_xor(f0[r], msk, 16));
                f1[r] = fmaxf(f1[r], __shfl_xor(f1[r], msk, 16));
            }
        if (m == 0) {
            #pragma unroll
            for (int r = 0; r < 4; ++r) {
                fg2[(size_t)g0*384 + o0 + r]     = f0[r];
                fg2[(size_t)(g0+1)*384 + o0 + r] = f1[r];
            }
        }
    }
    __syncthreads();   // B4 reads done; smem becomes f4s

    // ---- group 0: spill feat fp32 [o][33], knn
    #pragma unroll
    for (int mt = 0; mt < 4; ++mt) {
        const int o0 = wave*64 + mt*16 + quad*4;
        #pragma unroll
        for (int nt = 0; nt < 2; ++nt) {
            const int l = nt*16 + m;
            #pragma unroll
            for (int r = 0; r < 4; ++r) f4s[(o0 + r)*33 + l] = acc4[mt][nt][r];
        }
    }
    __syncthreads();
    float A0g0, qg0;
    {
        const float* row = &f4s[t*33];
        const int* ib = idxs[0];
        float A0 = 0.f, qq = 0.f;
        #pragma unroll
        for (int l = 0; l < 32; ++l) {
            const float sl = row[l];
            const int* ir = &ib[l*8];
            #pragma unroll
            for (int j = 0; j < 8; ++j) {
                float v = row[ir[j]] - sl;
                A0 += v; qq = fmaf(v, v, qq);
            }
        }
        A[(size_t)g0*384 + t] = A0;
        A0g0 = A0; qg0 = qq;
        float sA = A0, sQ = qq;
        #pragma unroll
        for (int off = 32; off > 0; off >>= 1) {
            sA += __shfl_down(sA, off, 64);
            sQ += __shfl_down(sQ, off, 64);
        }
        if (lane == 0) { r1[wave] = sA; r2[wave] = sQ; }
    }
    __syncthreads();
    if (t == 0) {
        S1p[g0] = r1[0]+r1[1]+r1[2]+r1[3]+r1[4]+r1[5];
        S2p[g0] = r2[0]+r2[1]+r2[2]+r2[3]+r2[4]+r2[5];
    }
    (void)A0g0; (void)qg0;

    // ---- group 1: spill, knn
    __syncthreads();   // t0's reads of r1/r2 done; f4s free
    #pragma unroll
    for (int mt = 0; mt < 4; ++mt) {
        const int o0 = wave*64 + mt*16 + quad*4;
        #pragma unroll
        for (int nt = 2; nt < 4; ++nt) {
            const int l = (nt - 2)*16 + m;
            #pragma unroll
            for (int r = 0; r < 4; ++r) f4s[(o0 + r)*33 + l] = acc4[mt][nt][r];
        }
    }
    __syncthreads();
    {
        const float* row = &f4s[t*33];
        const int* ib = idxs[1];
        float A0 = 0.f, qq = 0.f;
        #pragma unroll
        for (int l = 0; l < 32; ++l) {
            const float sl = row[l];
            const int* ir = &ib[l*8];
            #pragma unroll
            for (int j = 0; j < 8; ++j) {
                float v = row[ir[j]] - sl;
                A0 += v; qq = fmaf(v, v, qq);
            }
        }
        A[(size_t)(g0+1)*384 + t] = A0;
        float sA = A0, sQ = qq;
        #pragma unroll
        for (int off = 32; off > 0; off >>= 1) {
            sA += __shfl_down(sA, off, 64);
            sQ += __shfl_down(sQ, off, 64);
        }
        if (lane == 0) { r1[wave] = sA; r2[wave] = sQ; }
    }
    __syncthreads();
    if (t == 0) {
        S1p[g0+1] = r1[0]+r1[1]+r1[2]+r1[3]+r1[4]+r1[5];
        S2p[g0+1] = r2[0]+r2[1]+r2[2]+r2[3]+r2[4]+r2[5];
    }
}

// ---------------------------------------------------------------- K6: global std over dx (ddof=1)
__global__ void k6_std(const float* __restrict__ S1p, const float* __restrict__ S2p,
                       float* __restrict__ stdv)
{
    const int t = threadIdx.x;
    double s = 0.0, q = 0.0;
    for (int i = t; i < 1024; i += 256) { s += (double)S1p[i]; q += (double)S2p[i]; }
    #pragma unroll
    for (int off = 32; off > 0; off >>= 1) {
        s += __shfl_down(s, off, 64);
        q += __shfl_down(q, off, 64);
    }
    __shared__ double rs[4], rq[4];
    const int wid = t >> 6;
    if ((t & 63) == 0) { rs[wid] = s; rq[wid] = q; }
    __syncthreads();
    if (t == 0) {
        double S = rs[0]+rs[1]+rs[2]+rs[3];
        double Q = rq[0]+rq[1]+rq[2]+rq[3];
        const double N = 1024.0 * 32.0 * 8.0 * 384.0;
        double var = (Q - S*S/N) / (N - 1.0);
        stdv[0] = (float)sqrt(var);
    }
}

// ---------------------------------------------------------------- K7: fused head GEMM (1024 x 384, K=768), 128 blocks x 8 rows
__global__ __launch_bounds__(384) void k7_fused(
    const float* __restrict__ fg2, const float* __restrict__ A,
    const float* __restrict__ alpha, const float* __restrict__ beta_aff,
    const float* __restrict__ stdv,
    const float* __restrict__ Wf, const float* __restrict__ bf,
    float* __restrict__ hf, float* __restrict__ pfs, float* __restrict__ pfq)
{
    const int blk = blockIdx.x;
    const int b0 = blk * 8;
    const int t = threadIdx.x;
    __shared__ float xf[8*768];
    const float inv = 1.f / (256.f * (stdv[0] + EPS));
    #pragma unroll
    for (int bb = 0; bb < 8; ++bb) {
        for (int c = t; c < 768; c += 384) {
            float v;
            if (c < 384) v = fg2[(size_t)(b0+bb)*384 + c];
            else {
                int cc = c - 384;
                v = fmaf(alpha[cc] * inv, A[(size_t)(b0+bb)*384 + cc], beta_aff[cc]);
            }
            xf[bb*768 + c] = v;
        }
    }
    __syncthreads();
    const int o = t;
    float acc[8];
    const float bb0 = bf[o];
    #pragma unroll
    for (int i = 0; i < 8; ++i) acc[i] = bb0;
    const float4* wv = (const float4*)(Wf + (size_t)o*768);
    const float4* xv = (const float4*)xf;
    for (int c4 = 0; c4 < 192; ++c4) {
        float4 w = wv[c4];
        #pragma unroll
        for (int i = 0; i < 8; ++i) {
            float4 x = xv[i*192 + c4];
            acc[i] = fmaf(w.x, x.x, acc[i]);
            acc[i] = fmaf(w.y, x.y, acc[i]);
            acc[i] = fmaf(w.z, x.z, acc[i]);
            acc[i] = fmaf(w.w, x.w, acc[i]);
        }
    }
    float s = 0.f, q = 0.f;
    #pragma unroll
    for (int i = 0; i < 8; ++i) {
        hf[(size_t)(b0+i)*384 + o] = acc[i];
        s += acc[i]; q = fmaf(acc[i], acc[i], q);
    }
    pfs[(size_t)blk*384 + o] = s;
    pfq[(size_t)blk*384 + o] = q;
}

// ---------------------------------------------------------------- K9: BNf + relu -> out
__global__ __launch_bounds__(384) void k9_out(
    const float* __restrict__ hf, const float* __restrict__ scalef,
    const float* __restrict__ shiftf, float* __restrict__ out)
{
    const int b = blockIdx.x, t = threadIdx.x;
    float v = fmaf(hf[(size_t)b*384 + t], scalef[t], shiftf[t]);
    out[(size_t)b*384 + t] = fmaxf(v, 0.f);
}

extern "C" void kernel_launch(void* const* d_in, const int* in_sizes, int n_in,
                              void* d_out, int out_size, void* d_ws, size_t ws_size,
                              hipStream_t stream) {
    const float* pg      = (const float*)d_in[0];
    const float* W1      = (const float*)d_in[1];
    const float* b1      = (const float*)d_in[2];
    const float* gamma1  = (const float*)d_in[3];
    const float* beta1   = (const float*)d_in[4];
    const float* W2      = (const float*)d_in[5];
    const float* b2      = (const float*)d_in[6];
    const float* W3      = (const float*)d_in[7];
    const float* b3      = (const float*)d_in[8];
    const float* gamma3  = (const float*)d_in[9];
    const float* beta3   = (const float*)d_in[10];
    const float* W4      = (const float*)d_in[11];
    const float* b4      = (const float*)d_in[12];
    const float* alpha   = (const float*)d_in[13];
    const float* beta_af = (const float*)d_in[14];
    const float* Wf      = (const float*)d_in[15];
    const float* bf      = (const float*)d_in[16];
    const float* gammaf  = (const float*)d_in[17];
    const float* betaf   = (const float*)d_in[18];
    float* out = (float*)d_out;

    float* w = (float*)d_ws;
    float* h1     = w;  w += 1024*4096;                               // 16 MB [b][l][c]
    unsigned short* h3b = (unsigned short*)w; w += 1024*16384/2;      // 32 MB bf16 [b][l][o]
    unsigned short* W2b = (unsigned short*)w; w += 32768/2;
    unsigned short* W3b = (unsigned short*)w; w += 262144/2;
    unsigned short* W4b = (unsigned short*)w; w += 196608/2;
    float* hf     = w;  w += 1024*384;
    float* fg2    = w;  w += 1024*384;
    float* A      = w;  w += 1024*384;
    float* p1s    = w;  w += 1024*128;   // [b][c]
    float* p1q    = w;  w += 1024*128;
    float* p3s    = w;  w += 1024*512;   // [g][o]
    float* p3q    = w;  w += 1024*512;
    float* pfs    = w;  w += 128*384;    // [blk][o]
    float* pfq    = w;  w += 128*384;
    float* S1p    = w;  w += 1024;
    float* S2p    = w;  w += 1024;
    float* scale1 = w;  w += 128;
    float* shift1 = w;  w += 128;
    float* scale3 = w;  w += 512;
    float* shift3 = w;  w += 512;
    float* scalef = w;  w += 384;
    float* shiftf = w;  w += 384;
    float* stdv   = w;  w += 4;
    int*   idxw   = (int*)w;  w += 1024*256;

    hipLaunchKernelGGL(kprep, dim3(1024), dim3(256), 0, stream, W2, W3, W4, W2b, W3b, W4b);
    hipLaunchKernelGGL(k1_conv1_knn, dim3(1024), dim3(128), 0, stream,
                       pg, W1, b1, h1, p1s, p1q, idxw);
    hipLaunchKernelGGL(k_bn_fin2, dim3(8), dim3(256), 0, stream,
                       p1s, p1q, 1024, 128, 1.f/32768.f, gamma1, beta1, scale1, shift1);
    hipLaunchKernelGGL(k3_mfma, dim3(512), dim3(256), 0, stream,
                       h1, scale1, shift1, W2b, b2, W3b, b3, h3b, p3s, p3q);
    hipLaunchKernelGGL(k_bn_fin2, dim3(32), dim3(256), 0, stream,
                       p3s, p3q, 1024, 512, 1.f/32768.f, gamma3, beta3, scale3, shift3);
    hipLaunchKernelGGL(k5_mfma, dim3(512), dim3(384), 0, stream,
                       h3b, scale3, shift3, W4b, b4, idxw, fg2, A, S1p, S2p);
    hipLaunchKernelGGL(k6_std, dim3(1), dim3(256), 0, stream, S1p, S2p, stdv);
    hipLaunchKernelGGL(k7_fused, dim3(128), dim3(384), 0, stream,
                       fg2, A, alpha, beta_af, stdv, Wf, bf, hf, pfs, pfq);
    hipLaunchKernelGGL(k_bn_fin2, dim3(24), dim3(256), 0, stream,
                       pfs, pfq, 128, 384, 1.f/1024.f, gammaf, betaf, scalef, shiftf);
    hipLaunchKernelGGL(k9_out, dim3(1024), dim3(384), 0, stream,
                       hf, scalef, shiftf, out);
}

// Round 4
// 323.947 us; speedup vs baseline: 3.2729x; 1.0248x over previous
//
#include <hip/hip_runtime.h>
#include <math.h>

#define EPS 1e-5f

typedef __attribute__((ext_vector_type(8))) short s16x8;   // 8 bf16 (4 VGPRs)
typedef __attribute__((ext_vector_type(4))) float f32x4;   // MFMA C/D

__device__ __forceinline__ unsigned short f2bf(float x) {
    unsigned u = __float_as_uint(x);
    u += 0x7fffu + ((u >> 16) & 1u);           // round-to-nearest-even
    return (unsigned short)(u >> 16);
}
__device__ __forceinline__ float bf2f(unsigned short h) {
    return __uint_as_float(((unsigned)h) << 16);
}
__device__ __forceinline__ unsigned long long pack4bf(float a, float b, float c, float d) {
    return (unsigned long long)f2bf(a)
         | ((unsigned long long)f2bf(b) << 16)
         | ((unsigned long long)f2bf(c) << 32)
         | ((unsigned long long)f2bf(d) << 48);
}

// ---------------------------------------------------------------- kprep: fp32 weights -> bf16
__global__ __launch_bounds__(256) void kprep(
    const float* __restrict__ W2, const float* __restrict__ W3, const float* __restrict__ W4,
    unsigned short* __restrict__ W2b, unsigned short* __restrict__ W3b, unsigned short* __restrict__ W4b)
{
    int i = blockIdx.x * 256 + threadIdx.x;
    if (i < 32768)  W2b[i] = f2bf(W2[i]);
    if (i < 262144) W3b[i] = f2bf(W3[i]);
    if (i < 196608) W4b[i] = f2bf(W4[i]);
}

// ---------------------------------------------------------------- K1: conv1 (3->128) pre-BN + partial stats + knn indices
__global__ __launch_bounds__(128) void k1_conv1_knn(
    const float* __restrict__ pg, const float* __restrict__ W1,
    const float* __restrict__ b1,
    float* __restrict__ h1, float* __restrict__ p1s, float* __restrict__ p1q,
    int* __restrict__ idxw)
{
    const int b = blockIdx.x;
    const int t = threadIdx.x;
    __shared__ float pgs[96];
    __shared__ float sqs[32];
    if (t < 96) pgs[t] = pg[b * 96 + t];
    __syncthreads();
    if (t < 32) {
        float x = pgs[t*3+0], y = pgs[t*3+1], z = pgs[t*3+2];
        sqs[t] = x*x + y*y + z*z;
    }
    __syncthreads();
    {
        const float w0 = W1[t*3+0], w1 = W1[t*3+1], w2 = W1[t*3+2];
        const float bb = b1[t];
        float s = 0.f, q = 0.f;
        float* hcol = h1 + (size_t)b*4096 + t;
        #pragma unroll
        for (int l = 0; l < 32; ++l) {
            float v = fmaf(w2, pgs[l*3+2], fmaf(w1, pgs[l*3+1], fmaf(w0, pgs[l*3+0], bb)));
            hcol[l*128] = v; s += v; q += v*v;
        }
        p1s[b*128 + t] = s;
        p1q[b*128 + t] = q;
    }
    if (t < 32) {
        const float xl = pgs[t*3+0], yl = pgs[t*3+1], zl = pgs[t*3+2];
        const float sql = sqs[t];
        float dist[32];
        #pragma unroll
        for (int m = 0; m < 32; ++m) {
            float dot = xl*pgs[m*3+0] + yl*pgs[m*3+1] + zl*pgs[m*3+2];
            dist[m] = sql + sqs[m] - 2.f*dot;
        }
        unsigned used = 0u;
        int* orow = idxw + b*256 + t*8;
        #pragma unroll
        for (int j = 0; j < 8; ++j) {
            float best = 3.4e38f; int bi = 0;
            #pragma unroll
            for (int m = 0; m < 32; ++m) {
                if (!((used >> m) & 1u) && dist[m] < best) { best = dist[m]; bi = m; }
            }
            used |= (1u << bi);
            orow[j] = bi;
        }
    }
}

// ---------------------------------------------------------------- BN finalize, partials layout [part][chan]
__global__ __launch_bounds__(256) void k_bn_fin2(
    const float* __restrict__ ps, const float* __restrict__ pq,
    int nPart, int nChan, float invN,
    const float* __restrict__ gamma, const float* __restrict__ beta,
    float* __restrict__ scale, float* __restrict__ shift)
{
    const int ob = blockIdx.x * 16;
    const int t = threadIdx.x;
    const int co = t & 15, i0 = t >> 4;
    float s = 0.f, q = 0.f;
    for (int i = i0; i < nPart; i += 16) {
        s += ps[(size_t)i*nChan + ob + co];
        q += pq[(size_t)i*nChan + ob + co];
    }
    __shared__ float ss[16][17], qs[16][17];
    ss[i0][co] = s; qs[i0][co] = q;
    __syncthreads();
    if (t < 16) {
        float S = 0.f, Q = 0.f;
        #pragma unroll
        for (int i = 0; i < 16; ++i) { S += ss[i][t]; Q += qs[i][t]; }
        const int o = ob + t;
        float mu  = S * invN;
        float var = Q * invN - mu*mu;
        float sc  = gamma[o] * rsqrtf(var + EPS);
        scale[o] = sc;
        shift[o] = beta[o] - mu * sc;
    }
}

// ---------------------------------------------------------------- K3: 2 groups/block. MFMA conv2 + fg + MFMA conv3
__global__ __launch_bounds__(256, 2) void k3_mfma(
    const float* __restrict__ h1,
    const float* __restrict__ scale1, const float* __restrict__ shift1,
    const unsigned short* __restrict__ W2b, const float* __restrict__ b2,
    const unsigned short* __restrict__ W3b, const float* __restrict__ b3,
    unsigned short* __restrict__ h3b, float* __restrict__ p3s, float* __restrict__ p3q)
{
    const int g0 = blockIdx.x * 2;
    const int t = threadIdx.x;
    __shared__ __align__(16) unsigned short SB[64*520];
    unsigned short* B1 = SB;   // [64][136] during conv2
    unsigned short* B3 = SB;   // [64][520] during conv3

    {
        const int l = t >> 2, c0 = (t & 3) * 32;
        const int g = g0 + (l >> 5);
        const float4* src = (const float4*)(h1 + (size_t)g*4096 + (l & 31)*128 + c0);
        #pragma unroll
        for (int i = 0; i < 8; ++i) {
            float4 v = src[i];
            int c = c0 + i*4;
            float e0 = fmaxf(fmaf(v.x, scale1[c+0], shift1[c+0]), 0.f);
            float e1 = fmaxf(fmaf(v.y, scale1[c+1], shift1[c+1]), 0.f);
            float e2 = fmaxf(fmaf(v.z, scale1[c+2], shift1[c+2]), 0.f);
            float e3 = fmaxf(fmaf(v.w, scale1[c+3], shift1[c+3]), 0.f);
            *(unsigned long long*)&B1[l*136 + c] = pack4bf(e0, e1, e2, e3);
        }
    }
    __syncthreads();

    const int wave = t >> 6;
    const int lane = t & 63;
    const int m    = lane & 15;
    const int quad = lane >> 4;

    f32x4 acc2[4][4];
    #pragma unroll
    for (int mt = 0; mt < 4; ++mt)
        #pragma unroll
        for (int n = 0; n < 4; ++n)
            acc2[mt][n] = (f32x4){0.f, 0.f, 0.f, 0.f};

    #pragma unroll
    for (int kt = 0; kt < 4; ++kt) {
        s16x8 bv[4];
        #pragma unroll
        for (int nt = 0; nt < 4; ++nt)
            bv[nt] = *(const s16x8*)&B1[(nt*16 + m)*136 + kt*32 + quad*8];
        #pragma unroll
        for (int mt = 0; mt < 4; ++mt) {
            s16x8 av = *(const s16x8*)(W2b + (size_t)(wave*64 + mt*16 + m)*128 + kt*32 + quad*8);
            #pragma unroll
            for (int nt = 0; nt < 4; ++nt)
                acc2[mt][nt] = __builtin_amdgcn_mfma_f32_16x16x32_bf16(av, bv[nt], acc2[mt][nt], 0, 0, 0);
        }
    }
    __syncthreads();

    #pragma unroll
    for (int mt = 0; mt < 4; ++mt) {
        const int o0 = wave*64 + mt*16 + quad*4;
        #pragma unroll
        for (int r = 0; r < 4; ++r) {
            float bb = b2[o0 + r];
            #pragma unroll
            for (int nt = 0; nt < 4; ++nt) acc2[mt][nt][r] += bb;
        }
        #pragma unroll
        for (int nt = 0; nt < 4; ++nt) {
            const int row = nt*16 + m;
            *(unsigned long long*)&B3[row*520 + 256 + o0] =
                pack4bf(acc2[mt][nt][0], acc2[mt][nt][1], acc2[mt][nt][2], acc2[mt][nt][3]);
        }
        float f0[4], f1[4];
        #pragma unroll
        for (int r = 0; r < 4; ++r) {
            f0[r] = fmaxf(acc2[mt][0][r], acc2[mt][1][r]);
            f1[r] = fmaxf(acc2[mt][2][r], acc2[mt][3][r]);
        }
        #pragma unroll
        for (int msk = 1; msk < 16; msk <<= 1)
            #pragma unroll
            for (int r = 0; r < 4; ++r) {
                f0[r] = fmaxf(f0[r], __shfl_xor(f0[r], msk, 16));
                f1[r] = fmaxf(f1[r], __shfl_xor(f1[r], msk, 16));
            }
        unsigned long long pk0 = pack4bf(f0[0], f0[1], f0[2], f0[3]);
        unsigned long long pk1 = pack4bf(f1[0], f1[1], f1[2], f1[3]);
        *(unsigned long long*)&B3[(m     )*520 + o0] = pk0;
        *(unsigned long long*)&B3[(m + 16)*520 + o0] = pk0;
        *(unsigned long long*)&B3[(m + 32)*520 + o0] = pk1;
        *(unsigned long long*)&B3[(m + 48)*520 + o0] = pk1;
    }
    __syncthreads();

    f32x4 acc3[8][4];
    #pragma unroll
    for (int mt = 0; mt < 8; ++mt)
        #pragma unroll
        for (int n = 0; n < 4; ++n)
            acc3[mt][n] = (f32x4){0.f, 0.f, 0.f, 0.f};

    #pragma unroll 4
    for (int kt = 0; kt < 16; ++kt) {
        s16x8 bv[4];
        #pragma unroll
        for (int nt = 0; nt < 4; ++nt)
            bv[nt] = *(const s16x8*)&B3[(nt*16 + m)*520 + kt*32 + quad*8];
        #pragma unroll
        for (int mt = 0; mt < 8; ++mt) {
            s16x8 av = *(const s16x8*)(W3b + (size_t)(wave*128 + mt*16 + m)*512 + kt*32 + quad*8);
            #pragma unroll
            for (int nt = 0; nt < 4; ++nt)
                acc3[mt][nt] = __builtin_amdgcn_mfma_f32_16x16x32_bf16(av, bv[nt], acc3[mt][nt], 0, 0, 0);
        }
    }

    #pragma unroll
    for (int mt = 0; mt < 8; ++mt) {
        const int o0 = wave*128 + mt*16 + quad*4;
        float s0[4], q0[4], s1[4], q1[4];
        #pragma unroll
        for (int r = 0; r < 4; ++r) {
            float bb = b3[o0 + r];
            #pragma unroll
            for (int nt = 0; nt < 4; ++nt) acc3[mt][nt][r] += bb;
            s0[r] = acc3[mt][0][r] + acc3[mt][1][r];
            q0[r] = acc3[mt][0][r]*acc3[mt][0][r] + acc3[mt][1][r]*acc3[mt][1][r];
            s1[r] = acc3[mt][2][r] + acc3[mt][3][r];
            q1[r] = acc3[mt][2][r]*acc3[mt][2][r] + acc3[mt][3][r]*acc3[mt][3][r];
        }
        #pragma unroll
        for (int nt = 0; nt < 4; ++nt) {
            const int g = g0 + (nt >> 1);
            const int l = (nt & 1)*16 + m;
            *(unsigned long long*)(h3b + (size_t)g*16384 + l*512 + o0) =
                pack4bf(acc3[mt][nt][0], acc3[mt][nt][1], acc3[mt][nt][2], acc3[mt][nt][3]);
        }
        #pragma unroll
        for (int msk = 1; msk < 16; msk <<= 1)
            #pragma unroll
            for (int r = 0; r < 4; ++r) {
                s0[r] += __shfl_xor(s0[r], msk, 16);
                q0[r] += __shfl_xor(q0[r], msk, 16);
                s1[r] += __shfl_xor(s1[r], msk, 16);
                q1[r] += __shfl_xor(q1[r], msk, 16);
            }
        if (m == 0) {
            #pragma unroll
            for (int r = 0; r < 4; ++r) {
                p3s[(size_t)g0*512 + o0 + r]       = s0[r];
                p3q[(size_t)g0*512 + o0 + r]       = q0[r];
                p3s[(size_t)(g0+1)*512 + o0 + r]   = s1[r];
                p3q[(size_t)(g0+1)*512 + o0 + r]   = q1[r];
            }
        }
    }
}

// ---------------------------------------------------------------- K5: 2 groups/block. MFMA conv4 + fg2 + algebraic knn branch
// A[o]  = sum_m (cnt[m]-8) x[m,o]          (registers + shfl, fp32)
// qq    = sum (cnt[m]+8) x^2 - 2*sum x.*(M X)   (cross term via MFMA, M 0/1 bf16)
// grid 512, block 384 (6 waves). LDS: B4 [64][520] bf16 union { XT [2][384][40] bf16, M [2][32][40] bf16 }
__global__ __launch_bounds__(384, 2) void k5_mfma(
    const unsigned short* __restrict__ h3b,
    const float* __restrict__ scale3, const float* __restrict__ shift3,
    const unsigned short* __restrict__ W4b, const float* __restrict__ b4,
    const int* __restrict__ idxw,
    float* __restrict__ fg2, float* __restrict__ A,
    float* __restrict__ S1p, float* __restrict__ S2p)
{
    const int g0 = blockIdx.x * 2;
    const int t = threadIdx.x;
    __shared__ __align__(16) unsigned short SB[33280];   // 66560 B
    unsigned short* B4 = SB;                              // [64][520] staging
    unsigned short* XT = SB;                              // [g][o*40 + l], g stride 15360
    unsigned short* Mm = SB + 30720;                      // [g][l*40 + m], g stride 1280
    __shared__ int icnt[2][32];
    __shared__ float r1[2][6], r2[2][6];

    // ---- P0: stage x3 = relu(BN3(h3b)) bf16 [l64][c512]
    for (int i = t; i < 4096; i += 384) {
        const int l = i >> 6, c8 = (i & 63) * 8;
        const int g = g0 + (l >> 5);
        s16x8 hv = *(const s16x8*)(h3b + (size_t)g*16384 + (l & 31)*512 + c8);
        unsigned short ov[8];
        #pragma unroll
        for (int e = 0; e < 8; ++e) {
            int c = c8 + e;
            float v = fmaxf(fmaf(bf2f((unsigned short)hv[e]), scale3[c], shift3[c]), 0.f);
            ov[e] = f2bf(v);
        }
        uint4 o4;
        o4.x = (unsigned)ov[0] | ((unsigned)ov[1] << 16);
        o4.y = (unsigned)ov[2] | ((unsigned)ov[3] << 16);
        o4.z = (unsigned)ov[4] | ((unsigned)ov[5] << 16);
        o4.w = (unsigned)ov[6] | ((unsigned)ov[7] << 16);
        *(uint4*)&B4[l*520 + c8] = o4;
    }
    if (t < 64) icnt[t >> 5][t & 31] = 0;
    __syncthreads();

    const int wave = t >> 6;
    const int lane = t & 63;
    const int m    = lane & 15;
    const int quad = lane >> 4;

    // ---- P1: conv4 MFMA: M=384, N=64, K=512
    f32x4 acc4[4][4];
    #pragma unroll
    for (int mt = 0; mt < 4; ++mt)
        #pragma unroll
        for (int n = 0; n < 4; ++n)
            acc4[mt][n] = (f32x4){0.f, 0.f, 0.f, 0.f};

    #pragma unroll 4
    for (int kt = 0; kt < 16; ++kt) {
        s16x8 bv[4];
        #pragma unroll
        for (int nt = 0; nt < 4; ++nt)
            bv[nt] = *(const s16x8*)&B4[(nt*16 + m)*520 + kt*32 + quad*8];
        #pragma unroll
        for (int mt = 0; mt < 4; ++mt) {
            s16x8 av = *(const s16x8*)(W4b + (size_t)(wave*64 + mt*16 + m)*512 + kt*32 + quad*8);
            #pragma unroll
            for (int nt = 0; nt < 4; ++nt)
                acc4[mt][nt] = __builtin_amdgcn_mfma_f32_16x16x32_bf16(av, bv[nt], acc4[mt][nt], 0, 0, 0);
        }
    }

    // ---- P2: bias + fg2 (register-only, before LDS repurpose)
    #pragma unroll
    for (int mt = 0; mt < 4; ++mt) {
        const int o0 = wave*64 + mt*16 + quad*4;
        float f0[4], f1[4];
        #pragma unroll
        for (int r = 0; r < 4; ++r) {
            float bb = b4[o0 + r];
            #pragma unroll
            for (int nt = 0; nt < 4; ++nt) acc4[mt][nt][r] += bb;
            f0[r] = fmaxf(acc4[mt][0][r], acc4[mt][1][r]);
            f1[r] = fmaxf(acc4[mt][2][r], acc4[mt][3][r]);
        }
        #pragma unroll
        for (int msk = 1; msk < 16; msk <<= 1)
            #pragma unroll
            for (int r = 0; r < 4; ++r) {
                f0[r] = fmaxf(f0[r], __shfl_xor(f0[r], msk, 16));
                f1[r] = fmaxf(f1[r], __shfl_xor(f1[r], msk, 16));
            }
        if (m == 0) {
            #pragma unroll
            for (int r = 0; r < 4; ++r) {
                fg2[(size_t)g0*384 + o0 + r]     = f0[r];
                fg2[(size_t)(g0+1)*384 + o0 + r] = f1[r];
            }
        }
    }
    __syncthreads();   // B4 reads done; SB becomes XT + M

    // ---- P3: spill X^T bf16 [o][l] (stride 40), zero M
    #pragma unroll
    for (int mt = 0; mt < 4; ++mt) {
        const int o0 = wave*64 + mt*16 + quad*4;
        #pragma unroll
        for (int nt = 0; nt < 4; ++nt) {
            const int g = nt >> 1;
            const int l = (nt & 1)*16 + m;
            unsigned short* xg = XT + g*15360;
            #pragma unroll
            for (int r = 0; r < 4; ++r)
                xg[(o0 + r)*40 + l] = f2bf(acc4[mt][nt][r]);
        }
    }
    if (t < 64) {
        const int g = t >> 5, l = t & 31;
        uint4 z = make_uint4(0u, 0u, 0u, 0u);
        #pragma unroll
        for (int i = 0; i < 5; ++i)
            *(uint4*)&Mm[g*1280 + l*40 + i*8] = z;
    }
    __syncthreads();

    // ---- P4: build M (0/1 bf16) + neighbor counts
    if (t < 64) {
        const int g = t >> 5, l = t & 31;
        const int* ip = idxw + (size_t)(g0 + g)*256 + l*8;
        #pragma unroll
        for (int j = 0; j < 8; ++j) {
            int ix = ip[j];
            Mm[g*1280 + l*40 + ix] = 0x3F80;   // bf16 1.0
            atomicAdd(&icnt[g][ix], 1);
        }
    }
    __syncthreads();

    // ---- P5a: A + x^2 partials from registers (consumes acc4)
    float s1loc[2] = {0.f, 0.f}, s2loc[2] = {0.f, 0.f};
    #pragma unroll
    for (int g = 0; g < 2; ++g) {
        const float c0 = (float)icnt[g][m];
        const float c1 = (float)icnt[g][m + 16];
        const float w0 = c0 - 8.f, u0 = c0 + 8.f;
        const float w1 = c1 - 8.f, u1 = c1 + 8.f;
        #pragma unroll
        for (int mt = 0; mt < 4; ++mt) {
            const int o0 = wave*64 + mt*16 + quad*4;
            float Ap[4];
            #pragma unroll
            for (int r = 0; r < 4; ++r) {
                const float x0 = acc4[mt][g*2 + 0][r];
                const float x1 = acc4[mt][g*2 + 1][r];
                Ap[r] = w0*x0 + w1*x1;
                s1loc[g] += Ap[r];
                s2loc[g] += u0*x0*x0 + u1*x1*x1;
            }
            #pragma unroll
            for (int msk = 1; msk < 16; msk <<= 1)
                #pragma unroll
                for (int r = 0; r < 4; ++r)
                    Ap[r] += __shfl_xor(Ap[r], msk, 16);
            if (m == 0) {
                #pragma unroll
                for (int r = 0; r < 4; ++r)
                    A[(size_t)(g0 + g)*384 + o0 + r] = Ap[r];
            }
        }
    }

    // ---- P5b: cross term via MFMA: s = M X; cross += x .* s
    // wave handles o-tiles [wave*4, wave*4+4), both l'-tiles, both groups
    #pragma unroll
    for (int g = 0; g < 2; ++g) {
        const unsigned short* xg = XT + g*15360;
        float cross = 0.f;
        #pragma unroll
        for (int lt = 0; lt < 2; ++lt) {
            s16x8 af = *(const s16x8*)&Mm[g*1280 + (lt*16 + m)*40 + quad*8];
            #pragma unroll
            for (int i = 0; i < 4; ++i) {
                const int oc = (wave*4 + i)*16 + m;
                s16x8 bfv = *(const s16x8*)&xg[oc*40 + quad*8];
                f32x4 sa = __builtin_amdgcn_mfma_f32_16x16x32_bf16(
                    af, bfv, (f32x4){0.f, 0.f, 0.f, 0.f}, 0, 0, 0);
                #pragma unroll
                for (int r = 0; r < 4; ++r) {
                    const int lp = lt*16 + quad*4 + r;
                    cross = fmaf(bf2f(xg[oc*40 + lp]), sa[r], cross);
                }
            }
        }
        s2loc[g] -= 2.f * cross;
    }

    // ---- P5c: block reduce S1/S2 per group
    #pragma unroll
    for (int g = 0; g < 2; ++g) {
        float sA = s1loc[g], sQ = s2loc[g];
        #pragma unroll
        for (int off = 32; off > 0; off >>= 1) {
            sA += __shfl_down(sA, off, 64);
            sQ += __shfl_down(sQ, off, 64);
        }
        if (lane == 0) { r1[g][wave] = sA; r2[g][wave] = sQ; }
    }
    __syncthreads();
    if (t < 2) {
        float S = 0.f, Q = 0.f;
        #pragma unroll
        for (int w = 0; w < 6; ++w) { S += r1[t][w]; Q += r2[t][w]; }
        S1p[g0 + t] = S;
        S2p[g0 + t] = Q;
    }
}

// ---------------------------------------------------------------- K6: global std over dx (ddof=1)
__global__ void k6_std(const float* __restrict__ S1p, const float* __restrict__ S2p,
                       float* __restrict__ stdv)
{
    const int t = threadIdx.x;
    double s = 0.0, q = 0.0;
    for (int i = t; i < 1024; i += 256) { s += (double)S1p[i]; q += (double)S2p[i]; }
    #pragma unroll
    for (int off = 32; off > 0; off >>= 1) {
        s += __shfl_down(s, off, 64);
        q += __shfl_down(q, off, 64);
    }
    __shared__ double rs[4], rq[4];
    const int wid = t >> 6;
    if ((t & 63) == 0) { rs[wid] = s; rq[wid] = q; }
    __syncthreads();
    if (t == 0) {
        double S = rs[0]+rs[1]+rs[2]+rs[3];
        double Q = rq[0]+rq[1]+rq[2]+rq[3];
        const double N = 1024.0 * 32.0 * 8.0 * 384.0;
        double var = (Q - S*S/N) / (N - 1.0);
        stdv[0] = (float)sqrt(var);
    }
}

// ---------------------------------------------------------------- K7: fused head GEMM (1024 x 384, K=768), 128 blocks x 8 rows
__global__ __launch_bounds__(384) void k7_fused(
    const float* __restrict__ fg2, const float* __restrict__ A,
    const float* __restrict__ alpha, const float* __restrict__ beta_aff,
    const float* __restrict__ stdv,
    const float* __restrict__ Wf, const float* __restrict__ bf,
    float* __restrict__ hf, float* __restrict__ pfs, float* __restrict__ pfq)
{
    const int blk = blockIdx.x;
    const int b0 = blk * 8;
    const int t = threadIdx.x;
    __shared__ float xf[8*768];
    const float inv = 1.f / (256.f * (stdv[0] + EPS));
    #pragma unroll
    for (int bb = 0; bb < 8; ++bb) {
        for (int c = t; c < 768; c += 384) {
            float v;
            if (c < 384) v = fg2[(size_t)(b0+bb)*384 + c];
            else {
                int cc = c - 384;
                v = fmaf(alpha[cc] * inv, A[(size_t)(b0+bb)*384 + cc], beta_aff[cc]);
            }
            xf[bb*768 + c] = v;
        }
    }
    __syncthreads();
    const int o = t;
    float acc[8];
    const float bb0 = bf[o];
    #pragma unroll
    for (int i = 0; i < 8; ++i) acc[i] = bb0;
    const float4* wv = (const float4*)(Wf + (size_t)o*768);
    const float4* xv = (const float4*)xf;
    for (int c4 = 0; c4 < 192; ++c4) {
        float4 w = wv[c4];
        #pragma unroll
        for (int i = 0; i < 8; ++i) {
            float4 x = xv[i*192 + c4];
            acc[i] = fmaf(w.x, x.x, acc[i]);
            acc[i] = fmaf(w.y, x.y, acc[i]);
            acc[i] = fmaf(w.z, x.z, acc[i]);
            acc[i] = fmaf(w.w, x.w, acc[i]);
        }
    }
    float s = 0.f, q = 0.f;
    #pragma unroll
    for (int i = 0; i < 8; ++i) {
        hf[(size_t)(b0+i)*384 + o] = acc[i];
        s += acc[i]; q = fmaf(acc[i], acc[i], q);
    }
    pfs[(size_t)blk*384 + o] = s;
    pfq[(size_t)blk*384 + o] = q;
}

// ---------------------------------------------------------------- K9: BNf + relu -> out
__global__ __launch_bounds__(384) void k9_out(
    const float* __restrict__ hf, const float* __restrict__ scalef,
    const float* __restrict__ shiftf, float* __restrict__ out)
{
    const int b = blockIdx.x, t = threadIdx.x;
    float v = fmaf(hf[(size_t)b*384 + t], scalef[t], shiftf[t]);
    out[(size_t)b*384 + t] = fmaxf(v, 0.f);
}

extern "C" void kernel_launch(void* const* d_in, const int* in_sizes, int n_in,
                              void* d_out, int out_size, void* d_ws, size_t ws_size,
                              hipStream_t stream) {
    const float* pg      = (const float*)d_in[0];
    const float* W1      = (const float*)d_in[1];
    const float* b1      = (const float*)d_in[2];
    const float* gamma1  = (const float*)d_in[3];
    const float* beta1   = (const float*)d_in[4];
    const float* W2      = (const float*)d_in[5];
    const float* b2      = (const float*)d_in[6];
    const float* W3      = (const float*)d_in[7];
    const float* b3      = (const float*)d_in[8];
    const float* gamma3  = (const float*)d_in[9];
    const float* beta3   = (const float*)d_in[10];
    const float* W4      = (const float*)d_in[11];
    const float* b4      = (const float*)d_in[12];
    const float* alpha   = (const float*)d_in[13];
    const float* beta_af = (const float*)d_in[14];
    const float* Wf      = (const float*)d_in[15];
    const float* bf      = (const float*)d_in[16];
    const float* gammaf  = (const float*)d_in[17];
    const float* betaf   = (const float*)d_in[18];
    float* out = (float*)d_out;

    float* w = (float*)d_ws;
    float* h1     = w;  w += 1024*4096;                               // 16 MB [b][l][c]
    unsigned short* h3b = (unsigned short*)w; w += 1024*16384/2;      // 32 MB bf16 [b][l][o]
    unsigned short* W2b = (unsigned short*)w; w += 32768/2;
    unsigned short* W3b = (unsigned short*)w; w += 262144/2;
    unsigned short* W4b = (unsigned short*)w; w += 196608/2;
    float* hf     = w;  w += 1024*384;
    float* fg2    = w;  w += 1024*384;
    float* A      = w;  w += 1024*384;
    float* p1s    = w;  w += 1024*128;   // [b][c]
    float* p1q    = w;  w += 1024*128;
    float* p3s    = w;  w += 1024*512;   // [g][o]
    float* p3q    = w;  w += 1024*512;
    float* pfs    = w;  w += 128*384;    // [blk][o]
    float* pfq    = w;  w += 128*384;
    float* S1p    = w;  w += 1024;
    float* S2p    = w;  w += 1024;
    float* scale1 = w;  w += 128;
    float* shift1 = w;  w += 128;
    float* scale3 = w;  w += 512;
    float* shift3 = w;  w += 512;
    float* scalef = w;  w += 384;
    float* shiftf = w;  w += 384;
    float* stdv   = w;  w += 4;
    int*   idxw   = (int*)w;  w += 1024*256;

    hipLaunchKernelGGL(kprep, dim3(1024), dim3(256), 0, stream, W2, W3, W4, W2b, W3b, W4b);
    hipLaunchKernelGGL(k1_conv1_knn, dim3(1024), dim3(128), 0, stream,
                       pg, W1, b1, h1, p1s, p1q, idxw);
    hipLaunchKernelGGL(k_bn_fin2, dim3(8), dim3(256), 0, stream,
                       p1s, p1q, 1024, 128, 1.f/32768.f, gamma1, beta1, scale1, shift1);
    hipLaunchKernelGGL(k3_mfma, dim3(512), dim3(256), 0, stream,
                       h1, scale1, shift1, W2b, b2, W3b, b3, h3b, p3s, p3q);
    hipLaunchKernelGGL(k_bn_fin2, dim3(32), dim3(256), 0, stream,
                       p3s, p3q, 1024, 512, 1.f/32768.f, gamma3, beta3, scale3, shift3);
    hipLaunchKernelGGL(k5_mfma, dim3(512), dim3(384), 0, stream,
                       h3b, scale3, shift3, W4b, b4, idxw, fg2, A, S1p, S2p);
    hipLaunchKernelGGL(k6_std, dim3(1), dim3(256), 0, stream, S1p, S2p, stdv);
    hipLaunchKernelGGL(k7_fused, dim3(128), dim3(384), 0, stream,
                       fg2, A, alpha, beta_af, stdv, Wf, bf, hf, pfs, pfq);
    hipLaunchKernelGGL(k_bn_fin2, dim3(24), dim3(256), 0, stream,
                       pfs, pfq, 128, 384, 1.f/1024.f, gammaf, betaf, scalef, shiftf);
    hipLaunchKernelGGL(k9_out, dim3(1024), dim3(384), 0, stream,
                       hf, scalef, shiftf, out);
}

// Round 5
// 309.707 us; speedup vs baseline: 3.4234x; 1.0460x over previous
//
#include <hip/hip_runtime.h>
#include <math.h>

#define EPS 1e-5f

typedef __attribute__((ext_vector_type(8))) short s16x8;   // 8 bf16 (4 VGPRs)
typedef __attribute__((ext_vector_type(4))) float f32x4;   // MFMA C/D

__device__ __forceinline__ unsigned short f2bf(float x) {
    unsigned u = __float_as_uint(x);
    u += 0x7fffu + ((u >> 16) & 1u);           // round-to-nearest-even
    return (unsigned short)(u >> 16);
}
__device__ __forceinline__ float bf2f(unsigned short h) {
    return __uint_as_float(((unsigned)h) << 16);
}
__device__ __forceinline__ unsigned long long pack4bf(float a, float b, float c, float d) {
    return (unsigned long long)f2bf(a)
         | ((unsigned long long)f2bf(b) << 16)
         | ((unsigned long long)f2bf(c) << 32)
         | ((unsigned long long)f2bf(d) << 48);
}

// ---------------------------------------------------------------- kprep: fp32 weights -> bf16 (now incl. Wf)
__global__ __launch_bounds__(256) void kprep(
    const float* __restrict__ W2, const float* __restrict__ W3, const float* __restrict__ W4,
    const float* __restrict__ Wf,
    unsigned short* __restrict__ W2b, unsigned short* __restrict__ W3b,
    unsigned short* __restrict__ W4b, unsigned short* __restrict__ Wfb)
{
    int i = blockIdx.x * 256 + threadIdx.x;
    if (i < 32768)  W2b[i] = f2bf(W2[i]);
    if (i < 262144) W3b[i] = f2bf(W3[i]);
    if (i < 196608) W4b[i] = f2bf(W4[i]);
    if (i < 294912) Wfb[i] = f2bf(Wf[i]);
}

// ---------------------------------------------------------------- K1: conv1 (3->128) pre-BN + partial stats + knn indices
__global__ __launch_bounds__(128) void k1_conv1_knn(
    const float* __restrict__ pg, const float* __restrict__ W1,
    const float* __restrict__ b1,
    float* __restrict__ h1, float* __restrict__ p1s, float* __restrict__ p1q,
    int* __restrict__ idxw)
{
    const int b = blockIdx.x;
    const int t = threadIdx.x;
    __shared__ float pgs[96];
    __shared__ float sqs[32];
    if (t < 96) pgs[t] = pg[b * 96 + t];
    __syncthreads();
    if (t < 32) {
        float x = pgs[t*3+0], y = pgs[t*3+1], z = pgs[t*3+2];
        sqs[t] = x*x + y*y + z*z;
    }
    __syncthreads();
    {
        const float w0 = W1[t*3+0], w1 = W1[t*3+1], w2 = W1[t*3+2];
        const float bb = b1[t];
        float s = 0.f, q = 0.f;
        float* hcol = h1 + (size_t)b*4096 + t;
        #pragma unroll
        for (int l = 0; l < 32; ++l) {
            float v = fmaf(w2, pgs[l*3+2], fmaf(w1, pgs[l*3+1], fmaf(w0, pgs[l*3+0], bb)));
            hcol[l*128] = v; s += v; q += v*v;
        }
        p1s[b*128 + t] = s;
        p1q[b*128 + t] = q;
    }
    if (t < 32) {
        const float xl = pgs[t*3+0], yl = pgs[t*3+1], zl = pgs[t*3+2];
        const float sql = sqs[t];
        float dist[32];
        #pragma unroll
        for (int m = 0; m < 32; ++m) {
            float dot = xl*pgs[m*3+0] + yl*pgs[m*3+1] + zl*pgs[m*3+2];
            dist[m] = sql + sqs[m] - 2.f*dot;
        }
        unsigned used = 0u;
        int* orow = idxw + b*256 + t*8;
        #pragma unroll
        for (int j = 0; j < 8; ++j) {
            float best = 3.4e38f; int bi = 0;
            #pragma unroll
            for (int m = 0; m < 32; ++m) {
                if (!((used >> m) & 1u) && dist[m] < best) { best = dist[m]; bi = m; }
            }
            used |= (1u << bi);
            orow[j] = bi;
        }
    }
}

// ---------------------------------------------------------------- BN finalize, partials layout [part][chan]
__global__ __launch_bounds__(256) void k_bn_fin2(
    const float* __restrict__ ps, const float* __restrict__ pq,
    int nPart, int nChan, float invN,
    const float* __restrict__ gamma, const float* __restrict__ beta,
    float* __restrict__ scale, float* __restrict__ shift)
{
    const int ob = blockIdx.x * 16;
    const int t = threadIdx.x;
    const int co = t & 15, i0 = t >> 4;
    float s = 0.f, q = 0.f;
    for (int i = i0; i < nPart; i += 16) {
        s += ps[(size_t)i*nChan + ob + co];
        q += pq[(size_t)i*nChan + ob + co];
    }
    __shared__ float ss[16][17], qs[16][17];
    ss[i0][co] = s; qs[i0][co] = q;
    __syncthreads();
    if (t < 16) {
        float S = 0.f, Q = 0.f;
        #pragma unroll
        for (int i = 0; i < 16; ++i) { S += ss[i][t]; Q += qs[i][t]; }
        const int o = ob + t;
        float mu  = S * invN;
        float var = Q * invN - mu*mu;
        float sc  = gamma[o] * rsqrtf(var + EPS);
        scale[o] = sc;
        shift[o] = beta[o] - mu * sc;
    }
}

// ---------------------------------------------------------------- K3: 2 groups/block. MFMA conv2 + fg + MFMA conv3; coalesced h3b via LDS
__global__ __launch_bounds__(256, 2) void k3_mfma(
    const float* __restrict__ h1,
    const float* __restrict__ scale1, const float* __restrict__ shift1,
    const unsigned short* __restrict__ W2b, const float* __restrict__ b2,
    const unsigned short* __restrict__ W3b, const float* __restrict__ b3,
    unsigned short* __restrict__ h3b, float* __restrict__ p3s, float* __restrict__ p3q)
{
    const int g0 = blockIdx.x * 2;
    const int t = threadIdx.x;
    __shared__ __align__(16) unsigned short SB[64*520];
    unsigned short* B1 = SB;   // [64][136] during conv2
    unsigned short* B3 = SB;   // [64][520] during conv3
    unsigned short* OT = SB;   // [64][520] output tile after conv3 (cols 0..511 used)

    {
        const int l = t >> 2, c0 = (t & 3) * 32;
        const int g = g0 + (l >> 5);
        const float4* src = (const float4*)(h1 + (size_t)g*4096 + (l & 31)*128 + c0);
        #pragma unroll
        for (int i = 0; i < 8; ++i) {
            float4 v = src[i];
            int c = c0 + i*4;
            float e0 = fmaxf(fmaf(v.x, scale1[c+0], shift1[c+0]), 0.f);
            float e1 = fmaxf(fmaf(v.y, scale1[c+1], shift1[c+1]), 0.f);
            float e2 = fmaxf(fmaf(v.z, scale1[c+2], shift1[c+2]), 0.f);
            float e3 = fmaxf(fmaf(v.w, scale1[c+3], shift1[c+3]), 0.f);
            *(unsigned long long*)&B1[l*136 + c] = pack4bf(e0, e1, e2, e3);
        }
    }
    __syncthreads();

    const int wave = t >> 6;
    const int lane = t & 63;
    const int m    = lane & 15;
    const int quad = lane >> 4;

    f32x4 acc2[4][4];
    #pragma unroll
    for (int mt = 0; mt < 4; ++mt)
        #pragma unroll
        for (int n = 0; n < 4; ++n)
            acc2[mt][n] = (f32x4){0.f, 0.f, 0.f, 0.f};

    #pragma unroll
    for (int kt = 0; kt < 4; ++kt) {
        s16x8 bv[4];
        #pragma unroll
        for (int nt = 0; nt < 4; ++nt)
            bv[nt] = *(const s16x8*)&B1[(nt*16 + m)*136 + kt*32 + quad*8];
        #pragma unroll
        for (int mt = 0; mt < 4; ++mt) {
            s16x8 av = *(const s16x8*)(W2b + (size_t)(wave*64 + mt*16 + m)*128 + kt*32 + quad*8);
            #pragma unroll
            for (int nt = 0; nt < 4; ++nt)
                acc2[mt][nt] = __builtin_amdgcn_mfma_f32_16x16x32_bf16(av, bv[nt], acc2[mt][nt], 0, 0, 0);
        }
    }
    __syncthreads();

    #pragma unroll
    for (int mt = 0; mt < 4; ++mt) {
        const int o0 = wave*64 + mt*16 + quad*4;
        #pragma unroll
        for (int r = 0; r < 4; ++r) {
            float bb = b2[o0 + r];
            #pragma unroll
            for (int nt = 0; nt < 4; ++nt) acc2[mt][nt][r] += bb;
        }
        #pragma unroll
        for (int nt = 0; nt < 4; ++nt) {
            const int row = nt*16 + m;
            *(unsigned long long*)&B3[row*520 + 256 + o0] =
                pack4bf(acc2[mt][nt][0], acc2[mt][nt][1], acc2[mt][nt][2], acc2[mt][nt][3]);
        }
        float f0[4], f1[4];
        #pragma unroll
        for (int r = 0; r < 4; ++r) {
            f0[r] = fmaxf(acc2[mt][0][r], acc2[mt][1][r]);
            f1[r] = fmaxf(acc2[mt][2][r], acc2[mt][3][r]);
        }
        #pragma unroll
        for (int msk = 1; msk < 16; msk <<= 1)
            #pragma unroll
            for (int r = 0; r < 4; ++r) {
                f0[r] = fmaxf(f0[r], __shfl_xor(f0[r], msk, 16));
                f1[r] = fmaxf(f1[r], __shfl_xor(f1[r], msk, 16));
            }
        unsigned long long pk0 = pack4bf(f0[0], f0[1], f0[2], f0[3]);
        unsigned long long pk1 = pack4bf(f1[0], f1[1], f1[2], f1[3]);
        *(unsigned long long*)&B3[(m     )*520 + o0] = pk0;
        *(unsigned long long*)&B3[(m + 16)*520 + o0] = pk0;
        *(unsigned long long*)&B3[(m + 32)*520 + o0] = pk1;
        *(unsigned long long*)&B3[(m + 48)*520 + o0] = pk1;
    }
    __syncthreads();

    f32x4 acc3[8][4];
    #pragma unroll
    for (int mt = 0; mt < 8; ++mt)
        #pragma unroll
        for (int n = 0; n < 4; ++n)
            acc3[mt][n] = (f32x4){0.f, 0.f, 0.f, 0.f};

    #pragma unroll 4
    for (int kt = 0; kt < 16; ++kt) {
        s16x8 bv[4];
        #pragma unroll
        for (int nt = 0; nt < 4; ++nt)
            bv[nt] = *(const s16x8*)&B3[(nt*16 + m)*520 + kt*32 + quad*8];
        #pragma unroll
        for (int mt = 0; mt < 8; ++mt) {
            s16x8 av = *(const s16x8*)(W3b + (size_t)(wave*128 + mt*16 + m)*512 + kt*32 + quad*8);
            #pragma unroll
            for (int nt = 0; nt < 4; ++nt)
                acc3[mt][nt] = __builtin_amdgcn_mfma_f32_16x16x32_bf16(av, bv[nt], acc3[mt][nt], 0, 0, 0);
        }
    }

    // bias + stats (registers only)
    #pragma unroll
    for (int mt = 0; mt < 8; ++mt) {
        const int o0 = wave*128 + mt*16 + quad*4;
        float s0[4], q0[4], s1[4], q1[4];
        #pragma unroll
        for (int r = 0; r < 4; ++r) {
            float bb = b3[o0 + r];
            #pragma unroll
            for (int nt = 0; nt < 4; ++nt) acc3[mt][nt][r] += bb;
            s0[r] = acc3[mt][0][r] + acc3[mt][1][r];
            q0[r] = acc3[mt][0][r]*acc3[mt][0][r] + acc3[mt][1][r]*acc3[mt][1][r];
            s1[r] = acc3[mt][2][r] + acc3[mt][3][r];
            q1[r] = acc3[mt][2][r]*acc3[mt][2][r] + acc3[mt][3][r]*acc3[mt][3][r];
        }
        #pragma unroll
        for (int msk = 1; msk < 16; msk <<= 1)
            #pragma unroll
            for (int r = 0; r < 4; ++r) {
                s0[r] += __shfl_xor(s0[r], msk, 16);
                q0[r] += __shfl_xor(q0[r], msk, 16);
                s1[r] += __shfl_xor(s1[r], msk, 16);
                q1[r] += __shfl_xor(q1[r], msk, 16);
            }
        if (m == 0) {
            #pragma unroll
            for (int r = 0; r < 4; ++r) {
                p3s[(size_t)g0*512 + o0 + r]       = s0[r];
                p3q[(size_t)g0*512 + o0 + r]       = q0[r];
                p3s[(size_t)(g0+1)*512 + o0 + r]   = s1[r];
                p3q[(size_t)(g0+1)*512 + o0 + r]   = q1[r];
            }
        }
    }
    __syncthreads();   // all B3 reads done; SB becomes OT

    // write bias-added acc3 bf16 into OT [row=(g-g0)*32+l][o]
    #pragma unroll
    for (int mt = 0; mt < 8; ++mt) {
        const int o0 = wave*128 + mt*16 + quad*4;
        #pragma unroll
        for (int nt = 0; nt < 4; ++nt) {
            const int row = (nt >> 1)*32 + (nt & 1)*16 + m;
            *(unsigned long long*)&OT[row*520 + o0] =
                pack4bf(acc3[mt][nt][0], acc3[mt][nt][1], acc3[mt][nt][2], acc3[mt][nt][3]);
        }
    }
    __syncthreads();

    // coalesced readback: 256 threads, each 128 shorts (256 B contiguous in global)
    {
        const int row = t >> 2, seg = t & 3;
        const int g = g0 + (row >> 5), l = row & 31;
        const unsigned short* src = &OT[row*520 + seg*128];
        unsigned short* dst = h3b + (size_t)g*16384 + l*512 + seg*128;
        #pragma unroll
        for (int j = 0; j < 16; ++j)
            *(uint4*)(dst + j*8) = *(const uint4*)(src + j*8);
    }
}

// ---------------------------------------------------------------- K5: 2 groups/block. MFMA conv4 + fg2 + algebraic knn branch
__global__ __launch_bounds__(384, 2) void k5_mfma(
    const unsigned short* __restrict__ h3b,
    const float* __restrict__ scale3, const float* __restrict__ shift3,
    const unsigned short* __restrict__ W4b, const float* __restrict__ b4,
    const int* __restrict__ idxw,
    float* __restrict__ fg2, float* __restrict__ A,
    float* __restrict__ S1p, float* __restrict__ S2p)
{
    const int g0 = blockIdx.x * 2;
    const int t = threadIdx.x;
    __shared__ __align__(16) unsigned short SB[33280];   // 66560 B
    unsigned short* B4 = SB;                              // [64][520] staging
    unsigned short* XT = SB;                              // [g][o*40 + l], g stride 15360
    unsigned short* Mm = SB + 30720;                      // [g][l*40 + m], g stride 1280
    __shared__ int icnt[2][32];
    __shared__ float r1[2][6], r2[2][6];

    for (int i = t; i < 4096; i += 384) {
        const int l = i >> 6, c8 = (i & 63) * 8;
        const int g = g0 + (l >> 5);
        s16x8 hv = *(const s16x8*)(h3b + (size_t)g*16384 + (l & 31)*512 + c8);
        unsigned short ov[8];
        #pragma unroll
        for (int e = 0; e < 8; ++e) {
            int c = c8 + e;
            float v = fmaxf(fmaf(bf2f((unsigned short)hv[e]), scale3[c], shift3[c]), 0.f);
            ov[e] = f2bf(v);
        }
        uint4 o4;
        o4.x = (unsigned)ov[0] | ((unsigned)ov[1] << 16);
        o4.y = (unsigned)ov[2] | ((unsigned)ov[3] << 16);
        o4.z = (unsigned)ov[4] | ((unsigned)ov[5] << 16);
        o4.w = (unsigned)ov[6] | ((unsigned)ov[7] << 16);
        *(uint4*)&B4[l*520 + c8] = o4;
    }
    if (t < 64) icnt[t >> 5][t & 31] = 0;
    __syncthreads();

    const int wave = t >> 6;
    const int lane = t & 63;
    const int m    = lane & 15;
    const int quad = lane >> 4;

    f32x4 acc4[4][4];
    #pragma unroll
    for (int mt = 0; mt < 4; ++mt)
        #pragma unroll
        for (int n = 0; n < 4; ++n)
            acc4[mt][n] = (f32x4){0.f, 0.f, 0.f, 0.f};

    #pragma unroll 4
    for (int kt = 0; kt < 16; ++kt) {
        s16x8 bv[4];
        #pragma unroll
        for (int nt = 0; nt < 4; ++nt)
            bv[nt] = *(const s16x8*)&B4[(nt*16 + m)*520 + kt*32 + quad*8];
        #pragma unroll
        for (int mt = 0; mt < 4; ++mt) {
            s16x8 av = *(const s16x8*)(W4b + (size_t)(wave*64 + mt*16 + m)*512 + kt*32 + quad*8);
            #pragma unroll
            for (int nt = 0; nt < 4; ++nt)
                acc4[mt][nt] = __builtin_amdgcn_mfma_f32_16x16x32_bf16(av, bv[nt], acc4[mt][nt], 0, 0, 0);
        }
    }

    #pragma unroll
    for (int mt = 0; mt < 4; ++mt) {
        const int o0 = wave*64 + mt*16 + quad*4;
        float f0[4], f1[4];
        #pragma unroll
        for (int r = 0; r < 4; ++r) {
            float bb = b4[o0 + r];
            #pragma unroll
            for (int nt = 0; nt < 4; ++nt) acc4[mt][nt][r] += bb;
            f0[r] = fmaxf(acc4[mt][0][r], acc4[mt][1][r]);
            f1[r] = fmaxf(acc4[mt][2][r], acc4[mt][3][r]);
        }
        #pragma unroll
        for (int msk = 1; msk < 16; msk <<= 1)
            #pragma unroll
            for (int r = 0; r < 4; ++r) {
                f0[r] = fmaxf(f0[r], __shfl_xor(f0[r], msk, 16));
                f1[r] = fmaxf(f1[r], __shfl_xor(f1[r], msk, 16));
            }
        if (m == 0) {
            #pragma unroll
            for (int r = 0; r < 4; ++r) {
                fg2[(size_t)g0*384 + o0 + r]     = f0[r];
                fg2[(size_t)(g0+1)*384 + o0 + r] = f1[r];
            }
        }
    }
    __syncthreads();

    #pragma unroll
    for (int mt = 0; mt < 4; ++mt) {
        const int o0 = wave*64 + mt*16 + quad*4;
        #pragma unroll
        for (int nt = 0; nt < 4; ++nt) {
            const int g = nt >> 1;
            const int l = (nt & 1)*16 + m;
            unsigned short* xg = XT + g*15360;
            #pragma unroll
            for (int r = 0; r < 4; ++r)
                xg[(o0 + r)*40 + l] = f2bf(acc4[mt][nt][r]);
        }
    }
    if (t < 64) {
        const int g = t >> 5, l = t & 31;
        uint4 z = make_uint4(0u, 0u, 0u, 0u);
        #pragma unroll
        for (int i = 0; i < 5; ++i)
            *(uint4*)&Mm[g*1280 + l*40 + i*8] = z;
    }
    __syncthreads();

    if (t < 64) {
        const int g = t >> 5, l = t & 31;
        const int* ip = idxw + (size_t)(g0 + g)*256 + l*8;
        #pragma unroll
        for (int j = 0; j < 8; ++j) {
            int ix = ip[j];
            Mm[g*1280 + l*40 + ix] = 0x3F80;
            atomicAdd(&icnt[g][ix], 1);
        }
    }
    __syncthreads();

    float s1loc[2] = {0.f, 0.f}, s2loc[2] = {0.f, 0.f};
    #pragma unroll
    for (int g = 0; g < 2; ++g) {
        const float c0 = (float)icnt[g][m];
        const float c1 = (float)icnt[g][m + 16];
        const float w0 = c0 - 8.f, u0 = c0 + 8.f;
        const float w1 = c1 - 8.f, u1 = c1 + 8.f;
        #pragma unroll
        for (int mt = 0; mt < 4; ++mt) {
            const int o0 = wave*64 + mt*16 + quad*4;
            float Ap[4];
            #pragma unroll
            for (int r = 0; r < 4; ++r) {
                const float x0 = acc4[mt][g*2 + 0][r];
                const float x1 = acc4[mt][g*2 + 1][r];
                Ap[r] = w0*x0 + w1*x1;
                s1loc[g] += Ap[r];
                s2loc[g] += u0*x0*x0 + u1*x1*x1;
            }
            #pragma unroll
            for (int msk = 1; msk < 16; msk <<= 1)
                #pragma unroll
                for (int r = 0; r < 4; ++r)
                    Ap[r] += __shfl_xor(Ap[r], msk, 16);
            if (m == 0) {
                #pragma unroll
                for (int r = 0; r < 4; ++r)
                    A[(size_t)(g0 + g)*384 + o0 + r] = Ap[r];
            }
        }
    }

    #pragma unroll
    for (int g = 0; g < 2; ++g) {
        const unsigned short* xg = XT + g*15360;
        float cross = 0.f;
        #pragma unroll
        for (int lt = 0; lt < 2; ++lt) {
            s16x8 af = *(const s16x8*)&Mm[g*1280 + (lt*16 + m)*40 + quad*8];
            #pragma unroll
            for (int i = 0; i < 4; ++i) {
                const int oc = (wave*4 + i)*16 + m;
                s16x8 bfv = *(const s16x8*)&xg[oc*40 + quad*8];
                f32x4 sa = __builtin_amdgcn_mfma_f32_16x16x32_bf16(
                    af, bfv, (f32x4){0.f, 0.f, 0.f, 0.f}, 0, 0, 0);
                #pragma unroll
                for (int r = 0; r < 4; ++r) {
                    const int lp = lt*16 + quad*4 + r;
                    cross = fmaf(bf2f(xg[oc*40 + lp]), sa[r], cross);
                }
            }
        }
        s2loc[g] -= 2.f * cross;
    }

    #pragma unroll
    for (int g = 0; g < 2; ++g) {
        float sA = s1loc[g], sQ = s2loc[g];
        #pragma unroll
        for (int off = 32; off > 0; off >>= 1) {
            sA += __shfl_down(sA, off, 64);
            sQ += __shfl_down(sQ, off, 64);
        }
        if (lane == 0) { r1[g][wave] = sA; r2[g][wave] = sQ; }
    }
    __syncthreads();
    if (t < 2) {
        float S = 0.f, Q = 0.f;
        #pragma unroll
        for (int w = 0; w < 6; ++w) { S += r1[t][w]; Q += r2[t][w]; }
        S1p[g0 + t] = S;
        S2p[g0 + t] = Q;
    }
}

// ---------------------------------------------------------------- K6: global std over dx (ddof=1)
__global__ void k6_std(const float* __restrict__ S1p, const float* __restrict__ S2p,
                       float* __restrict__ stdv)
{
    const int t = threadIdx.x;
    double s = 0.0, q = 0.0;
    for (int i = t; i < 1024; i += 256) { s += (double)S1p[i]; q += (double)S2p[i]; }
    #pragma unroll
    for (int off = 32; off > 0; off >>= 1) {
        s += __shfl_down(s, off, 64);
        q += __shfl_down(q, off, 64);
    }
    __shared__ double rs[4], rq[4];
    const int wid = t >> 6;
    if ((t & 63) == 0) { rs[wid] = s; rq[wid] = q; }
    __syncthreads();
    if (t == 0) {
        double S = rs[0]+rs[1]+rs[2]+rs[3];
        double Q = rq[0]+rq[1]+rq[2]+rq[3];
        const double N = 1024.0 * 32.0 * 8.0 * 384.0;
        double var = (Q - S*S/N) / (N - 1.0);
        stdv[0] = (float)sqrt(var);
    }
}

// ---------------------------------------------------------------- K7: fused head MFMA GEMM: M=384 (Wf rows), K=768, N=32 groups/block
// grid 32, block 384 (6 waves). LDS: xfb bf16 [32][776] union OT fp32 [32][388]
__global__ __launch_bounds__(384) void k7_fused(
    const float* __restrict__ fg2, const float* __restrict__ A,
    const float* __restrict__ alpha, const float* __restrict__ beta_aff,
    const float* __restrict__ stdv,
    const unsigned short* __restrict__ Wfb, const float* __restrict__ bf,
    float* __restrict__ hf, float* __restrict__ pfs, float* __restrict__ pfq)
{
    const int blk = blockIdx.x;
    const int g0 = blk * 32;
    const int t = threadIdx.x;
    __shared__ __align__(16) char smem[49664];
    unsigned short* xfb = (unsigned short*)smem;   // [32][776]
    float* OTf = (float*)smem;                     // [32][388]

    const float inv = 1.f / (256.f * (stdv[0] + EPS));
    // stage xf bf16: row g (32), cols 0..767 = [fg2 | alpha*inv*A + beta]
    for (int i = t; i < 32*96; i += 384) {
        const int row = i / 96, c8 = (i % 96) * 8;
        const int g = g0 + row;
        float e[8];
        if (c8 < 384) {
            const float4* s0 = (const float4*)(fg2 + (size_t)g*384 + c8);
            float4 v0 = s0[0], v1 = s0[1];
            e[0]=v0.x; e[1]=v0.y; e[2]=v0.z; e[3]=v0.w;
            e[4]=v1.x; e[5]=v1.y; e[6]=v1.z; e[7]=v1.w;
        } else {
            const int cc = c8 - 384;
            const float4* s0 = (const float4*)(A + (size_t)g*384 + cc);
            float4 v0 = s0[0], v1 = s0[1];
            float av[8] = {v0.x,v0.y,v0.z,v0.w,v1.x,v1.y,v1.z,v1.w};
            #pragma unroll
            for (int j = 0; j < 8; ++j)
                e[j] = fmaf(alpha[cc+j] * inv, av[j], beta_aff[cc+j]);
        }
        uint4 o4;
        o4.x = (unsigned)f2bf(e[0]) | ((unsigned)f2bf(e[1]) << 16);
        o4.y = (unsigned)f2bf(e[2]) | ((unsigned)f2bf(e[3]) << 16);
        o4.z = (unsigned)f2bf(e[4]) | ((unsigned)f2bf(e[5]) << 16);
        o4.w = (unsigned)f2bf(e[6]) | ((unsigned)f2bf(e[7]) << 16);
        *(uint4*)&xfb[row*776 + c8] = o4;
    }
    __syncthreads();

    const int wave = t >> 6;
    const int lane = t & 63;
    const int m    = lane & 15;
    const int quad = lane >> 4;

    // MFMA: o = wave*64 + mt*16 + m (A rows), g-col = nt*16 + m
    f32x4 acc[4][2];
    #pragma unroll
    for (int mt = 0; mt < 4; ++mt)
        #pragma unroll
        for (int nt = 0; nt < 2; ++nt)
            acc[mt][nt] = (f32x4){0.f, 0.f, 0.f, 0.f};

    #pragma unroll 4
    for (int kt = 0; kt < 24; ++kt) {
        s16x8 bv[2];
        #pragma unroll
        for (int nt = 0; nt < 2; ++nt)
            bv[nt] = *(const s16x8*)&xfb[(nt*16 + m)*776 + kt*32 + quad*8];
        #pragma unroll
        for (int mt = 0; mt < 4; ++mt) {
            s16x8 av = *(const s16x8*)(Wfb + (size_t)(wave*64 + mt*16 + m)*768 + kt*32 + quad*8);
            #pragma unroll
            for (int nt = 0; nt < 2; ++nt)
                acc[mt][nt] = __builtin_amdgcn_mfma_f32_16x16x32_bf16(av, bv[nt], acc[mt][nt], 0, 0, 0);
        }
    }

    // bias + stats (over this block's 32 groups)
    #pragma unroll
    for (int mt = 0; mt < 4; ++mt) {
        const int o0 = wave*64 + mt*16 + quad*4;
        float s[4], q[4];
        #pragma unroll
        for (int r = 0; r < 4; ++r) {
            float bb = bf[o0 + r];
            acc[mt][0][r] += bb;
            acc[mt][1][r] += bb;
            s[r] = acc[mt][0][r] + acc[mt][1][r];
            q[r] = acc[mt][0][r]*acc[mt][0][r] + acc[mt][1][r]*acc[mt][1][r];
        }
        #pragma unroll
        for (int msk = 1; msk < 16; msk <<= 1)
            #pragma unroll
            for (int r = 0; r < 4; ++r) {
                s[r] += __shfl_xor(s[r], msk, 16);
                q[r] += __shfl_xor(q[r], msk, 16);
            }
        if (m == 0) {
            #pragma unroll
            for (int r = 0; r < 4; ++r) {
                pfs[(size_t)blk*384 + o0 + r] = s[r];
                pfq[(size_t)blk*384 + o0 + r] = q[r];
            }
        }
    }
    __syncthreads();   // xfb reads done; smem becomes OTf

    // transpose via LDS: OTf[g-row][o], stride 388
    #pragma unroll
    for (int mt = 0; mt < 4; ++mt) {
        const int o0 = wave*64 + mt*16 + quad*4;
        #pragma unroll
        for (int nt = 0; nt < 2; ++nt) {
            const int row = nt*16 + m;
            #pragma unroll
            for (int r = 0; r < 4; ++r)
                OTf[row*388 + o0 + r] = acc[mt][nt][r];
        }
    }
    __syncthreads();

    // coalesced hf store: flat idx trick (row*388 + col*4 == idx*4 + row)
    {
        float* dst = hf + (size_t)g0*384;
        for (int k = 0; k < 8; ++k) {
            const int i = t + k*384;           // float4 index in [0, 3072)
            const int row = i / 96;
            float4 v = *(const float4*)&OTf[i*4 + row*4];
            *(float4*)(dst + i*4) = v;
        }
    }
}

// ---------------------------------------------------------------- K9: BNf + relu -> out
__global__ __launch_bounds__(384) void k9_out(
    const float* __restrict__ hf, const float* __restrict__ scalef,
    const float* __restrict__ shiftf, float* __restrict__ out)
{
    const int b = blockIdx.x, t = threadIdx.x;
    float v = fmaf(hf[(size_t)b*384 + t], scalef[t], shiftf[t]);
    out[(size_t)b*384 + t] = fmaxf(v, 0.f);
}

extern "C" void kernel_launch(void* const* d_in, const int* in_sizes, int n_in,
                              void* d_out, int out_size, void* d_ws, size_t ws_size,
                              hipStream_t stream) {
    const float* pg      = (const float*)d_in[0];
    const float* W1      = (const float*)d_in[1];
    const float* b1      = (const float*)d_in[2];
    const float* gamma1  = (const float*)d_in[3];
    const float* beta1   = (const float*)d_in[4];
    const float* W2      = (const float*)d_in[5];
    const float* b2      = (const float*)d_in[6];
    const float* W3      = (const float*)d_in[7];
    const float* b3      = (const float*)d_in[8];
    const float* gamma3  = (const float*)d_in[9];
    const float* beta3   = (const float*)d_in[10];
    const float* W4      = (const float*)d_in[11];
    const float* b4      = (const float*)d_in[12];
    const float* alpha   = (const float*)d_in[13];
    const float* beta_af = (const float*)d_in[14];
    const float* Wf      = (const float*)d_in[15];
    const float* bf      = (const float*)d_in[16];
    const float* gammaf  = (const float*)d_in[17];
    const float* betaf   = (const float*)d_in[18];
    float* out = (float*)d_out;

    float* w = (float*)d_ws;
    float* h1     = w;  w += 1024*4096;                               // 16 MB [b][l][c]
    unsigned short* h3b = (unsigned short*)w; w += 1024*16384/2;      // 32 MB bf16 [g][l][o]
    unsigned short* W2b = (unsigned short*)w; w += 32768/2;
    unsigned short* W3b = (unsigned short*)w; w += 262144/2;
    unsigned short* W4b = (unsigned short*)w; w += 196608/2;
    unsigned short* Wfb = (unsigned short*)w; w += 294912/2;
    float* hf     = w;  w += 1024*384;
    float* fg2    = w;  w += 1024*384;
    float* A      = w;  w += 1024*384;
    float* p1s    = w;  w += 1024*128;   // [b][c]
    float* p1q    = w;  w += 1024*128;
    float* p3s    = w;  w += 1024*512;   // [g][o]
    float* p3q    = w;  w += 1024*512;
    float* pfs    = w;  w += 32*384;     // [blk][o]
    float* pfq    = w;  w += 32*384;
    float* S1p    = w;  w += 1024;
    float* S2p    = w;  w += 1024;
    float* scale1 = w;  w += 128;
    float* shift1 = w;  w += 128;
    float* scale3 = w;  w += 512;
    float* shift3 = w;  w += 512;
    float* scalef = w;  w += 384;
    float* shiftf = w;  w += 384;
    float* stdv   = w;  w += 4;
    int*   idxw   = (int*)w;  w += 1024*256;

    hipLaunchKernelGGL(kprep, dim3(1152), dim3(256), 0, stream,
                       W2, W3, W4, Wf, W2b, W3b, W4b, Wfb);
    hipLaunchKernelGGL(k1_conv1_knn, dim3(1024), dim3(128), 0, stream,
                       pg, W1, b1, h1, p1s, p1q, idxw);
    hipLaunchKernelGGL(k_bn_fin2, dim3(8), dim3(256), 0, stream,
                       p1s, p1q, 1024, 128, 1.f/32768.f, gamma1, beta1, scale1, shift1);
    hipLaunchKernelGGL(k3_mfma, dim3(512), dim3(256), 0, stream,
                       h1, scale1, shift1, W2b, b2, W3b, b3, h3b, p3s, p3q);
    hipLaunchKernelGGL(k_bn_fin2, dim3(32), dim3(256), 0, stream,
                       p3s, p3q, 1024, 512, 1.f/32768.f, gamma3, beta3, scale3, shift3);
    hipLaunchKernelGGL(k5_mfma, dim3(512), dim3(384), 0, stream,
                       h3b, scale3, shift3, W4b, b4, idxw, fg2, A, S1p, S2p);
    hipLaunchKernelGGL(k6_std, dim3(1), dim3(256), 0, stream, S1p, S2p, stdv);
    hipLaunchKernelGGL(k7_fused, dim3(32), dim3(384), 0, stream,
                       fg2, A, alpha, beta_af, stdv, Wfb, bf, hf, pfs, pfq);
    hipLaunchKernelGGL(k_bn_fin2, dim3(24), dim3(256), 0, stream,
                       pfs, pfq, 32, 384, 1.f/1024.f, gammaf, betaf, scalef, shiftf);
    hipLaunchKernelGGL(k9_out, dim3(1024), dim3(384), 0, stream,
                       hf, scalef, shiftf, out);
}

// Round 6
// 272.511 us; speedup vs baseline: 3.8907x; 1.1365x over previous
//
#include <hip/hip_runtime.h>
#include <math.h>

#define EPS 1e-5f

typedef __attribute__((ext_vector_type(8))) short s16x8;   // 8 bf16 (4 VGPRs)
typedef __attribute__((ext_vector_type(4))) float f32x4;   // MFMA C/D

__device__ __forceinline__ unsigned short f2bf(float x) {
    unsigned u = __float_as_uint(x);
    u += 0x7fffu + ((u >> 16) & 1u);           // round-to-nearest-even
    return (unsigned short)(u >> 16);
}
__device__ __forceinline__ float bf2f(unsigned short h) {
    return __uint_as_float(((unsigned)h) << 16);
}
__device__ __forceinline__ unsigned long long pack4bf(float a, float b, float c, float d) {
    return (unsigned long long)f2bf(a)
         | ((unsigned long long)f2bf(b) << 16)
         | ((unsigned long long)f2bf(c) << 32)
         | ((unsigned long long)f2bf(d) << 48);
}

// ---------------------------------------------------------------- kprep: fp32 weights -> bf16 (incl. Wf)
__global__ __launch_bounds__(256) void kprep(
    const float* __restrict__ W2, const float* __restrict__ W3, const float* __restrict__ W4,
    const float* __restrict__ Wf,
    unsigned short* __restrict__ W2b, unsigned short* __restrict__ W3b,
    unsigned short* __restrict__ W4b, unsigned short* __restrict__ Wfb)
{
    int i = blockIdx.x * 256 + threadIdx.x;
    if (i < 32768)  W2b[i] = f2bf(W2[i]);
    if (i < 262144) W3b[i] = f2bf(W3[i]);
    if (i < 196608) W4b[i] = f2bf(W4[i]);
    if (i < 294912) Wfb[i] = f2bf(Wf[i]);
}

// ---------------------------------------------------------------- K1: conv1 (3->128) pre-BN + partial stats + knn indices
__global__ __launch_bounds__(128) void k1_conv1_knn(
    const float* __restrict__ pg, const float* __restrict__ W1,
    const float* __restrict__ b1,
    float* __restrict__ h1, float* __restrict__ p1s, float* __restrict__ p1q,
    int* __restrict__ idxw)
{
    const int b = blockIdx.x;
    const int t = threadIdx.x;
    __shared__ float pgs[96];
    __shared__ float sqs[32];
    if (t < 96) pgs[t] = pg[b * 96 + t];
    __syncthreads();
    if (t < 32) {
        float x = pgs[t*3+0], y = pgs[t*3+1], z = pgs[t*3+2];
        sqs[t] = x*x + y*y + z*z;
    }
    __syncthreads();
    {
        const float w0 = W1[t*3+0], w1 = W1[t*3+1], w2 = W1[t*3+2];
        const float bb = b1[t];
        float s = 0.f, q = 0.f;
        float* hcol = h1 + (size_t)b*4096 + t;
        #pragma unroll
        for (int l = 0; l < 32; ++l) {
            float v = fmaf(w2, pgs[l*3+2], fmaf(w1, pgs[l*3+1], fmaf(w0, pgs[l*3+0], bb)));
            hcol[l*128] = v; s += v; q += v*v;
        }
        p1s[b*128 + t] = s;
        p1q[b*128 + t] = q;
    }
    if (t < 32) {
        const float xl = pgs[t*3+0], yl = pgs[t*3+1], zl = pgs[t*3+2];
        const float sql = sqs[t];
        float dist[32];
        #pragma unroll
        for (int m = 0; m < 32; ++m) {
            float dot = xl*pgs[m*3+0] + yl*pgs[m*3+1] + zl*pgs[m*3+2];
            dist[m] = sql + sqs[m] - 2.f*dot;
        }
        unsigned used = 0u;
        int* orow = idxw + b*256 + t*8;
        #pragma unroll
        for (int j = 0; j < 8; ++j) {
            float best = 3.4e38f; int bi = 0;
            #pragma unroll
            for (int m = 0; m < 32; ++m) {
                if (!((used >> m) & 1u) && dist[m] < best) { best = dist[m]; bi = m; }
            }
            used |= (1u << bi);
            orow[j] = bi;
        }
    }
}

// ---------------------------------------------------------------- BN finalize, partials layout [part][chan]
__global__ __launch_bounds__(256) void k_bn_fin2(
    const float* __restrict__ ps, const float* __restrict__ pq,
    int nPart, int nChan, float invN,
    const float* __restrict__ gamma, const float* __restrict__ beta,
    float* __restrict__ scale, float* __restrict__ shift)
{
    const int ob = blockIdx.x * 16;
    const int t = threadIdx.x;
    const int co = t & 15, i0 = t >> 4;
    float s = 0.f, q = 0.f;
    for (int i = i0; i < nPart; i += 16) {
        s += ps[(size_t)i*nChan + ob + co];
        q += pq[(size_t)i*nChan + ob + co];
    }
    __shared__ float ss[16][17], qs[16][17];
    ss[i0][co] = s; qs[i0][co] = q;
    __syncthreads();
    if (t < 16) {
        float S = 0.f, Q = 0.f;
        #pragma unroll
        for (int i = 0; i < 16; ++i) { S += ss[i][t]; Q += qs[i][t]; }
        const int o = ob + t;
        float mu  = S * invN;
        float var = Q * invN - mu*mu;
        float sc  = gamma[o] * rsqrtf(var + EPS);
        scale[o] = sc;
        shift[o] = beta[o] - mu * sc;
    }
}

// ---------------------------------------------------------------- K3: 2 groups/block, 8 waves. MFMA conv2 + fg + MFMA conv3.
// h3b written in MFMA fragment order: 16 shorts per (wave*4+mt, lane) unit:
//   shorts [nt*4 + r], value = conv3out(o = wave*64+mt*16+quad*4+r, row = nt*16+m)
// grid 512, block 512. LDS 66.5 KB -> 2 blocks/CU = 16 waves/CU.
__global__ __launch_bounds__(512, 2) void k3_mfma(
    const float* __restrict__ h1,
    const float* __restrict__ scale1, const float* __restrict__ shift1,
    const unsigned short* __restrict__ W2b, const float* __restrict__ b2,
    const unsigned short* __restrict__ W3b, const float* __restrict__ b3,
    unsigned short* __restrict__ h3b, float* __restrict__ p3s, float* __restrict__ p3q)
{
    const int g0 = blockIdx.x * 2;
    const int t = threadIdx.x;
    __shared__ __align__(16) unsigned short SB[64*520];
    unsigned short* B1 = SB;   // [64][136] during conv2
    unsigned short* B3 = SB;   // [64][520] during conv3

    // ---- stage x1 = relu(BN1(h1)) bf16, 64 rows x 128 c
    {
        const int l = t >> 3, c0 = (t & 7) * 16;
        const int g = g0 + (l >> 5);
        const float4* src = (const float4*)(h1 + (size_t)g*4096 + (l & 31)*128 + c0);
        #pragma unroll
        for (int i = 0; i < 4; ++i) {
            float4 v = src[i];
            int c = c0 + i*4;
            float e0 = fmaxf(fmaf(v.x, scale1[c+0], shift1[c+0]), 0.f);
            float e1 = fmaxf(fmaf(v.y, scale1[c+1], shift1[c+1]), 0.f);
            float e2 = fmaxf(fmaf(v.z, scale1[c+2], shift1[c+2]), 0.f);
            float e3 = fmaxf(fmaf(v.w, scale1[c+3], shift1[c+3]), 0.f);
            *(unsigned long long*)&B1[l*136 + c] = pack4bf(e0, e1, e2, e3);
        }
    }
    __syncthreads();

    const int wave = t >> 6;
    const int lane = t & 63;
    const int m    = lane & 15;
    const int quad = lane >> 4;

    // ---- conv2: M=256 (wave: 2 M-tiles), N=64, K=128
    f32x4 acc2[2][4];
    #pragma unroll
    for (int mt = 0; mt < 2; ++mt)
        #pragma unroll
        for (int n = 0; n < 4; ++n)
            acc2[mt][n] = (f32x4){0.f, 0.f, 0.f, 0.f};

    #pragma unroll
    for (int kt = 0; kt < 4; ++kt) {
        s16x8 bv[4];
        #pragma unroll
        for (int nt = 0; nt < 4; ++nt)
            bv[nt] = *(const s16x8*)&B1[(nt*16 + m)*136 + kt*32 + quad*8];
        #pragma unroll
        for (int mt = 0; mt < 2; ++mt) {
            s16x8 av = *(const s16x8*)(W2b + (size_t)(wave*32 + mt*16 + m)*128 + kt*32 + quad*8);
            #pragma unroll
            for (int nt = 0; nt < 4; ++nt)
                acc2[mt][nt] = __builtin_amdgcn_mfma_f32_16x16x32_bf16(av, bv[nt], acc2[mt][nt], 0, 0, 0);
        }
    }
    __syncthreads();   // B1 reads done; SB becomes B3

    // ---- epilogue conv2: bias, write f2 (c 256..511), fg replicated (c 0..255)
    #pragma unroll
    for (int mt = 0; mt < 2; ++mt) {
        const int o0 = wave*32 + mt*16 + quad*4;
        #pragma unroll
        for (int r = 0; r < 4; ++r) {
            float bb = b2[o0 + r];
            #pragma unroll
            for (int nt = 0; nt < 4; ++nt) acc2[mt][nt][r] += bb;
        }
        #pragma unroll
        for (int nt = 0; nt < 4; ++nt) {
            const int row = nt*16 + m;
            *(unsigned long long*)&B3[row*520 + 256 + o0] =
                pack4bf(acc2[mt][nt][0], acc2[mt][nt][1], acc2[mt][nt][2], acc2[mt][nt][3]);
        }
        float f0[4], f1[4];
        #pragma unroll
        for (int r = 0; r < 4; ++r) {
            f0[r] = fmaxf(acc2[mt][0][r], acc2[mt][1][r]);
            f1[r] = fmaxf(acc2[mt][2][r], acc2[mt][3][r]);
        }
        #pragma unroll
        for (int msk = 1; msk < 16; msk <<= 1)
            #pragma unroll
            for (int r = 0; r < 4; ++r) {
                f0[r] = fmaxf(f0[r], __shfl_xor(f0[r], msk, 16));
                f1[r] = fmaxf(f1[r], __shfl_xor(f1[r], msk, 16));
            }
        unsigned long long pk0 = pack4bf(f0[0], f0[1], f0[2], f0[3]);
        unsigned long long pk1 = pack4bf(f1[0], f1[1], f1[2], f1[3]);
        *(unsigned long long*)&B3[(m     )*520 + o0] = pk0;
        *(unsigned long long*)&B3[(m + 16)*520 + o0] = pk0;
        *(unsigned long long*)&B3[(m + 32)*520 + o0] = pk1;
        *(unsigned long long*)&B3[(m + 48)*520 + o0] = pk1;
    }
    __syncthreads();

    // ---- conv3: M=512 (wave: 4 M-tiles), N=64, K=512
    f32x4 acc3[4][4];
    #pragma unroll
    for (int mt = 0; mt < 4; ++mt)
        #pragma unroll
        for (int n = 0; n < 4; ++n)
            acc3[mt][n] = (f32x4){0.f, 0.f, 0.f, 0.f};

    #pragma unroll 4
    for (int kt = 0; kt < 16; ++kt) {
        s16x8 bv[4];
        #pragma unroll
        for (int nt = 0; nt < 4; ++nt)
            bv[nt] = *(const s16x8*)&B3[(nt*16 + m)*520 + kt*32 + quad*8];
        #pragma unroll
        for (int mt = 0; mt < 4; ++mt) {
            s16x8 av = *(const s16x8*)(W3b + (size_t)(wave*64 + mt*16 + m)*512 + kt*32 + quad*8);
            #pragma unroll
            for (int nt = 0; nt < 4; ++nt)
                acc3[mt][nt] = __builtin_amdgcn_mfma_f32_16x16x32_bf16(av, bv[nt], acc3[mt][nt], 0, 0, 0);
        }
    }

    // ---- epilogue conv3: bias, fragment-order h3b store (perfectly coalesced), stats
    unsigned short* dst = h3b + (size_t)blockIdx.x * 32768;
    #pragma unroll
    for (int mt = 0; mt < 4; ++mt) {
        const int o0 = wave*64 + mt*16 + quad*4;
        float s0[4], q0[4], s1[4], q1[4];
        #pragma unroll
        for (int r = 0; r < 4; ++r) {
            float bb = b3[o0 + r];
            #pragma unroll
            for (int nt = 0; nt < 4; ++nt) acc3[mt][nt][r] += bb;
            s0[r] = acc3[mt][0][r] + acc3[mt][1][r];
            q0[r] = acc3[mt][0][r]*acc3[mt][0][r] + acc3[mt][1][r]*acc3[mt][1][r];
            s1[r] = acc3[mt][2][r] + acc3[mt][3][r];
            q1[r] = acc3[mt][2][r]*acc3[mt][2][r] + acc3[mt][3][r]*acc3[mt][3][r];
        }
        // fragment store: 32 B per lane, lane-consecutive
        {
            unsigned long long u0 = pack4bf(acc3[mt][0][0], acc3[mt][0][1], acc3[mt][0][2], acc3[mt][0][3]);
            unsigned long long u1 = pack4bf(acc3[mt][1][0], acc3[mt][1][1], acc3[mt][1][2], acc3[mt][1][3]);
            unsigned long long u2 = pack4bf(acc3[mt][2][0], acc3[mt][2][1], acc3[mt][2][2], acc3[mt][2][3]);
            unsigned long long u3 = pack4bf(acc3[mt][3][0], acc3[mt][3][1], acc3[mt][3][2], acc3[mt][3][3]);
            unsigned short* p = dst + (size_t)(((wave*4 + mt)*64 + lane)) * 16;
            *(uint4*)(p)     = make_uint4((unsigned)u0, (unsigned)(u0 >> 32), (unsigned)u1, (unsigned)(u1 >> 32));
            *(uint4*)(p + 8) = make_uint4((unsigned)u2, (unsigned)(u2 >> 32), (unsigned)u3, (unsigned)(u3 >> 32));
        }
        #pragma unroll
        for (int msk = 1; msk < 16; msk <<= 1)
            #pragma unroll
            for (int r = 0; r < 4; ++r) {
                s0[r] += __shfl_xor(s0[r], msk, 16);
                q0[r] += __shfl_xor(q0[r], msk, 16);
                s1[r] += __shfl_xor(s1[r], msk, 16);
                q1[r] += __shfl_xor(q1[r], msk, 16);
            }
        if (m == 0) {
            #pragma unroll
            for (int r = 0; r < 4; ++r) {
                p3s[(size_t)g0*512 + o0 + r]       = s0[r];
                p3q[(size_t)g0*512 + o0 + r]       = q0[r];
                p3s[(size_t)(g0+1)*512 + o0 + r]   = s1[r];
                p3q[(size_t)(g0+1)*512 + o0 + r]   = q1[r];
            }
        }
    }
}

// ---------------------------------------------------------------- K5: 2 groups/block, 12 waves. MFMA conv4 + fg2 + algebraic knn branch.
// Reads fragment-order h3b (same block<->group alignment as k3).
__global__ __launch_bounds__(768, 2) void k5_mfma(
    const unsigned short* __restrict__ h3b,
    const float* __restrict__ scale3, const float* __restrict__ shift3,
    const unsigned short* __restrict__ W4b, const float* __restrict__ b4,
    const int* __restrict__ idxw,
    float* __restrict__ fg2, float* __restrict__ A,
    float* __restrict__ S1p, float* __restrict__ S2p)
{
    const int g0 = blockIdx.x * 2;
    const int t = threadIdx.x;
    __shared__ __align__(16) unsigned short SB[33280];   // 66560 B
    unsigned short* B4 = SB;                              // [64][520] staging
    unsigned short* XT = SB;                              // [g][o*40 + l], g stride 15360
    unsigned short* Mm = SB + 30720;                      // [g][l*40 + m], g stride 1280
    __shared__ int icnt[2][32];
    __shared__ float r1[2][12], r2[2][12];

    // ---- stage x3 = relu(BN3(h3b_frag)) bf16 [row64][c512]
    {
        const uint4* src = (const uint4*)(h3b + (size_t)blockIdx.x * 32768);
        for (int i = t; i < 4096; i += 768) {
            uint4 hv = src[i];
            const int flat16 = i >> 1, half = i & 1;
            const int ln = flat16 & 63, m2 = ln & 15, q2 = ln >> 4;
            const int wm = flat16 >> 6;                    // wave*4+mt of k3 conv3
            const int o0 = (wm >> 2)*64 + (wm & 3)*16 + q2*4;
            const float4 sc = *(const float4*)(scale3 + o0);
            const float4 sh = *(const float4*)(shift3 + o0);
            const int rowa = (half*2)*16 + m2;             // nt = half*2
            float a0 = fmaxf(fmaf(bf2f((unsigned short)(hv.x       )), sc.x, sh.x), 0.f);
            float a1 = fmaxf(fmaf(bf2f((unsigned short)(hv.x >> 16 )), sc.y, sh.y), 0.f);
            float a2 = fmaxf(fmaf(bf2f((unsigned short)(hv.y       )), sc.z, sh.z), 0.f);
            float a3 = fmaxf(fmaf(bf2f((unsigned short)(hv.y >> 16 )), sc.w, sh.w), 0.f);
            float b0 = fmaxf(fmaf(bf2f((unsigned short)(hv.z       )), sc.x, sh.x), 0.f);
            float b1 = fmaxf(fmaf(bf2f((unsigned short)(hv.z >> 16 )), sc.y, sh.y), 0.f);
            float b2 = fmaxf(fmaf(bf2f((unsigned short)(hv.w       )), sc.z, sh.z), 0.f);
            float b3 = fmaxf(fmaf(bf2f((unsigned short)(hv.w >> 16 )), sc.w, sh.w), 0.f);
            *(unsigned long long*)&B4[rowa*520 + o0]        = pack4bf(a0, a1, a2, a3);
            *(unsigned long long*)&B4[(rowa + 16)*520 + o0] = pack4bf(b0, b1, b2, b3);
        }
    }
    if (t < 64) icnt[t >> 5][t & 31] = 0;
    __syncthreads();

    const int wave = t >> 6;
    const int lane = t & 63;
    const int m    = lane & 15;
    const int quad = lane >> 4;

    // ---- conv4: M=384 (wave: 2 M-tiles), N=64, K=512
    f32x4 acc4[2][4];
    #pragma unroll
    for (int mt = 0; mt < 2; ++mt)
        #pragma unroll
        for (int n = 0; n < 4; ++n)
            acc4[mt][n] = (f32x4){0.f, 0.f, 0.f, 0.f};

    #pragma unroll 4
    for (int kt = 0; kt < 16; ++kt) {
        s16x8 bv[4];
        #pragma unroll
        for (int nt = 0; nt < 4; ++nt)
            bv[nt] = *(const s16x8*)&B4[(nt*16 + m)*520 + kt*32 + quad*8];
        #pragma unroll
        for (int mt = 0; mt < 2; ++mt) {
            s16x8 av = *(const s16x8*)(W4b + (size_t)(wave*32 + mt*16 + m)*512 + kt*32 + quad*8);
            #pragma unroll
            for (int nt = 0; nt < 4; ++nt)
                acc4[mt][nt] = __builtin_amdgcn_mfma_f32_16x16x32_bf16(av, bv[nt], acc4[mt][nt], 0, 0, 0);
        }
    }

    // ---- bias + fg2
    #pragma unroll
    for (int mt = 0; mt < 2; ++mt) {
        const int o0 = wave*32 + mt*16 + quad*4;
        float f0[4], f1[4];
        #pragma unroll
        for (int r = 0; r < 4; ++r) {
            float bb = b4[o0 + r];
            #pragma unroll
            for (int nt = 0; nt < 4; ++nt) acc4[mt][nt][r] += bb;
            f0[r] = fmaxf(acc4[mt][0][r], acc4[mt][1][r]);
            f1[r] = fmaxf(acc4[mt][2][r], acc4[mt][3][r]);
        }
        #pragma unroll
        for (int msk = 1; msk < 16; msk <<= 1)
            #pragma unroll
            for (int r = 0; r < 4; ++r) {
                f0[r] = fmaxf(f0[r], __shfl_xor(f0[r], msk, 16));
                f1[r] = fmaxf(f1[r], __shfl_xor(f1[r], msk, 16));
            }
        if (m == 0) {
            #pragma unroll
            for (int r = 0; r < 4; ++r) {
                fg2[(size_t)g0*384 + o0 + r]     = f0[r];
                fg2[(size_t)(g0+1)*384 + o0 + r] = f1[r];
            }
        }
    }
    __syncthreads();   // B4 reads done; SB becomes XT + Mm

    // ---- spill X^T bf16 [o][l] (stride 40), zero M
    #pragma unroll
    for (int mt = 0; mt < 2; ++mt) {
        const int o0 = wave*32 + mt*16 + quad*4;
        #pragma unroll
        for (int nt = 0; nt < 4; ++nt) {
            const int g = nt >> 1;
            const int l = (nt & 1)*16 + m;
            unsigned short* xg = XT + g*15360;
            #pragma unroll
            for (int r = 0; r < 4; ++r)
                xg[(o0 + r)*40 + l] = f2bf(acc4[mt][nt][r]);
        }
    }
    if (t < 64) {
        const int g = t >> 5, l = t & 31;
        uint4 z = make_uint4(0u, 0u, 0u, 0u);
        #pragma unroll
        for (int i = 0; i < 5; ++i)
            *(uint4*)&Mm[g*1280 + l*40 + i*8] = z;
    }
    __syncthreads();

    // ---- build M (0/1 bf16) + neighbor counts
    if (t < 64) {
        const int g = t >> 5, l = t & 31;
        const int* ip = idxw + (size_t)(g0 + g)*256 + l*8;
        #pragma unroll
        for (int j = 0; j < 8; ++j) {
            int ix = ip[j];
            Mm[g*1280 + l*40 + ix] = 0x3F80;
            atomicAdd(&icnt[g][ix], 1);
        }
    }
    __syncthreads();

    // ---- A + x^2 partials from registers
    float s1loc[2] = {0.f, 0.f}, s2loc[2] = {0.f, 0.f};
    #pragma unroll
    for (int g = 0; g < 2; ++g) {
        const float c0 = (float)icnt[g][m];
        const float c1 = (float)icnt[g][m + 16];
        const float w0 = c0 - 8.f, u0 = c0 + 8.f;
        const float w1 = c1 - 8.f, u1 = c1 + 8.f;
        #pragma unroll
        for (int mt = 0; mt < 2; ++mt) {
            const int o0 = wave*32 + mt*16 + quad*4;
            float Ap[4];
            #pragma unroll
            for (int r = 0; r < 4; ++r) {
                const float x0 = acc4[mt][g*2 + 0][r];
                const float x1 = acc4[mt][g*2 + 1][r];
                Ap[r] = w0*x0 + w1*x1;
                s1loc[g] += Ap[r];
                s2loc[g] += u0*x0*x0 + u1*x1*x1;
            }
            #pragma unroll
            for (int msk = 1; msk < 16; msk <<= 1)
                #pragma unroll
                for (int r = 0; r < 4; ++r)
                    Ap[r] += __shfl_xor(Ap[r], msk, 16);
            if (m == 0) {
                #pragma unroll
                for (int r = 0; r < 4; ++r)
                    A[(size_t)(g0 + g)*384 + o0 + r] = Ap[r];
            }
        }
    }

    // ---- cross term via MFMA: s = M X; cross += x .* s  (wave: 2 o-tiles of 16)
    #pragma unroll
    for (int g = 0; g < 2; ++g) {
        const unsigned short* xg = XT + g*15360;
        float cross = 0.f;
        #pragma unroll
        for (int lt = 0; lt < 2; ++lt) {
            s16x8 af = *(const s16x8*)&Mm[g*1280 + (lt*16 + m)*40 + quad*8];
            #pragma unroll
            for (int i = 0; i < 2; ++i) {
                const int oc = (wave*2 + i)*16 + m;
                s16x8 bfv = *(const s16x8*)&xg[oc*40 + quad*8];
                f32x4 sa = __builtin_amdgcn_mfma_f32_16x16x32_bf16(
                    af, bfv, (f32x4){0.f, 0.f, 0.f, 0.f}, 0, 0, 0);
                #pragma unroll
                for (int r = 0; r < 4; ++r) {
                    const int lp = lt*16 + quad*4 + r;
                    cross = fmaf(bf2f(xg[oc*40 + lp]), sa[r], cross);
                }
            }
        }
        s2loc[g] -= 2.f * cross;
    }

    // ---- block reduce S1/S2 per group
    #pragma unroll
    for (int g = 0; g < 2; ++g) {
        float sA = s1loc[g], sQ = s2loc[g];
        #pragma unroll
        for (int off = 32; off > 0; off >>= 1) {
            sA += __shfl_down(sA, off, 64);
            sQ += __shfl_down(sQ, off, 64);
        }
        if (lane == 0) { r1[g][wave] = sA; r2[g][wave] = sQ; }
    }
    __syncthreads();
    if (t < 2) {
        float S = 0.f, Q = 0.f;
        #pragma unroll
        for (int w = 0; w < 12; ++w) { S += r1[t][w]; Q += r2[t][w]; }
        S1p[g0 + t] = S;
        S2p[g0 + t] = Q;
    }
}

// ---------------------------------------------------------------- K6: global std over dx (ddof=1)
__global__ void k6_std(const float* __restrict__ S1p, const float* __restrict__ S2p,
                       float* __restrict__ stdv)
{
    const int t = threadIdx.x;
    double s = 0.0, q = 0.0;
    for (int i = t; i < 1024; i += 256) { s += (double)S1p[i]; q += (double)S2p[i]; }
    #pragma unroll
    for (int off = 32; off > 0; off >>= 1) {
        s += __shfl_down(s, off, 64);
        q += __shfl_down(q, off, 64);
    }
    __shared__ double rs[4], rq[4];
    const int wid = t >> 6;
    if ((t & 63) == 0) { rs[wid] = s; rq[wid] = q; }
    __syncthreads();
    if (t == 0) {
        double S = rs[0]+rs[1]+rs[2]+rs[3];
        double Q = rq[0]+rq[1]+rq[2]+rq[3];
        const double N = 1024.0 * 32.0 * 8.0 * 384.0;
        double var = (Q - S*S/N) / (N - 1.0);
        stdv[0] = (float)sqrt(var);
    }
}

// ---------------------------------------------------------------- K7: fused head MFMA GEMM: M=384 (Wf rows), K=768, N=32 groups/block
__global__ __launch_bounds__(384) void k7_fused(
    const float* __restrict__ fg2, const float* __restrict__ A,
    const float* __restrict__ alpha, const float* __restrict__ beta_aff,
    const float* __restrict__ stdv,
    const unsigned short* __restrict__ Wfb, const float* __restrict__ bf,
    float* __restrict__ hf, float* __restrict__ pfs, float* __restrict__ pfq)
{
    const int blk = blockIdx.x;
    const int g0 = blk * 32;
    const int t = threadIdx.x;
    __shared__ __align__(16) char smem[49664];
    unsigned short* xfb = (unsigned short*)smem;   // [32][776]
    float* OTf = (float*)smem;                     // [32][388]

    const float inv = 1.f / (256.f * (stdv[0] + EPS));
    for (int i = t; i < 32*96; i += 384) {
        const int row = i / 96, c8 = (i % 96) * 8;
        const int g = g0 + row;
        float e[8];
        if (c8 < 384) {
            const float4* s0 = (const float4*)(fg2 + (size_t)g*384 + c8);
            float4 v0 = s0[0], v1 = s0[1];
            e[0]=v0.x; e[1]=v0.y; e[2]=v0.z; e[3]=v0.w;
            e[4]=v1.x; e[5]=v1.y; e[6]=v1.z; e[7]=v1.w;
        } else {
            const int cc = c8 - 384;
            const float4* s0 = (const float4*)(A + (size_t)g*384 + cc);
            float4 v0 = s0[0], v1 = s0[1];
            float av[8] = {v0.x,v0.y,v0.z,v0.w,v1.x,v1.y,v1.z,v1.w};
            #pragma unroll
            for (int j = 0; j < 8; ++j)
                e[j] = fmaf(alpha[cc+j] * inv, av[j], beta_aff[cc+j]);
        }
        uint4 o4;
        o4.x = (unsigned)f2bf(e[0]) | ((unsigned)f2bf(e[1]) << 16);
        o4.y = (unsigned)f2bf(e[2]) | ((unsigned)f2bf(e[3]) << 16);
        o4.z = (unsigned)f2bf(e[4]) | ((unsigned)f2bf(e[5]) << 16);
        o4.w = (unsigned)f2bf(e[6]) | ((unsigned)f2bf(e[7]) << 16);
        *(uint4*)&xfb[row*776 + c8] = o4;
    }
    __syncthreads();

    const int wave = t >> 6;
    const int lane = t & 63;
    const int m    = lane & 15;
    const int quad = lane >> 4;

    f32x4 acc[4][2];
    #pragma unroll
    for (int mt = 0; mt < 4; ++mt)
        #pragma unroll
        for (int nt = 0; nt < 2; ++nt)
            acc[mt][nt] = (f32x4){0.f, 0.f, 0.f, 0.f};

    #pragma unroll 4
    for (int kt = 0; kt < 24; ++kt) {
        s16x8 bv[2];
        #pragma unroll
        for (int nt = 0; nt < 2; ++nt)
            bv[nt] = *(const s16x8*)&xfb[(nt*16 + m)*776 + kt*32 + quad*8];
        #pragma unroll
        for (int mt = 0; mt < 4; ++mt) {
            s16x8 av = *(const s16x8*)(Wfb + (size_t)(wave*64 + mt*16 + m)*768 + kt*32 + quad*8);
            #pragma unroll
            for (int nt = 0; nt < 2; ++nt)
                acc[mt][nt] = __builtin_amdgcn_mfma_f32_16x16x32_bf16(av, bv[nt], acc[mt][nt], 0, 0, 0);
        }
    }

    #pragma unroll
    for (int mt = 0; mt < 4; ++mt) {
        const int o0 = wave*64 + mt*16 + quad*4;
        float s[4], q[4];
        #pragma unroll
        for (int r = 0; r < 4; ++r) {
            float bb = bf[o0 + r];
            acc[mt][0][r] += bb;
            acc[mt][1][r] += bb;
            s[r] = acc[mt][0][r] + acc[mt][1][r];
            q[r] = acc[mt][0][r]*acc[mt][0][r] + acc[mt][1][r]*acc[mt][1][r];
        }
        #pragma unroll
        for (int msk = 1; msk < 16; msk <<= 1)
            #pragma unroll
            for (int r = 0; r < 4; ++r) {
                s[r] += __shfl_xor(s[r], msk, 16);
                q[r] += __shfl_xor(q[r], msk, 16);
            }
        if (m == 0) {
            #pragma unroll
            for (int r = 0; r < 4; ++r) {
                pfs[(size_t)blk*384 + o0 + r] = s[r];
                pfq[(size_t)blk*384 + o0 + r] = q[r];
            }
        }
    }
    __syncthreads();

    #pragma unroll
    for (int mt = 0; mt < 4; ++mt) {
        const int o0 = wave*64 + mt*16 + quad*4;
        #pragma unroll
        for (int nt = 0; nt < 2; ++nt) {
            const int row = nt*16 + m;
            #pragma unroll
            for (int r = 0; r < 4; ++r)
                OTf[row*388 + o0 + r] = acc[mt][nt][r];
        }
    }
    __syncthreads();

    {
        float* dst = hf + (size_t)g0*384;
        for (int k = 0; k < 8; ++k) {
            const int i = t + k*384;
            const int row = i / 96;
            float4 v = *(const float4*)&OTf[i*4 + row*4];
            *(float4*)(dst + i*4) = v;
        }
    }
}

// ---------------------------------------------------------------- K9: BNf + relu -> out
__global__ __launch_bounds__(384) void k9_out(
    const float* __restrict__ hf, const float* __restrict__ scalef,
    const float* __restrict__ shiftf, float* __restrict__ out)
{
    const int b = blockIdx.x, t = threadIdx.x;
    float v = fmaf(hf[(size_t)b*384 + t], scalef[t], shiftf[t]);
    out[(size_t)b*384 + t] = fmaxf(v, 0.f);
}

extern "C" void kernel_launch(void* const* d_in, const int* in_sizes, int n_in,
                              void* d_out, int out_size, void* d_ws, size_t ws_size,
                              hipStream_t stream) {
    const float* pg      = (const float*)d_in[0];
    const float* W1      = (const float*)d_in[1];
    const float* b1      = (const float*)d_in[2];
    const float* gamma1  = (const float*)d_in[3];
    const float* beta1   = (const float*)d_in[4];
    const float* W2      = (const float*)d_in[5];
    const float* b2      = (const float*)d_in[6];
    const float* W3      = (const float*)d_in[7];
    const float* b3      = (const float*)d_in[8];
    const float* gamma3  = (const float*)d_in[9];
    const float* beta3   = (const float*)d_in[10];
    const float* W4      = (const float*)d_in[11];
    const float* b4      = (const float*)d_in[12];
    const float* alpha   = (const float*)d_in[13];
    const float* beta_af = (const float*)d_in[14];
    const float* Wf      = (const float*)d_in[15];
    const float* bf      = (const float*)d_in[16];
    const float* gammaf  = (const float*)d_in[17];
    const float* betaf   = (const float*)d_in[18];
    float* out = (float*)d_out;

    float* w = (float*)d_ws;
    float* h1     = w;  w += 1024*4096;                               // 16 MB [b][l][c]
    unsigned short* h3b = (unsigned short*)w; w += 1024*16384/2;      // 32 MB bf16, fragment order per k3 block
    unsigned short* W2b = (unsigned short*)w; w += 32768/2;
    unsigned short* W3b = (unsigned short*)w; w += 262144/2;
    unsigned short* W4b = (unsigned short*)w; w += 196608/2;
    unsigned short* Wfb = (unsigned short*)w; w += 294912/2;
    float* hf     = w;  w += 1024*384;
    float* fg2    = w;  w += 1024*384;
    float* A      = w;  w += 1024*384;
    float* p1s    = w;  w += 1024*128;   // [b][c]
    float* p1q    = w;  w += 1024*128;
    float* p3s    = w;  w += 1024*512;   // [g][o]
    float* p3q    = w;  w += 1024*512;
    float* pfs    = w;  w += 32*384;     // [blk][o]
    float* pfq    = w;  w += 32*384;
    float* S1p    = w;  w += 1024;
    float* S2p    = w;  w += 1024;
    float* scale1 = w;  w += 128;
    float* shift1 = w;  w += 128;
    float* scale3 = w;  w += 512;
    float* shift3 = w;  w += 512;
    float* scalef = w;  w += 384;
    float* shiftf = w;  w += 384;
    float* stdv   = w;  w += 4;
    int*   idxw   = (int*)w;  w += 1024*256;

    hipLaunchKernelGGL(kprep, dim3(1152), dim3(256), 0, stream,
                       W2, W3, W4, Wf, W2b, W3b, W4b, Wfb);
    hipLaunchKernelGGL(k1_conv1_knn, dim3(1024), dim3(128), 0, stream,
                       pg, W1, b1, h1, p1s, p1q, idxw);
    hipLaunchKernelGGL(k_bn_fin2, dim3(8), dim3(256), 0, stream,
                       p1s, p1q, 1024, 128, 1.f/32768.f, gamma1, beta1, scale1, shift1);
    hipLaunchKernelGGL(k3_mfma, dim3(512), dim3(512), 0, stream,
                       h1, scale1, shift1, W2b, b2, W3b, b3, h3b, p3s, p3q);
    hipLaunchKernelGGL(k_bn_fin2, dim3(32), dim3(256), 0, stream,
                       p3s, p3q, 1024, 512, 1.f/32768.f, gamma3, beta3, scale3, shift3);
    hipLaunchKernelGGL(k5_mfma, dim3(512), dim3(768), 0, stream,
                       h3b, scale3, shift3, W4b, b4, idxw, fg2, A, S1p, S2p);
    hipLaunchKernelGGL(k6_std, dim3(1), dim3(256), 0, stream, S1p, S2p, stdv);
    hipLaunchKernelGGL(k7_fused, dim3(32), dim3(384), 0, stream,
                       fg2, A, alpha, beta_af, stdv, Wfb, bf, hf, pfs, pfq);
    hipLaunchKernelGGL(k_bn_fin2, dim3(24), dim3(256), 0, stream,
                       pfs, pfq, 32, 384, 1.f/1024.f, gammaf, betaf, scalef, shiftf);
    hipLaunchKernelGGL(k9_out, dim3(1024), dim3(384), 0, stream,
                       hf, scalef, shiftf, out);
}

// Round 7
// 234.259 us; speedup vs baseline: 4.5260x; 1.1633x over previous
//
#include <hip/hip_runtime.h>
#include <math.h>

#define EPS 1e-5f

typedef __attribute__((ext_vector_type(8))) short s16x8;   // 8 bf16 (4 VGPRs)
typedef __attribute__((ext_vector_type(4))) float f32x4;   // MFMA C/D

__device__ __forceinline__ unsigned short f2bf(float x) {
    unsigned u = __float_as_uint(x);
    u += 0x7fffu + ((u >> 16) & 1u);           // round-to-nearest-even
    return (unsigned short)(u >> 16);
}
__device__ __forceinline__ float bf2f(unsigned short h) {
    return __uint_as_float(((unsigned)h) << 16);
}
__device__ __forceinline__ unsigned long long pack4bf(float a, float b, float c, float d) {
    return (unsigned long long)f2bf(a)
         | ((unsigned long long)f2bf(b) << 16)
         | ((unsigned long long)f2bf(c) << 32)
         | ((unsigned long long)f2bf(d) << 48);
}

// ---------------------------------------------------------------- K1: conv1 + knn + (fused) weight bf16 conversion
// grid 1024 + 2304: blocks >=1024 convert weights (kprep fused to drop a launch)
__global__ __launch_bounds__(128) void k1_conv1_knn(
    const float* __restrict__ pg, const float* __restrict__ W1,
    const float* __restrict__ b1,
    const float* __restrict__ W2, const float* __restrict__ W3,
    const float* __restrict__ W4, const float* __restrict__ Wf,
    float* __restrict__ h1, float* __restrict__ p1s, float* __restrict__ p1q,
    int* __restrict__ idxw,
    unsigned short* __restrict__ W2b, unsigned short* __restrict__ W3b,
    unsigned short* __restrict__ W4b, unsigned short* __restrict__ Wfb)
{
    __shared__ float pgs[96];
    __shared__ float sqs[32];
    if (blockIdx.x >= 1024) {
        const int i = (blockIdx.x - 1024) * 128 + threadIdx.x;
        if (i < 32768)  W2b[i] = f2bf(W2[i]);
        if (i < 262144) W3b[i] = f2bf(W3[i]);
        if (i < 196608) W4b[i] = f2bf(W4[i]);
        if (i < 294912) Wfb[i] = f2bf(Wf[i]);
        return;
    }
    const int b = blockIdx.x;
    const int t = threadIdx.x;
    if (t < 96) pgs[t] = pg[b * 96 + t];
    __syncthreads();
    if (t < 32) {
        float x = pgs[t*3+0], y = pgs[t*3+1], z = pgs[t*3+2];
        sqs[t] = x*x + y*y + z*z;
    }
    __syncthreads();
    {
        const float w0 = W1[t*3+0], w1 = W1[t*3+1], w2 = W1[t*3+2];
        const float bb = b1[t];
        float s = 0.f, q = 0.f;
        float* hcol = h1 + (size_t)b*4096 + t;
        #pragma unroll
        for (int l = 0; l < 32; ++l) {
            float v = fmaf(w2, pgs[l*3+2], fmaf(w1, pgs[l*3+1], fmaf(w0, pgs[l*3+0], bb)));
            hcol[l*128] = v; s += v; q += v*v;
        }
        p1s[b*128 + t] = s;
        p1q[b*128 + t] = q;
    }
    if (t < 32) {
        const float xl = pgs[t*3+0], yl = pgs[t*3+1], zl = pgs[t*3+2];
        const float sql = sqs[t];
        float dist[32];
        #pragma unroll
        for (int m = 0; m < 32; ++m) {
            float dot = xl*pgs[m*3+0] + yl*pgs[m*3+1] + zl*pgs[m*3+2];
            dist[m] = sql + sqs[m] - 2.f*dot;
        }
        unsigned used = 0u;
        int* orow = idxw + b*256 + t*8;
        #pragma unroll
        for (int j = 0; j < 8; ++j) {
            float best = 3.4e38f; int bi = 0;
            #pragma unroll
            for (int m = 0; m < 32; ++m) {
                if (!((used >> m) & 1u) && dist[m] < best) { best = dist[m]; bi = m; }
            }
            used |= (1u << bi);
            orow[j] = bi;
        }
    }
}

// ---------------------------------------------------------------- BN finalize, partials [part][chan], 4 channels/block
__global__ __launch_bounds__(256) void k_bn_fin2(
    const float* __restrict__ ps, const float* __restrict__ pq,
    int nPart, int nChan, float invN,
    const float* __restrict__ gamma, const float* __restrict__ beta,
    float* __restrict__ scale, float* __restrict__ shift)
{
    const int ob = blockIdx.x * 4;
    const int t = threadIdx.x;
    const int co = t & 3, i0 = t >> 2;   // 64 part-lanes per channel
    float s = 0.f, q = 0.f;
    for (int i = i0; i < nPart; i += 64) {
        s += ps[(size_t)i*nChan + ob + co];
        q += pq[(size_t)i*nChan + ob + co];
    }
    #pragma unroll
    for (int off = 32; off >= 4; off >>= 1) {
        s += __shfl_down(s, off, 64);
        q += __shfl_down(q, off, 64);
    }
    __shared__ float ss[4][4], qs[4][4];
    const int wid = t >> 6, lane = t & 63;
    if (lane < 4) { ss[wid][lane] = s; qs[wid][lane] = q; }
    __syncthreads();
    if (t < 4) {
        float S = ss[0][t] + ss[1][t] + ss[2][t] + ss[3][t];
        float Q = qs[0][t] + qs[1][t] + qs[2][t] + qs[3][t];
        const int o = ob + t;
        float mu  = S * invN;
        float var = Q * invN - mu*mu;
        float sc  = gamma[o] * rsqrtf(var + EPS);
        scale[o] = sc;
        shift[o] = beta[o] - mu * sc;
    }
}

// ---------------------------------------------------------------- K3 v2: 2 groups/block, 8 waves.
// conv2 (K=128) -> fg-bias GEMM (K=256, tiny N) -> conv3 main (K=256 over f2 only).
// h3b fragment order unchanged. LDS ~39 KB.
__global__ __launch_bounds__(512, 2) void k3_mfma(
    const float* __restrict__ h1,
    const float* __restrict__ scale1, const float* __restrict__ shift1,
    const unsigned short* __restrict__ W2b, const float* __restrict__ b2,
    const unsigned short* __restrict__ W3b, const float* __restrict__ b3,
    unsigned short* __restrict__ h3b, float* __restrict__ p3s, float* __restrict__ p3q)
{
    const int g0 = blockIdx.x * 2;
    const int t = threadIdx.x;
    __shared__ __align__(16) unsigned short SB[19472];
    unsigned short* B1  = SB;            // [64][136] conv2 staging (dead after conv2)
    unsigned short* F2  = SB;            // [64][264] f2 (cols o 0..255), conv3 B-matrix
    unsigned short* FGB = SB + 16896;    // [2][264] fg per group (bf16)
    float* FGR = (float*)(SB + 17424);   // [512][2] fg-bias result fp32

    // ---- P0: stage x1 = relu(BN1(h1)) bf16 [l64][c128]
    {
        const int l = t >> 3, c0 = (t & 7) * 16;
        const int g = g0 + (l >> 5);
        const float4* src = (const float4*)(h1 + (size_t)g*4096 + (l & 31)*128 + c0);
        #pragma unroll
        for (int i = 0; i < 4; ++i) {
            float4 v = src[i];
            int c = c0 + i*4;
            float e0 = fmaxf(fmaf(v.x, scale1[c+0], shift1[c+0]), 0.f);
            float e1 = fmaxf(fmaf(v.y, scale1[c+1], shift1[c+1]), 0.f);
            float e2 = fmaxf(fmaf(v.z, scale1[c+2], shift1[c+2]), 0.f);
            float e3 = fmaxf(fmaf(v.w, scale1[c+3], shift1[c+3]), 0.f);
            *(unsigned long long*)&B1[l*136 + c] = pack4bf(e0, e1, e2, e3);
        }
    }
    __syncthreads();

    const int wave = t >> 6;
    const int lane = t & 63;
    const int m    = lane & 15;
    const int quad = lane >> 4;

    // ---- P1: conv2 MFMA: M=256 (2 mt/wave), N=64, K=128
    f32x4 acc2[2][4];
    #pragma unroll
    for (int mt = 0; mt < 2; ++mt)
        #pragma unroll
        for (int n = 0; n < 4; ++n)
            acc2[mt][n] = (f32x4){0.f, 0.f, 0.f, 0.f};

    #pragma unroll
    for (int kt = 0; kt < 4; ++kt) {
        s16x8 bv[4];
        #pragma unroll
        for (int nt = 0; nt < 4; ++nt)
            bv[nt] = *(const s16x8*)&B1[(nt*16 + m)*136 + kt*32 + quad*8];
        #pragma unroll
        for (int mt = 0; mt < 2; ++mt) {
            s16x8 av = *(const s16x8*)(W2b + (size_t)(wave*32 + mt*16 + m)*128 + kt*32 + quad*8);
            #pragma unroll
            for (int nt = 0; nt < 4; ++nt)
                acc2[mt][nt] = __builtin_amdgcn_mfma_f32_16x16x32_bf16(av, bv[nt], acc2[mt][nt], 0, 0, 0);
        }
    }
    __syncthreads();   // B1 dead; SB becomes F2

    // ---- P2: epilogue conv2: bias, write f2 cols, fg into FGB
    #pragma unroll
    for (int mt = 0; mt < 2; ++mt) {
        const int o0 = wave*32 + mt*16 + quad*4;
        #pragma unroll
        for (int r = 0; r < 4; ++r) {
            float bb = b2[o0 + r];
            #pragma unroll
            for (int nt = 0; nt < 4; ++nt) acc2[mt][nt][r] += bb;
        }
        #pragma unroll
        for (int nt = 0; nt < 4; ++nt) {
            const int row = nt*16 + m;
            *(unsigned long long*)&F2[row*264 + o0] =
                pack4bf(acc2[mt][nt][0], acc2[mt][nt][1], acc2[mt][nt][2], acc2[mt][nt][3]);
        }
        float f0[4], f1[4];
        #pragma unroll
        for (int r = 0; r < 4; ++r) {
            f0[r] = fmaxf(acc2[mt][0][r], acc2[mt][1][r]);
            f1[r] = fmaxf(acc2[mt][2][r], acc2[mt][3][r]);
        }
        #pragma unroll
        for (int msk = 1; msk < 16; msk <<= 1)
            #pragma unroll
            for (int r = 0; r < 4; ++r) {
                f0[r] = fmaxf(f0[r], __shfl_xor(f0[r], msk, 16));
                f1[r] = fmaxf(f1[r], __shfl_xor(f1[r], msk, 16));
            }
        if (m == 0) {
            *(unsigned long long*)&FGB[o0]       = pack4bf(f0[0], f0[1], f0[2], f0[3]);
            *(unsigned long long*)&FGB[264 + o0] = pack4bf(f1[0], f1[1], f1[2], f1[3]);
        }
    }
    __syncthreads();

    // ---- P3: fg-bias GEMM: fgb[o][g] = W3[:, :256] . fg[g]; M=512 (4 tiles/wave), K=256
    // B rows m>=2 read duplicate rows (m&1); garbage C cols 2..15 ignored.
    {
        f32x4 facc[4];
        #pragma unroll
        for (int i = 0; i < 4; ++i) facc[i] = (f32x4){0.f, 0.f, 0.f, 0.f};
        #pragma unroll
        for (int kt = 0; kt < 8; ++kt) {
            s16x8 bg = *(const s16x8*)&FGB[(m & 1)*264 + kt*32 + quad*8];
            #pragma unroll
            for (int i = 0; i < 4; ++i) {
                s16x8 av = *(const s16x8*)(W3b + (size_t)((wave*4 + i)*16 + m)*512 + kt*32 + quad*8);
                facc[i] = __builtin_amdgcn_mfma_f32_16x16x32_bf16(av, bg, facc[i], 0, 0, 0);
            }
        }
        if (m < 2) {
            #pragma unroll
            for (int i = 0; i < 4; ++i)
                #pragma unroll
                for (int r = 0; r < 4; ++r)
                    FGR[((wave*4 + i)*16 + quad*4 + r)*2 + m] = facc[i][r];
        }
    }
    __syncthreads();

    // ---- P4: conv3 main: M=512 (4 mt/wave), N=64, K=256 (f2 only); acc init = b3 + fgb
    f32x4 acc3[4][4];
    #pragma unroll
    for (int mt = 0; mt < 4; ++mt) {
        const int ob = wave*64 + mt*16 + quad*4;
        #pragma unroll
        for (int r = 0; r < 4; ++r) {
            float2 fb = *(const float2*)&FGR[(ob + r)*2];
            float bb = b3[ob + r];
            acc3[mt][0][r] = bb + fb.x;
            acc3[mt][1][r] = bb + fb.x;
            acc3[mt][2][r] = bb + fb.y;
            acc3[mt][3][r] = bb + fb.y;
        }
    }
    #pragma unroll 4
    for (int kt = 0; kt < 8; ++kt) {
        s16x8 bv[4];
        #pragma unroll
        for (int nt = 0; nt < 4; ++nt)
            bv[nt] = *(const s16x8*)&F2[(nt*16 + m)*264 + kt*32 + quad*8];
        #pragma unroll
        for (int mt = 0; mt < 4; ++mt) {
            s16x8 av = *(const s16x8*)(W3b + (size_t)(wave*64 + mt*16 + m)*512 + 256 + kt*32 + quad*8);
            #pragma unroll
            for (int nt = 0; nt < 4; ++nt)
                acc3[mt][nt] = __builtin_amdgcn_mfma_f32_16x16x32_bf16(av, bv[nt], acc3[mt][nt], 0, 0, 0);
        }
    }

    // ---- epilogue: stats + fragment-order h3b store (unchanged layout)
    unsigned short* dst = h3b + (size_t)blockIdx.x * 32768;
    #pragma unroll
    for (int mt = 0; mt < 4; ++mt) {
        const int o0 = wave*64 + mt*16 + quad*4;
        float s0[4], q0[4], s1[4], q1[4];
        #pragma unroll
        for (int r = 0; r < 4; ++r) {
            s0[r] = acc3[mt][0][r] + acc3[mt][1][r];
            q0[r] = acc3[mt][0][r]*acc3[mt][0][r] + acc3[mt][1][r]*acc3[mt][1][r];
            s1[r] = acc3[mt][2][r] + acc3[mt][3][r];
            q1[r] = acc3[mt][2][r]*acc3[mt][2][r] + acc3[mt][3][r]*acc3[mt][3][r];
        }
        {
            unsigned long long u0 = pack4bf(acc3[mt][0][0], acc3[mt][0][1], acc3[mt][0][2], acc3[mt][0][3]);
            unsigned long long u1 = pack4bf(acc3[mt][1][0], acc3[mt][1][1], acc3[mt][1][2], acc3[mt][1][3]);
            unsigned long long u2 = pack4bf(acc3[mt][2][0], acc3[mt][2][1], acc3[mt][2][2], acc3[mt][2][3]);
            unsigned long long u3 = pack4bf(acc3[mt][3][0], acc3[mt][3][1], acc3[mt][3][2], acc3[mt][3][3]);
            unsigned short* p = dst + (size_t)(((wave*4 + mt)*64 + lane)) * 16;
            *(uint4*)(p)     = make_uint4((unsigned)u0, (unsigned)(u0 >> 32), (unsigned)u1, (unsigned)(u1 >> 32));
            *(uint4*)(p + 8) = make_uint4((unsigned)u2, (unsigned)(u2 >> 32), (unsigned)u3, (unsigned)(u3 >> 32));
        }
        #pragma unroll
        for (int msk = 1; msk < 16; msk <<= 1)
            #pragma unroll
            for (int r = 0; r < 4; ++r) {
                s0[r] += __shfl_xor(s0[r], msk, 16);
                q0[r] += __shfl_xor(q0[r], msk, 16);
                s1[r] += __shfl_xor(s1[r], msk, 16);
                q1[r] += __shfl_xor(q1[r], msk, 16);
            }
        if (m == 0) {
            #pragma unroll
            for (int r = 0; r < 4; ++r) {
                p3s[(size_t)g0*512 + o0 + r]       = s0[r];
                p3q[(size_t)g0*512 + o0 + r]       = q0[r];
                p3s[(size_t)(g0+1)*512 + o0 + r]   = s1[r];
                p3q[(size_t)(g0+1)*512 + o0 + r]   = q1[r];
            }
        }
    }
}

// ---------------------------------------------------------------- K5: 2 groups/block, 12 waves. MFMA conv4 + fg2 + algebraic knn branch.
__global__ __launch_bounds__(768, 2) void k5_mfma(
    const unsigned short* __restrict__ h3b,
    const float* __restrict__ scale3, const float* __restrict__ shift3,
    const unsigned short* __restrict__ W4b, const float* __restrict__ b4,
    const int* __restrict__ idxw,
    float* __restrict__ fg2, float* __restrict__ A,
    float* __restrict__ S1p, float* __restrict__ S2p)
{
    const int g0 = blockIdx.x * 2;
    const int t = threadIdx.x;
    __shared__ __align__(16) unsigned short SB[33280];   // 66560 B
    unsigned short* B4 = SB;                              // [64][520] staging
    unsigned short* XT = SB;                              // [g][o*40 + l], g stride 15360
    unsigned short* Mm = SB + 30720;                      // [g][l*40 + m], g stride 1280
    __shared__ int icnt[2][32];
    __shared__ float r1[2][12], r2[2][12];

    {
        const uint4* src = (const uint4*)(h3b + (size_t)blockIdx.x * 32768);
        for (int i = t; i < 4096; i += 768) {
            uint4 hv = src[i];
            const int flat16 = i >> 1, half = i & 1;
            const int ln = flat16 & 63, m2 = ln & 15, q2 = ln >> 4;
            const int wm = flat16 >> 6;
            const int o0 = (wm >> 2)*64 + (wm & 3)*16 + q2*4;
            const float4 sc = *(const float4*)(scale3 + o0);
            const float4 sh = *(const float4*)(shift3 + o0);
            const int rowa = (half*2)*16 + m2;
            float a0 = fmaxf(fmaf(bf2f((unsigned short)(hv.x       )), sc.x, sh.x), 0.f);
            float a1 = fmaxf(fmaf(bf2f((unsigned short)(hv.x >> 16 )), sc.y, sh.y), 0.f);
            float a2 = fmaxf(fmaf(bf2f((unsigned short)(hv.y       )), sc.z, sh.z), 0.f);
            float a3 = fmaxf(fmaf(bf2f((unsigned short)(hv.y >> 16 )), sc.w, sh.w), 0.f);
            float b0 = fmaxf(fmaf(bf2f((unsigned short)(hv.z       )), sc.x, sh.x), 0.f);
            float b1 = fmaxf(fmaf(bf2f((unsigned short)(hv.z >> 16 )), sc.y, sh.y), 0.f);
            float b2 = fmaxf(fmaf(bf2f((unsigned short)(hv.w       )), sc.z, sh.z), 0.f);
            float b3 = fmaxf(fmaf(bf2f((unsigned short)(hv.w >> 16 )), sc.w, sh.w), 0.f);
            *(unsigned long long*)&B4[rowa*520 + o0]        = pack4bf(a0, a1, a2, a3);
            *(unsigned long long*)&B4[(rowa + 16)*520 + o0] = pack4bf(b0, b1, b2, b3);
        }
    }
    if (t < 64) icnt[t >> 5][t & 31] = 0;
    __syncthreads();

    const int wave = t >> 6;
    const int lane = t & 63;
    const int m    = lane & 15;
    const int quad = lane >> 4;

    f32x4 acc4[2][4];
    #pragma unroll
    for (int mt = 0; mt < 2; ++mt)
        #pragma unroll
        for (int n = 0; n < 4; ++n)
            acc4[mt][n] = (f32x4){0.f, 0.f, 0.f, 0.f};

    #pragma unroll 4
    for (int kt = 0; kt < 16; ++kt) {
        s16x8 bv[4];
        #pragma unroll
        for (int nt = 0; nt < 4; ++nt)
            bv[nt] = *(const s16x8*)&B4[(nt*16 + m)*520 + kt*32 + quad*8];
        #pragma unroll
        for (int mt = 0; mt < 2; ++mt) {
            s16x8 av = *(const s16x8*)(W4b + (size_t)(wave*32 + mt*16 + m)*512 + kt*32 + quad*8);
            #pragma unroll
            for (int nt = 0; nt < 4; ++nt)
                acc4[mt][nt] = __builtin_amdgcn_mfma_f32_16x16x32_bf16(av, bv[nt], acc4[mt][nt], 0, 0, 0);
        }
    }

    #pragma unroll
    for (int mt = 0; mt < 2; ++mt) {
        const int o0 = wave*32 + mt*16 + quad*4;
        float f0[4], f1[4];
        #pragma unroll
        for (int r = 0; r < 4; ++r) {
            float bb = b4[o0 + r];
            #pragma unroll
            for (int nt = 0; nt < 4; ++nt) acc4[mt][nt][r] += bb;
            f0[r] = fmaxf(acc4[mt][0][r], acc4[mt][1][r]);
            f1[r] = fmaxf(acc4[mt][2][r], acc4[mt][3][r]);
        }
        #pragma unroll
        for (int msk = 1; msk < 16; msk <<= 1)
            #pragma unroll
            for (int r = 0; r < 4; ++r) {
                f0[r] = fmaxf(f0[r], __shfl_xor(f0[r], msk, 16));
                f1[r] = fmaxf(f1[r], __shfl_xor(f1[r], msk, 16));
            }
        if (m == 0) {
            #pragma unroll
            for (int r = 0; r < 4; ++r) {
                fg2[(size_t)g0*384 + o0 + r]     = f0[r];
                fg2[(size_t)(g0+1)*384 + o0 + r] = f1[r];
            }
        }
    }
    __syncthreads();

    #pragma unroll
    for (int mt = 0; mt < 2; ++mt) {
        const int o0 = wave*32 + mt*16 + quad*4;
        #pragma unroll
        for (int nt = 0; nt < 4; ++nt) {
            const int g = nt >> 1;
            const int l = (nt & 1)*16 + m;
            unsigned short* xg = XT + g*15360;
            #pragma unroll
            for (int r = 0; r < 4; ++r)
                xg[(o0 + r)*40 + l] = f2bf(acc4[mt][nt][r]);
        }
    }
    if (t < 64) {
        const int g = t >> 5, l = t & 31;
        uint4 z = make_uint4(0u, 0u, 0u, 0u);
        #pragma unroll
        for (int i = 0; i < 5; ++i)
            *(uint4*)&Mm[g*1280 + l*40 + i*8] = z;
    }
    __syncthreads();

    if (t < 64) {
        const int g = t >> 5, l = t & 31;
        const int* ip = idxw + (size_t)(g0 + g)*256 + l*8;
        #pragma unroll
        for (int j = 0; j < 8; ++j) {
            int ix = ip[j];
            Mm[g*1280 + l*40 + ix] = 0x3F80;
            atomicAdd(&icnt[g][ix], 1);
        }
    }
    __syncthreads();

    float s1loc[2] = {0.f, 0.f}, s2loc[2] = {0.f, 0.f};
    #pragma unroll
    for (int g = 0; g < 2; ++g) {
        const float c0 = (float)icnt[g][m];
        const float c1 = (float)icnt[g][m + 16];
        const float w0 = c0 - 8.f, u0 = c0 + 8.f;
        const float w1 = c1 - 8.f, u1 = c1 + 8.f;
        #pragma unroll
        for (int mt = 0; mt < 2; ++mt) {
            const int o0 = wave*32 + mt*16 + quad*4;
            float Ap[4];
            #pragma unroll
            for (int r = 0; r < 4; ++r) {
                const float x0 = acc4[mt][g*2 + 0][r];
                const float x1 = acc4[mt][g*2 + 1][r];
                Ap[r] = w0*x0 + w1*x1;
                s1loc[g] += Ap[r];
                s2loc[g] += u0*x0*x0 + u1*x1*x1;
            }
            #pragma unroll
            for (int msk = 1; msk < 16; msk <<= 1)
                #pragma unroll
                for (int r = 0; r < 4; ++r)
                    Ap[r] += __shfl_xor(Ap[r], msk, 16);
            if (m == 0) {
                #pragma unroll
                for (int r = 0; r < 4; ++r)
                    A[(size_t)(g0 + g)*384 + o0 + r] = Ap[r];
            }
        }
    }

    #pragma unroll
    for (int g = 0; g < 2; ++g) {
        const unsigned short* xg = XT + g*15360;
        float cross = 0.f;
        #pragma unroll
        for (int lt = 0; lt < 2; ++lt) {
            s16x8 af = *(const s16x8*)&Mm[g*1280 + (lt*16 + m)*40 + quad*8];
            #pragma unroll
            for (int i = 0; i < 2; ++i) {
                const int oc = (wave*2 + i)*16 + m;
                s16x8 bfv = *(const s16x8*)&xg[oc*40 + quad*8];
                f32x4 sa = __builtin_amdgcn_mfma_f32_16x16x32_bf16(
                    af, bfv, (f32x4){0.f, 0.f, 0.f, 0.f}, 0, 0, 0);
                #pragma unroll
                for (int r = 0; r < 4; ++r) {
                    const int lp = lt*16 + quad*4 + r;
                    cross = fmaf(bf2f(xg[oc*40 + lp]), sa[r], cross);
                }
            }
        }
        s2loc[g] -= 2.f * cross;
    }

    #pragma unroll
    for (int g = 0; g < 2; ++g) {
        float sA = s1loc[g], sQ = s2loc[g];
        #pragma unroll
        for (int off = 32; off > 0; off >>= 1) {
            sA += __shfl_down(sA, off, 64);
            sQ += __shfl_down(sQ, off, 64);
        }
        if (lane == 0) { r1[g][wave] = sA; r2[g][wave] = sQ; }
    }
    __syncthreads();
    if (t < 2) {
        float S = 0.f, Q = 0.f;
        #pragma unroll
        for (int w = 0; w < 12; ++w) { S += r1[t][w]; Q += r2[t][w]; }
        S1p[g0 + t] = S;
        S2p[g0 + t] = Q;
    }
}

// ---------------------------------------------------------------- K7: fused head MFMA GEMM, N=16 groups/block, grid 64. Inlines k6 std.
__global__ __launch_bounds__(384) void k7_fused(
    const float* __restrict__ fg2, const float* __restrict__ A,
    const float* __restrict__ alpha, const float* __restrict__ beta_aff,
    const float* __restrict__ S1p, const float* __restrict__ S2p,
    const unsigned short* __restrict__ Wfb, const float* __restrict__ bf,
    float* __restrict__ hf, float* __restrict__ pfs, float* __restrict__ pfq)
{
    const int blk = blockIdx.x;
    const int g0 = blk * 16;
    const int t = threadIdx.x;
    __shared__ __align__(16) char smem[24832];
    unsigned short* xfb = (unsigned short*)smem;   // [16][776]
    float* OTf = (float*)smem;                     // [16][388]
    __shared__ double rs[6], rq[6];
    __shared__ float stdsh;

    // ---- inline k6: every block redundantly computes the global std (deterministic)
    {
        double s = 0.0, q = 0.0;
        for (int i = t; i < 1024; i += 384) { s += (double)S1p[i]; q += (double)S2p[i]; }
        #pragma unroll
        for (int off = 32; off > 0; off >>= 1) {
            s += __shfl_down(s, off, 64);
            q += __shfl_down(q, off, 64);
        }
        if ((t & 63) == 0) { rs[t >> 6] = s; rq[t >> 6] = q; }
        __syncthreads();
        if (t == 0) {
            double S = 0.0, Q = 0.0;
            #pragma unroll
            for (int w = 0; w < 6; ++w) { S += rs[w]; Q += rq[w]; }
            const double N = 1024.0 * 32.0 * 8.0 * 384.0;
            double var = (Q - S*S/N) / (N - 1.0);
            stdsh = (float)sqrt(var);
        }
        __syncthreads();
    }
    const float inv = 1.f / (256.f * (stdsh + EPS));

    for (int i = t; i < 16*96; i += 384) {
        const int row = i / 96, c8 = (i % 96) * 8;
        const int g = g0 + row;
        float e[8];
        if (c8 < 384) {
            const float4* s0 = (const float4*)(fg2 + (size_t)g*384 + c8);
            float4 v0 = s0[0], v1 = s0[1];
            e[0]=v0.x; e[1]=v0.y; e[2]=v0.z; e[3]=v0.w;
            e[4]=v1.x; e[5]=v1.y; e[6]=v1.z; e[7]=v1.w;
        } else {
            const int cc = c8 - 384;
            const float4* s0 = (const float4*)(A + (size_t)g*384 + cc);
            float4 v0 = s0[0], v1 = s0[1];
            float av[8] = {v0.x,v0.y,v0.z,v0.w,v1.x,v1.y,v1.z,v1.w};
            #pragma unroll
            for (int j = 0; j < 8; ++j)
                e[j] = fmaf(alpha[cc+j] * inv, av[j], beta_aff[cc+j]);
        }
        uint4 o4;
        o4.x = (unsigned)f2bf(e[0]) | ((unsigned)f2bf(e[1]) << 16);
        o4.y = (unsigned)f2bf(e[2]) | ((unsigned)f2bf(e[3]) << 16);
        o4.z = (unsigned)f2bf(e[4]) | ((unsigned)f2bf(e[5]) << 16);
        o4.w = (unsigned)f2bf(e[6]) | ((unsigned)f2bf(e[7]) << 16);
        *(uint4*)&xfb[row*776 + c8] = o4;
    }
    __syncthreads();

    const int wave = t >> 6;
    const int lane = t & 63;
    const int m    = lane & 15;
    const int quad = lane >> 4;

    f32x4 acc[4];
    #pragma unroll
    for (int mt = 0; mt < 4; ++mt) acc[mt] = (f32x4){0.f, 0.f, 0.f, 0.f};

    #pragma unroll 4
    for (int kt = 0; kt < 24; ++kt) {
        s16x8 bv = *(const s16x8*)&xfb[m*776 + kt*32 + quad*8];
        #pragma unroll
        for (int mt = 0; mt < 4; ++mt) {
            s16x8 av = *(const s16x8*)(Wfb + (size_t)(wave*64 + mt*16 + m)*768 + kt*32 + quad*8);
            acc[mt] = __builtin_amdgcn_mfma_f32_16x16x32_bf16(av, bv, acc[mt], 0, 0, 0);
        }
    }

    #pragma unroll
    for (int mt = 0; mt < 4; ++mt) {
        const int o0 = wave*64 + mt*16 + quad*4;
        float s[4], q[4];
        #pragma unroll
        for (int r = 0; r < 4; ++r) {
            acc[mt][r] += bf[o0 + r];
            s[r] = acc[mt][r];
            q[r] = acc[mt][r]*acc[mt][r];
        }
        #pragma unroll
        for (int msk = 1; msk < 16; msk <<= 1)
            #pragma unroll
            for (int r = 0; r < 4; ++r) {
                s[r] += __shfl_xor(s[r], msk, 16);
                q[r] += __shfl_xor(q[r], msk, 16);
            }
        if (m == 0) {
            #pragma unroll
            for (int r = 0; r < 4; ++r) {
                pfs[(size_t)blk*384 + o0 + r] = s[r];
                pfq[(size_t)blk*384 + o0 + r] = q[r];
            }
        }
    }
    __syncthreads();   // xfb reads done; smem becomes OTf

    #pragma unroll
    for (int mt = 0; mt < 4; ++mt) {
        const int o0 = wave*64 + mt*16 + quad*4;
        #pragma unroll
        for (int r = 0; r < 4; ++r)
            OTf[m*388 + o0 + r] = acc[mt][r];
    }
    __syncthreads();

    {
        float* dst = hf + (size_t)g0*384;
        #pragma unroll
        for (int k = 0; k < 4; ++k) {
            const int i = t + k*384;
            const int row = i / 96;
            float4 v = *(const float4*)&OTf[i*4 + row*4];
            *(float4*)(dst + i*4) = v;
        }
    }
}

// ---------------------------------------------------------------- K9: BNf + relu -> out
__global__ __launch_bounds__(384) void k9_out(
    const float* __restrict__ hf, const float* __restrict__ scalef,
    const float* __restrict__ shiftf, float* __restrict__ out)
{
    const int b = blockIdx.x, t = threadIdx.x;
    float v = fmaf(hf[(size_t)b*384 + t], scalef[t], shiftf[t]);
    out[(size_t)b*384 + t] = fmaxf(v, 0.f);
}

extern "C" void kernel_launch(void* const* d_in, const int* in_sizes, int n_in,
                              void* d_out, int out_size, void* d_ws, size_t ws_size,
                              hipStream_t stream) {
    const float* pg      = (const float*)d_in[0];
    const float* W1      = (const float*)d_in[1];
    const float* b1      = (const float*)d_in[2];
    const float* gamma1  = (const float*)d_in[3];
    const float* beta1   = (const float*)d_in[4];
    const float* W2      = (const float*)d_in[5];
    const float* b2      = (const float*)d_in[6];
    const float* W3      = (const float*)d_in[7];
    const float* b3      = (const float*)d_in[8];
    const float* gamma3  = (const float*)d_in[9];
    const float* beta3   = (const float*)d_in[10];
    const float* W4      = (const float*)d_in[11];
    const float* b4      = (const float*)d_in[12];
    const float* alpha   = (const float*)d_in[13];
    const float* beta_af = (const float*)d_in[14];
    const float* Wf      = (const float*)d_in[15];
    const float* bf      = (const float*)d_in[16];
    const float* gammaf  = (const float*)d_in[17];
    const float* betaf   = (const float*)d_in[18];
    float* out = (float*)d_out;

    float* w = (float*)d_ws;
    float* h1     = w;  w += 1024*4096;                               // 16 MB [b][l][c]
    unsigned short* h3b = (unsigned short*)w; w += 1024*16384/2;      // 32 MB bf16, fragment order
    unsigned short* W2b = (unsigned short*)w; w += 32768/2;
    unsigned short* W3b = (unsigned short*)w; w += 262144/2;
    unsigned short* W4b = (unsigned short*)w; w += 196608/2;
    unsigned short* Wfb = (unsigned short*)w; w += 294912/2;
    float* hf     = w;  w += 1024*384;
    float* fg2    = w;  w += 1024*384;
    float* A      = w;  w += 1024*384;
    float* p1s    = w;  w += 1024*128;   // [b][c]
    float* p1q    = w;  w += 1024*128;
    float* p3s    = w;  w += 1024*512;   // [g][o]
    float* p3q    = w;  w += 1024*512;
    float* pfs    = w;  w += 64*384;     // [blk][o]
    float* pfq    = w;  w += 64*384;
    float* S1p    = w;  w += 1024;
    float* S2p    = w;  w += 1024;
    float* scale1 = w;  w += 128;
    float* shift1 = w;  w += 128;
    float* scale3 = w;  w += 512;
    float* shift3 = w;  w += 512;
    float* scalef = w;  w += 384;
    float* shiftf = w;  w += 384;
    int*   idxw   = (int*)w;  w += 1024*256;

    hipLaunchKernelGGL(k1_conv1_knn, dim3(1024 + 2304), dim3(128), 0, stream,
                       pg, W1, b1, W2, W3, W4, Wf,
                       h1, p1s, p1q, idxw, W2b, W3b, W4b, Wfb);
    hipLaunchKernelGGL(k_bn_fin2, dim3(32), dim3(256), 0, stream,
                       p1s, p1q, 1024, 128, 1.f/32768.f, gamma1, beta1, scale1, shift1);
    hipLaunchKernelGGL(k3_mfma, dim3(512), dim3(512), 0, stream,
                       h1, scale1, shift1, W2b, b2, W3b, b3, h3b, p3s, p3q);
    hipLaunchKernelGGL(k_bn_fin2, dim3(128), dim3(256), 0, stream,
                       p3s, p3q, 1024, 512, 1.f/32768.f, gamma3, beta3, scale3, shift3);
    hipLaunchKernelGGL(k5_mfma, dim3(512), dim3(768), 0, stream,
                       h3b, scale3, shift3, W4b, b4, idxw, fg2, A, S1p, S2p);
    hipLaunchKernelGGL(k7_fused, dim3(64), dim3(384), 0, stream,
                       fg2, A, alpha, beta_af, S1p, S2p, Wfb, bf, hf, pfs, pfq);
    hipLaunchKernelGGL(k_bn_fin2, dim3(96), dim3(256), 0, stream,
                       pfs, pfq, 64, 384, 1.f/1024.f, gammaf, betaf, scalef, shiftf);
    hipLaunchKernelGGL(k9_out, dim3(1024), dim3(384), 0, stream,
                       hf, scalef, shiftf, out);
}